// Round 1
// baseline (1531.586 us; speedup 1.0000x reference)
//
#include <hip/hip_runtime.h>
#include <math.h>

// Problem constants
#define BB_ 4
#define LL_ 1024
#define DD_ 1024
#define HH_ 16
#define HD_ 64
#define KTOP_ 716
#define SCALE_ 0.125f

// ---------------------------------------------------------------------------
// K1: pooled[b,d] = (mean_l x[b,l,d] + max_l x[b,l,d]) / 2
// ---------------------------------------------------------------------------
__global__ __launch_bounds__(256) void pool_kernel(const float* __restrict__ x,
                                                   float* __restrict__ pooled) {
  int g = blockIdx.x * 256 + threadIdx.x;      // 0..4095
  int b = g >> 10, d = g & 1023;
  const float* xp = x + ((size_t)b << 20) + d;
  float s = 0.f, m = -INFINITY;
  #pragma unroll 4
  for (int l = 0; l < LL_; ++l) {
    float v = xp[(size_t)l << 10];
    s += v;
    m = fmaxf(m, v);
  }
  pooled[g] = (s * (1.0f / 1024.0f) + m) * 0.5f;
}

// ---------------------------------------------------------------------------
// K2: pattern selector MLP -> per-batch mask-regime booleans
// meta[b*8+0..4] = t00, t10, t01, t11, need_sparse
// ---------------------------------------------------------------------------
__global__ __launch_bounds__(256) void pattern_kernel(
    const float* __restrict__ pooled,
    const float* __restrict__ w1, const float* __restrict__ b1,
    const float* __restrict__ lng, const float* __restrict__ lnb,
    const float* __restrict__ w2, const float* __restrict__ b2,
    const float* __restrict__ w3, const float* __restrict__ b3,
    const float* __restrict__ pb, int* __restrict__ meta) {
  __shared__ float pool_s[1024];
  __shared__ float h1[1024];
  __shared__ float h2[512];
  __shared__ float red[256];
  int b = blockIdx.x, t = threadIdx.x;

  for (int i = t; i < 1024; i += 256) pool_s[i] = pooled[b * 1024 + i];
  __syncthreads();

  // h1 = pooled @ w1^T + b1
  for (int o = t; o < 1024; o += 256) {
    float acc = b1[o];
    const float* wr = w1 + (size_t)o * 1024;
    for (int k = 0; k < 1024; ++k) acc += pool_s[k] * wr[k];
    h1[o] = acc;
  }
  __syncthreads();

  // LayerNorm: mu
  float ls = 0.f;
  for (int i = t; i < 1024; i += 256) ls += h1[i];
  red[t] = ls; __syncthreads();
  for (int s = 128; s > 0; s >>= 1) { if (t < s) red[t] += red[t + s]; __syncthreads(); }
  float mean = red[0] * (1.0f / 1024.0f);
  __syncthreads();
  // var = mean((h-mu)^2)
  float lq = 0.f;
  for (int i = t; i < 1024; i += 256) { float dv = h1[i] - mean; lq += dv * dv; }
  red[t] = lq; __syncthreads();
  for (int s = 128; s > 0; s >>= 1) { if (t < s) red[t] += red[t + s]; __syncthreads(); }
  float var = red[0] * (1.0f / 1024.0f);
  float rstd = 1.0f / sqrtf(var + 1e-5f);
  __syncthreads();
  // normalize + exact gelu
  for (int i = t; i < 1024; i += 256) {
    float v = (h1[i] - mean) * rstd * lng[i] + lnb[i];
    h1[i] = 0.5f * v * (1.0f + erff(v * 0.70710678118654752f));
  }
  __syncthreads();

  // h2 = gelu(h1 @ w2^T + b2)
  for (int o = t; o < 512; o += 256) {
    float acc = b2[o];
    const float* wr = w2 + (size_t)o * 1024;
    for (int k = 0; k < 1024; ++k) acc += h1[k] * wr[k];
    h2[o] = 0.5f * acc * (1.0f + erff(acc * 0.70710678118654752f));
  }
  __syncthreads();

  // logits (3) + pattern_bias, softmax, regime flags
  float lgv[3];
  for (int c = 0; c < 3; ++c) {
    float p = 0.f;
    for (int i = t; i < 512; i += 256) p += h2[i] * w3[c * 512 + i];
    __syncthreads();
    red[t] = p; __syncthreads();
    for (int s = 128; s > 0; s >>= 1) { if (t < s) red[t] += red[t + s]; __syncthreads(); }
    lgv[c] = red[0] + b3[c] + pb[c];
  }
  if (t == 0) {
    float mx = fmaxf(lgv[0], fmaxf(lgv[1], lgv[2]));
    float e0 = __expf(lgv[0] - mx), e1 = __expf(lgv[1] - mx), e2 = __expf(lgv[2] - mx);
    float inv = 1.0f / (e0 + e1 + e2);
    float p0 = e0 * inv, p1 = e1 * inv, p2 = e2 * inv;
    // replicate reference add order: (pw0*local + pw1) + pw2*sparse
    float c00 = p1;
    float c10 = p0 + p1;
    float c01 = p1 + p2;
    float c11 = (p0 + p1) + p2;
    int t00 = c00 > 0.1f, t10 = c10 > 0.1f, t01 = c01 > 0.1f, t11 = c11 > 0.1f;
    meta[b * 8 + 0] = t00;
    meta[b * 8 + 1] = t10;
    meta[b * 8 + 2] = t01;
    meta[b * 8 + 3] = t11;
    meta[b * 8 + 4] = (t00 != t01) || (t10 != t11);  // need_sparse
  }
}

// ---------------------------------------------------------------------------
// K3: QKV GEMM  qkv[m][n] = sum_k x[m][k]*w_qkv[n][k], scatter to q/k/v [B,H,L,HD]
// 128x128 tile, BK=8, 8x8 per thread
// ---------------------------------------------------------------------------
__global__ __launch_bounds__(256) void qkv_gemm(const float* __restrict__ X,
                                                const float* __restrict__ W,
                                                float* __restrict__ qw,
                                                float* __restrict__ kw,
                                                float* __restrict__ vw) {
  __shared__ float As[8][128];
  __shared__ float Bs[8][128];
  int tid = threadIdx.x;
  int row0 = blockIdx.y * 128, col0 = blockIdx.x * 128;
  int lr = tid >> 1;
  int lk = (tid & 1) * 4;
  int ty = tid >> 4, tx = tid & 15;
  float acc[8][8] = {};

  for (int kb = 0; kb < 1024; kb += 8) {
    float4 a4 = *(const float4*)(X + (size_t)(row0 + lr) * 1024 + kb + lk);
    float4 b4 = *(const float4*)(W + (size_t)(col0 + lr) * 1024 + kb + lk);
    __syncthreads();
    As[lk + 0][lr] = a4.x; As[lk + 1][lr] = a4.y; As[lk + 2][lr] = a4.z; As[lk + 3][lr] = a4.w;
    Bs[lk + 0][lr] = b4.x; Bs[lk + 1][lr] = b4.y; Bs[lk + 2][lr] = b4.z; Bs[lk + 3][lr] = b4.w;
    __syncthreads();
    #pragma unroll
    for (int kk = 0; kk < 8; ++kk) {
      float av[8], bv[8];
      #pragma unroll
      for (int i = 0; i < 8; ++i) av[i] = As[kk][ty * 8 + i];
      #pragma unroll
      for (int j = 0; j < 8; ++j) bv[j] = Bs[kk][tx * 8 + j];
      #pragma unroll
      for (int i = 0; i < 8; ++i)
        #pragma unroll
        for (int j = 0; j < 8; ++j) acc[i][j] += av[i] * bv[j];
    }
  }

  // scatter: n = c*1024 + h*64 + hd
  #pragma unroll
  for (int i = 0; i < 8; ++i) {
    int m = row0 + ty * 8 + i;
    int bb = m >> 10, l = m & 1023;
    #pragma unroll
    for (int j = 0; j < 8; j += 4) {
      int n = col0 + tx * 8 + j;
      int c = n >> 10;
      int hh = (n >> 6) & 15;
      int hd = n & 63;
      float* base = (c == 0) ? qw : (c == 1) ? kw : vw;
      float* dst = base + ((size_t)(bb * 16 + hh) * 1024 + l) * 64 + hd;
      *(float4*)dst = make_float4(acc[i][j], acc[i][j + 1], acc[i][j + 2], acc[i][j + 3]);
    }
  }
}

// ---------------------------------------------------------------------------
// K4: fused attention: scores -> per-row topk threshold -> mask -> softmax -> PV
// one block per (b, h, 32-row tile); 256 threads = 4 waves; wave w owns rows w*8..w*8+7
// ---------------------------------------------------------------------------
__global__ __launch_bounds__(256) void attn_kernel(const float* __restrict__ qw,
                                                   const float* __restrict__ kw,
                                                   const float* __restrict__ vw,
                                                   const int* __restrict__ meta,
                                                   float* __restrict__ ao) {
  __shared__ float S[32][1028];      // scores / probs, padded
  __shared__ float qs[32][68];       // q tile, padded
  __shared__ float kc[64][68];       // k/v chunk, padded
  __shared__ float rowsum_s[32];

  int tid = threadIdx.x;
  int lane = tid & 63;
  int wv = tid >> 6;                  // wave id == row group
  int id = blockIdx.x;
  int rt = id & 31;
  int h = (id >> 5) & 15;
  int b = id >> 9;
  int bh = b * 16 + h;
  int row0 = rt * 32;

  // wave-local q tile load: rows wv*8..wv*8+7 (512 floats)
  {
    const float4* qp = (const float4*)(qw + ((size_t)bh * 1024 + row0 + wv * 8) * 64);
    #pragma unroll
    for (int i = 0; i < 2; ++i) {
      int f = lane + 64 * i;          // 0..127 float4s
      float4 v = qp[f];
      int r = wv * 8 + (f >> 4);
      int d = (f & 15) << 2;
      qs[r][d] = v.x; qs[r][d + 1] = v.y; qs[r][d + 2] = v.z; qs[r][d + 3] = v.w;
    }
  }
  const int* mb = meta + b * 8;
  int t00 = mb[0], t10 = mb[1], t01 = mb[2], t11 = mb[3], needs = mb[4];

  int lr = lane >> 4, lc = lane & 15;
  int r_a = wv * 8 + lr * 2;
  int r_b = r_a + 1;

  // ---- scores: S[r][j] = SCALE * dot(q[r], k[j]) ----
  for (int cb = 0; cb < 16; ++cb) {
    __syncthreads();
    const float4* kp = (const float4*)(kw + ((size_t)bh * 1024 + cb * 64) * 64);
    #pragma unroll
    for (int i = 0; i < 4; ++i) {
      int f = tid + 256 * i;          // 0..1023 float4s
      float4 v = kp[f];
      int c = f >> 4, d = (f & 15) << 2;
      kc[c][d] = v.x; kc[c][d + 1] = v.y; kc[c][d + 2] = v.z; kc[c][d + 3] = v.w;
    }
    __syncthreads();

    float acc0[4] = {0.f, 0.f, 0.f, 0.f};
    float acc1[4] = {0.f, 0.f, 0.f, 0.f};
    for (int dq = 0; dq < 64; dq += 4) {
      float4 qa = *(const float4*)&qs[r_a][dq];
      float4 qb = *(const float4*)&qs[r_b][dq];
      #pragma unroll
      for (int cj = 0; cj < 4; ++cj) {
        float4 kv = *(const float4*)&kc[lc + 16 * cj][dq];
        acc0[cj] += qa.x * kv.x + qa.y * kv.y + qa.z * kv.z + qa.w * kv.w;
        acc1[cj] += qb.x * kv.x + qb.y * kv.y + qb.z * kv.z + qb.w * kv.w;
      }
    }
    #pragma unroll
    for (int cj = 0; cj < 4; ++cj) {
      S[r_a][cb * 64 + lc + 16 * cj] = acc0[cj] * SCALE_;
      S[r_b][cb * 64 + lc + 16 * cj] = acc1[cj] * SCALE_;
    }
  }

  // ---- per-row topk threshold + mask + softmax (wave-local rows) ----
  for (int rr = 0; rr < 8; ++rr) {
    int r = wv * 8 + rr;
    int grow = row0 + r;
    float sv[16];
    unsigned kv[16];
    #pragma unroll
    for (int i2 = 0; i2 < 16; ++i2) {
      float s = S[r][lane + 64 * i2];
      sv[i2] = s;
      unsigned u = __float_as_uint(s);
      kv[i2] = (u & 0x80000000u) ? ~u : (u | 0x80000000u);  // order-preserving key
    }
    unsigned T = 0u;
    if (needs) {
      // largest T with count(key >= T) >= KTOP  ==  KTOP-th largest key
      for (int bit = 31; bit >= 0; --bit) {
        unsigned cand = T | (1u << bit);
        int cnt = 0;
        #pragma unroll
        for (int i2 = 0; i2 < 16; ++i2) cnt += (kv[i2] >= cand) ? 1 : 0;
        for (int off = 32; off; off >>= 1) cnt += __shfl_xor(cnt, off, 64);
        if (cnt >= KTOP_) T = cand;
      }
    }
    // mask: keep = tbl[local][sparse]
    float mx = -INFINITY;
    int kept = 0;
    unsigned kmask = 0;
    #pragma unroll
    for (int i2 = 0; i2 < 16; ++i2) {
      int j = lane + 64 * i2;
      int sp = (kv[i2] >= T) ? 1 : 0;   // needs==0 -> T=0 -> sp=1 (regime-consistent)
      int dj = grow - j;
      int lo = (dj <= 16 && dj >= -16) ? 1 : 0;
      int keep = sp ? (lo ? t11 : t01) : (lo ? t10 : t00);
      kept += keep;
      if (keep) { kmask |= (1u << i2); mx = fmaxf(mx, sv[i2]); }
    }
    for (int off = 32; off; off >>= 1) {
      mx = fmaxf(mx, __shfl_xor(mx, off, 64));
      kept += __shfl_xor(kept, off, 64);
    }
    if (kept == 0) {
      // fallback: attend only to self with score 0 -> one-hot row
      #pragma unroll
      for (int i2 = 0; i2 < 16; ++i2) {
        int j = lane + 64 * i2;
        S[r][j] = (j == grow) ? 1.0f : 0.0f;
      }
      if (lane == 0) rowsum_s[r] = 1.0f;
    } else {
      float sum = 0.f;
      #pragma unroll
      for (int i2 = 0; i2 < 16; ++i2) {
        float p = ((kmask >> i2) & 1u) ? __expf(sv[i2] - mx) : 0.0f;
        sum += p;
        S[r][lane + 64 * i2] = p;
      }
      for (int off = 32; off; off >>= 1) sum += __shfl_xor(sum, off, 64);
      if (lane == 0) rowsum_s[r] = sum;
    }
  }

  // ---- PV: out[r][d] = sum_j P[r][j] * v[j][d], then /rowsum ----
  int ld = lane & 15;
  int d0 = ld * 4;
  // reuse lr-based rows (r_a, r_b)
  float4 oa0 = make_float4(0.f, 0.f, 0.f, 0.f);
  float4 oa1 = make_float4(0.f, 0.f, 0.f, 0.f);
  for (int vb = 0; vb < 16; ++vb) {
    __syncthreads();
    const float4* vp = (const float4*)(vw + ((size_t)bh * 1024 + vb * 64) * 64);
    #pragma unroll
    for (int i = 0; i < 4; ++i) {
      int f = tid + 256 * i;
      float4 v = vp[f];
      int c = f >> 4, d = (f & 15) << 2;
      kc[c][d] = v.x; kc[c][d + 1] = v.y; kc[c][d + 2] = v.z; kc[c][d + 3] = v.w;
    }
    __syncthreads();
    for (int cq = 0; cq < 64; cq += 4) {
      float4 pa = *(const float4*)&S[r_a][vb * 64 + cq];
      float4 pb = *(const float4*)&S[r_b][vb * 64 + cq];
      float par[4] = {pa.x, pa.y, pa.z, pa.w};
      float pbr[4] = {pb.x, pb.y, pb.z, pb.w};
      #pragma unroll
      for (int tt = 0; tt < 4; ++tt) {
        float4 vv = *(const float4*)&kc[cq + tt][d0];
        oa0.x += par[tt] * vv.x; oa0.y += par[tt] * vv.y;
        oa0.z += par[tt] * vv.z; oa0.w += par[tt] * vv.w;
        oa1.x += pbr[tt] * vv.x; oa1.y += pbr[tt] * vv.y;
        oa1.z += pbr[tt] * vv.z; oa1.w += pbr[tt] * vv.w;
      }
    }
  }
  float inv0 = 1.0f / rowsum_s[r_a];
  float inv1 = 1.0f / rowsum_s[r_b];
  // ao layout: [b][l][h*64+d]
  float* o0 = ao + ((size_t)b * 1024 + row0 + r_a) * 1024 + h * 64 + d0;
  float* o1 = ao + ((size_t)b * 1024 + row0 + r_b) * 1024 + h * 64 + d0;
  *(float4*)o0 = make_float4(oa0.x * inv0, oa0.y * inv0, oa0.z * inv0, oa0.w * inv0);
  *(float4*)o1 = make_float4(oa1.x * inv1, oa1.y * inv1, oa1.z * inv1, oa1.w * inv1);
}

// ---------------------------------------------------------------------------
// K5: out = ao @ w_proj^T + b_proj   (128x128 tile, BK=8, 8x8/thread)
// ---------------------------------------------------------------------------
__global__ __launch_bounds__(256) void proj_gemm(const float* __restrict__ A,
                                                 const float* __restrict__ W,
                                                 const float* __restrict__ bias,
                                                 float* __restrict__ out) {
  __shared__ float As[8][128];
  __shared__ float Bs[8][128];
  int tid = threadIdx.x;
  int row0 = blockIdx.y * 128, col0 = blockIdx.x * 128;
  int lr = tid >> 1;
  int lk = (tid & 1) * 4;
  int ty = tid >> 4, tx = tid & 15;
  float acc[8][8] = {};

  for (int kb = 0; kb < 1024; kb += 8) {
    float4 a4 = *(const float4*)(A + (size_t)(row0 + lr) * 1024 + kb + lk);
    float4 b4 = *(const float4*)(W + (size_t)(col0 + lr) * 1024 + kb + lk);
    __syncthreads();
    As[lk + 0][lr] = a4.x; As[lk + 1][lr] = a4.y; As[lk + 2][lr] = a4.z; As[lk + 3][lr] = a4.w;
    Bs[lk + 0][lr] = b4.x; Bs[lk + 1][lr] = b4.y; Bs[lk + 2][lr] = b4.z; Bs[lk + 3][lr] = b4.w;
    __syncthreads();
    #pragma unroll
    for (int kk = 0; kk < 8; ++kk) {
      float av[8], bv[8];
      #pragma unroll
      for (int i = 0; i < 8; ++i) av[i] = As[kk][ty * 8 + i];
      #pragma unroll
      for (int j = 0; j < 8; ++j) bv[j] = Bs[kk][tx * 8 + j];
      #pragma unroll
      for (int i = 0; i < 8; ++i)
        #pragma unroll
        for (int j = 0; j < 8; ++j) acc[i][j] += av[i] * bv[j];
    }
  }
  #pragma unroll
  for (int i = 0; i < 8; ++i) {
    int m = row0 + ty * 8 + i;
    #pragma unroll
    for (int j = 0; j < 8; j += 4) {
      int n = col0 + tx * 8 + j;
      *(float4*)(out + (size_t)m * 1024 + n) =
          make_float4(acc[i][j] + bias[n], acc[i][j + 1] + bias[n + 1],
                      acc[i][j + 2] + bias[n + 2], acc[i][j + 3] + bias[n + 3]);
    }
  }
}

// ---------------------------------------------------------------------------
extern "C" void kernel_launch(void* const* d_in, const int* in_sizes, int n_in,
                              void* d_out, int out_size, void* d_ws, size_t ws_size,
                              hipStream_t stream) {
  const float* x      = (const float*)d_in[0];
  const float* w_qkv  = (const float*)d_in[1];
  const float* w_proj = (const float*)d_in[2];
  const float* b_proj = (const float*)d_in[3];
  const float* ps_w1  = (const float*)d_in[4];
  const float* ps_b1  = (const float*)d_in[5];
  const float* ln_g   = (const float*)d_in[6];
  const float* ln_b   = (const float*)d_in[7];
  const float* ps_w2  = (const float*)d_in[8];
  const float* ps_b2  = (const float*)d_in[9];
  const float* ps_w3  = (const float*)d_in[10];
  const float* ps_b3  = (const float*)d_in[11];
  const float* pbias  = (const float*)d_in[12];
  // d_in[13]=sparse_w, d_in[14]=sparse_b: provably irrelevant to output
  // (per-row monotone affine map preserves top-k order).

  float* ws = (float*)d_ws;
  float* pooled = ws;                       // 4096 floats
  int*   meta   = (int*)(ws + 4096);        // 32 ints
  float* qw = ws + 262144;                  // [B,H,L,HD] each 4 MiFloats
  float* kw = qw + 4194304;
  float* vw = kw + 4194304;
  float* ao = vw + 4194304;                 // [B,L,D]
  float* out = (float*)d_out;

  pool_kernel<<<16, 256, 0, stream>>>(x, pooled);
  pattern_kernel<<<4, 256, 0, stream>>>(pooled, ps_w1, ps_b1, ln_g, ln_b,
                                        ps_w2, ps_b2, ps_w3, ps_b3, pbias, meta);
  qkv_gemm<<<dim3(24, 32), 256, 0, stream>>>(x, w_qkv, qw, kw, vw);
  attn_kernel<<<2048, 256, 0, stream>>>(qw, kw, vw, meta, ao);
  proj_gemm<<<dim3(8, 32), 256, 0, stream>>>(ao, w_proj, b_proj, out);
}

// Round 2
// 980.552 us; speedup vs baseline: 1.5620x; 1.5620x over previous
//
#include <hip/hip_runtime.h>
#include <math.h>

// Problem constants
#define BB_ 4
#define LL_ 1024
#define DD_ 1024
#define HH_ 16
#define HD_ 64
#define KTOP_ 716
#define SCALE_ 0.125f

typedef float f4v __attribute__((ext_vector_type(4)));
typedef short s8v __attribute__((ext_vector_type(8)));
typedef __bf16 bf8v __attribute__((ext_vector_type(8)));

static __device__ inline unsigned short f2bf(float f) {
  unsigned u = __float_as_uint(f);
  u += 0x7fffu + ((u >> 16) & 1u);
  return (unsigned short)(u >> 16);
}
static __device__ inline float bf2f(unsigned short h) {
  return __uint_as_float((unsigned)h << 16);
}
static __device__ inline f4v mfma16(s8v a, s8v b, f4v c) {
  union { s8v s; bf8v b; } ua, ub;
  ua.s = a; ub.s = b;
  return __builtin_amdgcn_mfma_f32_16x16x32_bf16(ua.b, ub.b, c, 0, 0, 0);
}

// ---------------------------------------------------------------------------
// K1: pooled[b,d] = (mean_l x[b,l,d] + max_l x[b,l,d]) / 2
// ---------------------------------------------------------------------------
__global__ __launch_bounds__(256) void pool_kernel(const float* __restrict__ x,
                                                   float* __restrict__ pooled) {
  int g = blockIdx.x * 256 + threadIdx.x;
  int b = g >> 10, d = g & 1023;
  const float* xp = x + ((size_t)b << 20) + d;
  float s = 0.f, m = -INFINITY;
  #pragma unroll 4
  for (int l = 0; l < LL_; ++l) {
    float v = xp[(size_t)l << 10];
    s += v;
    m = fmaxf(m, v);
  }
  pooled[g] = (s * (1.0f / 1024.0f) + m) * 0.5f;
}

// ---------------------------------------------------------------------------
// K2: pattern selector MLP -> per-batch mask-regime booleans
// ---------------------------------------------------------------------------
__global__ __launch_bounds__(256) void pattern_kernel(
    const float* __restrict__ pooled,
    const float* __restrict__ w1, const float* __restrict__ b1,
    const float* __restrict__ lng, const float* __restrict__ lnb,
    const float* __restrict__ w2, const float* __restrict__ b2,
    const float* __restrict__ w3, const float* __restrict__ b3,
    const float* __restrict__ pb, int* __restrict__ meta) {
  __shared__ float pool_s[1024];
  __shared__ float h1[1024];
  __shared__ float h2[512];
  __shared__ float red[256];
  int b = blockIdx.x, t = threadIdx.x;

  for (int i = t; i < 1024; i += 256) pool_s[i] = pooled[b * 1024 + i];
  __syncthreads();

  for (int o = t; o < 1024; o += 256) {
    float acc = b1[o];
    const float* wr = w1 + (size_t)o * 1024;
    for (int k = 0; k < 1024; ++k) acc += pool_s[k] * wr[k];
    h1[o] = acc;
  }
  __syncthreads();

  float ls = 0.f;
  for (int i = t; i < 1024; i += 256) ls += h1[i];
  red[t] = ls; __syncthreads();
  for (int s = 128; s > 0; s >>= 1) { if (t < s) red[t] += red[t + s]; __syncthreads(); }
  float mean = red[0] * (1.0f / 1024.0f);
  __syncthreads();
  float lq = 0.f;
  for (int i = t; i < 1024; i += 256) { float dv = h1[i] - mean; lq += dv * dv; }
  red[t] = lq; __syncthreads();
  for (int s = 128; s > 0; s >>= 1) { if (t < s) red[t] += red[t + s]; __syncthreads(); }
  float var = red[0] * (1.0f / 1024.0f);
  float rstd = 1.0f / sqrtf(var + 1e-5f);
  __syncthreads();
  for (int i = t; i < 1024; i += 256) {
    float v = (h1[i] - mean) * rstd * lng[i] + lnb[i];
    h1[i] = 0.5f * v * (1.0f + erff(v * 0.70710678118654752f));
  }
  __syncthreads();

  for (int o = t; o < 512; o += 256) {
    float acc = b2[o];
    const float* wr = w2 + (size_t)o * 1024;
    for (int k = 0; k < 1024; ++k) acc += h1[k] * wr[k];
    h2[o] = 0.5f * acc * (1.0f + erff(acc * 0.70710678118654752f));
  }
  __syncthreads();

  float lgv[3];
  for (int c = 0; c < 3; ++c) {
    float p = 0.f;
    for (int i = t; i < 512; i += 256) p += h2[i] * w3[c * 512 + i];
    __syncthreads();
    red[t] = p; __syncthreads();
    for (int s = 128; s > 0; s >>= 1) { if (t < s) red[t] += red[t + s]; __syncthreads(); }
    lgv[c] = red[0] + b3[c] + pb[c];
  }
  if (t == 0) {
    float mx = fmaxf(lgv[0], fmaxf(lgv[1], lgv[2]));
    float e0 = __expf(lgv[0] - mx), e1 = __expf(lgv[1] - mx), e2 = __expf(lgv[2] - mx);
    float inv = 1.0f / (e0 + e1 + e2);
    float p0 = e0 * inv, p1 = e1 * inv, p2 = e2 * inv;
    float c00 = p1;
    float c10 = p0 + p1;
    float c01 = p1 + p2;
    float c11 = (p0 + p1) + p2;
    int t00 = c00 > 0.1f, t10 = c10 > 0.1f, t01 = c01 > 0.1f, t11 = c11 > 0.1f;
    meta[b * 8 + 0] = t00;
    meta[b * 8 + 1] = t10;
    meta[b * 8 + 2] = t01;
    meta[b * 8 + 3] = t11;
    meta[b * 8 + 4] = (t00 != t01) || (t10 != t11);  // need_sparse
  }
}

// ---------------------------------------------------------------------------
// K3: QKV GEMM (f32, unchanged this round)
// ---------------------------------------------------------------------------
__global__ __launch_bounds__(256) void qkv_gemm(const float* __restrict__ X,
                                                const float* __restrict__ W,
                                                float* __restrict__ qw,
                                                float* __restrict__ kw,
                                                float* __restrict__ vw) {
  __shared__ float As[8][128];
  __shared__ float Bs[8][128];
  int tid = threadIdx.x;
  int row0 = blockIdx.y * 128, col0 = blockIdx.x * 128;
  int lr = tid >> 1;
  int lk = (tid & 1) * 4;
  int ty = tid >> 4, tx = tid & 15;
  float acc[8][8] = {};

  for (int kb = 0; kb < 1024; kb += 8) {
    float4 a4 = *(const float4*)(X + (size_t)(row0 + lr) * 1024 + kb + lk);
    float4 b4 = *(const float4*)(W + (size_t)(col0 + lr) * 1024 + kb + lk);
    __syncthreads();
    As[lk + 0][lr] = a4.x; As[lk + 1][lr] = a4.y; As[lk + 2][lr] = a4.z; As[lk + 3][lr] = a4.w;
    Bs[lk + 0][lr] = b4.x; Bs[lk + 1][lr] = b4.y; Bs[lk + 2][lr] = b4.z; Bs[lk + 3][lr] = b4.w;
    __syncthreads();
    #pragma unroll
    for (int kk = 0; kk < 8; ++kk) {
      float av[8], bv[8];
      #pragma unroll
      for (int i = 0; i < 8; ++i) av[i] = As[kk][ty * 8 + i];
      #pragma unroll
      for (int j = 0; j < 8; ++j) bv[j] = Bs[kk][tx * 8 + j];
      #pragma unroll
      for (int i = 0; i < 8; ++i)
        #pragma unroll
        for (int j = 0; j < 8; ++j) acc[i][j] += av[i] * bv[j];
    }
  }
  #pragma unroll
  for (int i = 0; i < 8; ++i) {
    int m = row0 + ty * 8 + i;
    int bb = m >> 10, l = m & 1023;
    #pragma unroll
    for (int j = 0; j < 8; j += 4) {
      int n = col0 + tx * 8 + j;
      int c = n >> 10;
      int hh = (n >> 6) & 15;
      int hd = n & 63;
      float* base = (c == 0) ? qw : (c == 1) ? kw : vw;
      float* dst = base + ((size_t)(bb * 16 + hh) * 1024 + l) * 64 + hd;
      *(float4*)dst = make_float4(acc[i][j], acc[i][j + 1], acc[i][j + 2], acc[i][j + 3]);
    }
  }
}

// ---------------------------------------------------------------------------
// K3b: prep — split q (prescaled by 0.125) and k into bf16 hi/lo
// ---------------------------------------------------------------------------
__global__ __launch_bounds__(256) void prep_qk(const float* __restrict__ qw,
                                               const float* __restrict__ kw,
                                               unsigned short* __restrict__ qh,
                                               unsigned short* __restrict__ ql,
                                               unsigned short* __restrict__ kh,
                                               unsigned short* __restrict__ kl) {
  int i4 = blockIdx.x * 256 + threadIdx.x;   // 0 .. 1M-1 (float4 units)
  float4 q = ((const float4*)qw)[i4];
  float4 k = ((const float4*)kw)[i4];
  float qf[4] = {q.x * SCALE_, q.y * SCALE_, q.z * SCALE_, q.w * SCALE_};
  float kf[4] = {k.x, k.y, k.z, k.w};
  ushort4 qh4, ql4, kh4, kl4;
  unsigned short* qhp = (unsigned short*)&qh4;
  unsigned short* qlp = (unsigned short*)&ql4;
  unsigned short* khp = (unsigned short*)&kh4;
  unsigned short* klp = (unsigned short*)&kl4;
  #pragma unroll
  for (int i = 0; i < 4; ++i) {
    unsigned short h = f2bf(qf[i]);
    qhp[i] = h; qlp[i] = f2bf(qf[i] - bf2f(h));
    unsigned short h2 = f2bf(kf[i]);
    khp[i] = h2; klp[i] = f2bf(kf[i] - bf2f(h2));
  }
  *(ushort4*)(qh + 4 * (size_t)i4) = qh4;
  *(ushort4*)(ql + 4 * (size_t)i4) = ql4;
  *(ushort4*)(kh + 4 * (size_t)i4) = kh4;
  *(ushort4*)(kl + 4 * (size_t)i4) = kl4;
}

// ---------------------------------------------------------------------------
// K3c: prep — transpose v [bh][l][d] -> vt [bh][d][l] split bf16 hi/lo
// ---------------------------------------------------------------------------
__global__ __launch_bounds__(256) void prep_vt(const float* __restrict__ vw,
                                               unsigned short* __restrict__ vth,
                                               unsigned short* __restrict__ vtl) {
  __shared__ float t[64][65];
  int bh = blockIdx.y;
  int l0 = blockIdx.x * 64;
  int tid = threadIdx.x;
  int lr = tid >> 4, dc = (tid & 15) * 4;
  #pragma unroll
  for (int it = 0; it < 4; ++it) {
    int ll = lr + it * 16;
    float4 v = *(const float4*)(vw + ((size_t)bh * 1024 + l0 + ll) * 64 + dc);
    t[dc + 0][ll] = v.x; t[dc + 1][ll] = v.y; t[dc + 2][ll] = v.z; t[dc + 3][ll] = v.w;
  }
  __syncthreads();
  int d = tid >> 2, lc = (tid & 3) * 16;
  unsigned short* dsth = vth + ((size_t)bh * 64 + d) * 1024 + l0 + lc;
  unsigned short* dstl = vtl + ((size_t)bh * 64 + d) * 1024 + l0 + lc;
  #pragma unroll
  for (int i = 0; i < 16; i += 4) {
    ushort4 h4, l4;
    unsigned short* hp = (unsigned short*)&h4;
    unsigned short* lp = (unsigned short*)&l4;
    #pragma unroll
    for (int jj = 0; jj < 4; ++jj) {
      float f = t[d][lc + i + jj];
      unsigned short h = f2bf(f);
      hp[jj] = h; lp[jj] = f2bf(f - bf2f(h));
    }
    *(ushort4*)(dsth + i) = h4;
    *(ushort4*)(dstl + i) = l4;
  }
}

// ---------------------------------------------------------------------------
// K4a: flash MFMA attention (needs==0 regimes: dense / local / self-only)
// grid 1024 blocks; block = 4 waves x 16 q-rows; online softmax; split-bf16
// ---------------------------------------------------------------------------
__global__ __launch_bounds__(256) void attn_flash(
    const unsigned short* __restrict__ qh, const unsigned short* __restrict__ ql,
    const unsigned short* __restrict__ kh, const unsigned short* __restrict__ kl,
    const unsigned short* __restrict__ vth, const unsigned short* __restrict__ vtl,
    const float* __restrict__ vw, const int* __restrict__ meta,
    float* __restrict__ ao) {
  int n = blockIdx.x;
  // XCD swizzle: all 16 q-tiles of one bh share an XCD (dispatch id % 8 const)
  int bh = ((n & 7) << 3) | (n >> 7);
  int qt = (n >> 3) & 15;
  int b = bh >> 4, h = bh & 15;
  const int* mb = meta + b * 8;
  if (mb[4]) return;  // needs sparse -> fallback kernel owns this batch
  int t00 = mb[0], t10 = mb[1];

  int tid = threadIdx.x, lane = tid & 63, wv = tid >> 6;
  int rowg = lane >> 4, colc = lane & 15;
  int q0 = qt * 64 + wv * 16;

  if (!t10) {
    // self-only regime: out row = v row
    #pragma unroll
    for (int it = 0; it < 4; ++it) {
      int idx = tid + it * 256;           // 1024 float4s = 64 rows x 64 d
      int r = idx >> 4, dc = (idx & 15) * 4;
      float4 v = *(const float4*)(vw + ((size_t)bh * 1024 + qt * 64 + r) * 64 + dc);
      *(float4*)(ao + ((size_t)b * 1024 + qt * 64 + r) * 1024 + h * 64 + dc) = v;
    }
    return;
  }
  bool local_only = !t00;

  __shared__ unsigned short pls[4][2][16][72];  // [wave][hi/lo][row][col(64)+pad]

  // hoist Q fragments (A operand: row = colc, k = rowg*8 .. +8, ks in {0,1})
  const unsigned short* qb_h = qh + ((size_t)bh * 1024 + q0 + colc) * 64 + rowg * 8;
  const unsigned short* qb_l = ql + ((size_t)bh * 1024 + q0 + colc) * 64 + rowg * 8;
  s8v Qh[2], Ql[2];
  Qh[0] = *(const s8v*)(qb_h);      Qh[1] = *(const s8v*)(qb_h + 32);
  Ql[0] = *(const s8v*)(qb_l);      Ql[1] = *(const s8v*)(qb_l + 32);

  f4v O[4];
  #pragma unroll
  for (int df = 0; df < 4; ++df) O[df] = (f4v){0.f, 0.f, 0.f, 0.f};
  float m[4] = {-1e30f, -1e30f, -1e30f, -1e30f};
  float lsum[4] = {0.f, 0.f, 0.f, 0.f};

  const unsigned short* vbh_base = vth + ((size_t)bh * 64 + colc) * 1024;
  const unsigned short* vbl_base = vtl + ((size_t)bh * 64 + colc) * 1024;

  for (int jb = 0; jb < 16; ++jb) {
    int jc0 = jb * 64;
    if (local_only && (jc0 + 63 < q0 - 16 || jc0 > q0 + 31)) continue;

    // ---- S chunk: 4 frags of 16x16, K=64 (2 k-steps), 3 split terms ----
    f4v s[4];
    const unsigned short* kb_h = kh + ((size_t)bh * 1024 + jc0 + colc) * 64 + rowg * 8;
    const unsigned short* kb_l = kl + ((size_t)bh * 1024 + jc0 + colc) * 64 + rowg * 8;
    #pragma unroll
    for (int jf = 0; jf < 4; ++jf) {
      f4v acc = (f4v){0.f, 0.f, 0.f, 0.f};
      const unsigned short* ph_ = kb_h + jf * 16 * 64;
      const unsigned short* pl_ = kb_l + jf * 16 * 64;
      s8v Kh0 = *(const s8v*)(ph_);
      s8v Kh1 = *(const s8v*)(ph_ + 32);
      s8v Kl0 = *(const s8v*)(pl_);
      s8v Kl1 = *(const s8v*)(pl_ + 32);
      acc = mfma16(Qh[0], Kh0, acc);
      acc = mfma16(Qh[1], Kh1, acc);
      acc = mfma16(Qh[0], Kl0, acc);
      acc = mfma16(Qh[1], Kl1, acc);
      acc = mfma16(Ql[0], Kh0, acc);
      acc = mfma16(Ql[1], Kh1, acc);
      s[jf] = acc;
    }

    // ---- mask + chunk row-max ----
    float cm[4] = {-1e30f, -1e30f, -1e30f, -1e30f};
    #pragma unroll
    for (int jf = 0; jf < 4; ++jf) {
      #pragma unroll
      for (int r = 0; r < 4; ++r) {
        float sv = s[jf][r];
        if (local_only) {
          int i = q0 + rowg * 4 + r;
          int j = jc0 + jf * 16 + colc;
          int dj = i - j;
          if (dj > 16 || dj < -16) { sv = -1e30f; s[jf][r] = sv; }
        }
        cm[r] = fmaxf(cm[r], sv);
      }
    }
    #pragma unroll
    for (int off = 1; off < 16; off <<= 1) {
      #pragma unroll
      for (int r = 0; r < 4; ++r) cm[r] = fmaxf(cm[r], __shfl_xor(cm[r], off, 64));
    }

    float fac[4], psum[4];
    #pragma unroll
    for (int r = 0; r < 4; ++r) {
      float mn = fmaxf(m[r], cm[r]);
      fac[r] = __expf(m[r] - mn);
      m[r] = mn;
      psum[r] = 0.f;
    }

    // ---- P = exp(s - m), split to bf16 hi/lo in LDS (C-layout write) ----
    #pragma unroll
    for (int jf = 0; jf < 4; ++jf) {
      #pragma unroll
      for (int r = 0; r < 4; ++r) {
        float sv = s[jf][r];
        float p = (sv > -1e29f) ? __expf(sv - m[r]) : 0.f;
        psum[r] += p;
        unsigned short ph = f2bf(p);
        unsigned short pl = f2bf(p - bf2f(ph));
        pls[wv][0][rowg * 4 + r][jf * 16 + colc] = ph;
        pls[wv][1][rowg * 4 + r][jf * 16 + colc] = pl;
      }
    }
    #pragma unroll
    for (int off = 1; off < 16; off <<= 1) {
      #pragma unroll
      for (int r = 0; r < 4; ++r) psum[r] += __shfl_xor(psum[r], off, 64);
    }
    #pragma unroll
    for (int r = 0; r < 4; ++r) lsum[r] = lsum[r] * fac[r] + psum[r];
    #pragma unroll
    for (int df = 0; df < 4; ++df) {
      #pragma unroll
      for (int r = 0; r < 4; ++r) O[df][r] *= fac[r];
    }

    // ---- PV: A = P (re-read in A-layout from LDS), B = VT fragments ----
    s8v Ph[2], Pl[2];
    #pragma unroll
    for (int ks = 0; ks < 2; ++ks) {
      Ph[ks] = *(const s8v*)((const void*)&pls[wv][0][colc][ks * 32 + rowg * 8]);
      Pl[ks] = *(const s8v*)((const void*)&pls[wv][1][colc][ks * 32 + rowg * 8]);
    }
    #pragma unroll
    for (int df = 0; df < 4; ++df) {
      const unsigned short* vph = vbh_base + (size_t)df * 16 * 1024 + jc0 + rowg * 8;
      const unsigned short* vpl = vbl_base + (size_t)df * 16 * 1024 + jc0 + rowg * 8;
      #pragma unroll
      for (int ks = 0; ks < 2; ++ks) {
        s8v Vh = *(const s8v*)(vph + ks * 32);
        s8v Vl = *(const s8v*)(vpl + ks * 32);
        O[df] = mfma16(Ph[ks], Vh, O[df]);
        O[df] = mfma16(Ph[ks], Vl, O[df]);
        O[df] = mfma16(Pl[ks], Vh, O[df]);
      }
    }
  }

  // ---- epilogue: normalize and store ----
  float inv[4];
  #pragma unroll
  for (int r = 0; r < 4; ++r) inv[r] = 1.0f / lsum[r];
  #pragma unroll
  for (int df = 0; df < 4; ++df) {
    #pragma unroll
    for (int r = 0; r < 4; ++r) {
      int i = q0 + rowg * 4 + r;
      ao[((size_t)b * 1024 + i) * 1024 + h * 64 + df * 16 + colc] = O[df][r] * inv[r];
    }
  }
}

// ---------------------------------------------------------------------------
// K4b: fallback attention (full scores in LDS, handles sparse topk regime).
// Runs when force==1 (ws too small) or per-batch need_sparse==1.
// ---------------------------------------------------------------------------
__global__ __launch_bounds__(256) void attn_kernel(const float* __restrict__ qw,
                                                   const float* __restrict__ kw,
                                                   const float* __restrict__ vw,
                                                   const int* __restrict__ meta,
                                                   float* __restrict__ ao,
                                                   int force) {
  __shared__ float S[32][1028];
  __shared__ float qs[32][68];
  __shared__ float kc[64][68];
  __shared__ float rowsum_s[32];

  int tid = threadIdx.x;
  int lane = tid & 63;
  int wv = tid >> 6;
  int id = blockIdx.x;
  int rt = id & 31;
  int h = (id >> 5) & 15;
  int b = id >> 9;
  int bh = b * 16 + h;
  int row0 = rt * 32;

  const int* mb = meta + b * 8;
  int t00 = mb[0], t10 = mb[1], t01 = mb[2], t11 = mb[3], needs = mb[4];
  if (!force && !needs) return;

  {
    const float4* qp = (const float4*)(qw + ((size_t)bh * 1024 + row0 + wv * 8) * 64);
    #pragma unroll
    for (int i = 0; i < 2; ++i) {
      int f = lane + 64 * i;
      float4 v = qp[f];
      int r = wv * 8 + (f >> 4);
      int d = (f & 15) << 2;
      qs[r][d] = v.x; qs[r][d + 1] = v.y; qs[r][d + 2] = v.z; qs[r][d + 3] = v.w;
    }
  }

  int lr = lane >> 4, lc = lane & 15;
  int r_a = wv * 8 + lr * 2;
  int r_b = r_a + 1;

  for (int cb = 0; cb < 16; ++cb) {
    __syncthreads();
    const float4* kp = (const float4*)(kw + ((size_t)bh * 1024 + cb * 64) * 64);
    #pragma unroll
    for (int i = 0; i < 4; ++i) {
      int f = tid + 256 * i;
      float4 v = kp[f];
      int c = f >> 4, d = (f & 15) << 2;
      kc[c][d] = v.x; kc[c][d + 1] = v.y; kc[c][d + 2] = v.z; kc[c][d + 3] = v.w;
    }
    __syncthreads();

    float acc0[4] = {0.f, 0.f, 0.f, 0.f};
    float acc1[4] = {0.f, 0.f, 0.f, 0.f};
    for (int dq = 0; dq < 64; dq += 4) {
      float4 qa = *(const float4*)&qs[r_a][dq];
      float4 qb = *(const float4*)&qs[r_b][dq];
      #pragma unroll
      for (int cj = 0; cj < 4; ++cj) {
        float4 kv = *(const float4*)&kc[lc + 16 * cj][dq];
        acc0[cj] += qa.x * kv.x + qa.y * kv.y + qa.z * kv.z + qa.w * kv.w;
        acc1[cj] += qb.x * kv.x + qb.y * kv.y + qb.z * kv.z + qb.w * kv.w;
      }
    }
    #pragma unroll
    for (int cj = 0; cj < 4; ++cj) {
      S[r_a][cb * 64 + lc + 16 * cj] = acc0[cj] * SCALE_;
      S[r_b][cb * 64 + lc + 16 * cj] = acc1[cj] * SCALE_;
    }
  }

  for (int rr = 0; rr < 8; ++rr) {
    int r = wv * 8 + rr;
    int grow = row0 + r;
    float sv[16];
    unsigned kv[16];
    #pragma unroll
    for (int i2 = 0; i2 < 16; ++i2) {
      float s = S[r][lane + 64 * i2];
      sv[i2] = s;
      unsigned u = __float_as_uint(s);
      kv[i2] = (u & 0x80000000u) ? ~u : (u | 0x80000000u);
    }
    unsigned T = 0u;
    if (needs) {
      for (int bit = 31; bit >= 0; --bit) {
        unsigned cand = T | (1u << bit);
        int cnt = 0;
        #pragma unroll
        for (int i2 = 0; i2 < 16; ++i2) cnt += (kv[i2] >= cand) ? 1 : 0;
        for (int off = 32; off; off >>= 1) cnt += __shfl_xor(cnt, off, 64);
        if (cnt >= KTOP_) T = cand;
      }
    }
    float mx = -INFINITY;
    int kept = 0;
    unsigned kmask = 0;
    #pragma unroll
    for (int i2 = 0; i2 < 16; ++i2) {
      int j = lane + 64 * i2;
      int sp = (kv[i2] >= T) ? 1 : 0;
      int dj = grow - j;
      int lo = (dj <= 16 && dj >= -16) ? 1 : 0;
      int keep = sp ? (lo ? t11 : t01) : (lo ? t10 : t00);
      kept += keep;
      if (keep) { kmask |= (1u << i2); mx = fmaxf(mx, sv[i2]); }
    }
    for (int off = 32; off; off >>= 1) {
      mx = fmaxf(mx, __shfl_xor(mx, off, 64));
      kept += __shfl_xor(kept, off, 64);
    }
    if (kept == 0) {
      #pragma unroll
      for (int i2 = 0; i2 < 16; ++i2) {
        int j = lane + 64 * i2;
        S[r][j] = (j == grow) ? 1.0f : 0.0f;
      }
      if (lane == 0) rowsum_s[r] = 1.0f;
    } else {
      float sum = 0.f;
      #pragma unroll
      for (int i2 = 0; i2 < 16; ++i2) {
        float p = ((kmask >> i2) & 1u) ? __expf(sv[i2] - mx) : 0.0f;
        sum += p;
        S[r][lane + 64 * i2] = p;
      }
      for (int off = 32; off; off >>= 1) sum += __shfl_xor(sum, off, 64);
      if (lane == 0) rowsum_s[r] = sum;
    }
  }

  int ld = lane & 15;
  int d0 = ld * 4;
  float4 oa0 = make_float4(0.f, 0.f, 0.f, 0.f);
  float4 oa1 = make_float4(0.f, 0.f, 0.f, 0.f);
  for (int vb = 0; vb < 16; ++vb) {
    __syncthreads();
    const float4* vp = (const float4*)(vw + ((size_t)bh * 1024 + vb * 64) * 64);
    #pragma unroll
    for (int i = 0; i < 4; ++i) {
      int f = tid + 256 * i;
      float4 v = vp[f];
      int c = f >> 4, d = (f & 15) << 2;
      kc[c][d] = v.x; kc[c][d + 1] = v.y; kc[c][d + 2] = v.z; kc[c][d + 3] = v.w;
    }
    __syncthreads();
    for (int cq = 0; cq < 64; cq += 4) {
      float4 pa = *(const float4*)&S[r_a][vb * 64 + cq];
      float4 pb = *(const float4*)&S[r_b][vb * 64 + cq];
      float par[4] = {pa.x, pa.y, pa.z, pa.w};
      float pbr[4] = {pb.x, pb.y, pb.z, pb.w};
      #pragma unroll
      for (int tt = 0; tt < 4; ++tt) {
        float4 vv = *(const float4*)&kc[cq + tt][d0];
        oa0.x += par[tt] * vv.x; oa0.y += par[tt] * vv.y;
        oa0.z += par[tt] * vv.z; oa0.w += par[tt] * vv.w;
        oa1.x += pbr[tt] * vv.x; oa1.y += pbr[tt] * vv.y;
        oa1.z += pbr[tt] * vv.z; oa1.w += pbr[tt] * vv.w;
      }
    }
  }
  float inv0 = 1.0f / rowsum_s[r_a];
  float inv1 = 1.0f / rowsum_s[r_b];
  float* o0 = ao + ((size_t)b * 1024 + row0 + r_a) * 1024 + h * 64 + d0;
  float* o1 = ao + ((size_t)b * 1024 + row0 + r_b) * 1024 + h * 64 + d0;
  *(float4*)o0 = make_float4(oa0.x * inv0, oa0.y * inv0, oa0.z * inv0, oa0.w * inv0);
  *(float4*)o1 = make_float4(oa1.x * inv1, oa1.y * inv1, oa1.z * inv1, oa1.w * inv1);
}

// ---------------------------------------------------------------------------
// K5: out = ao @ w_proj^T + b_proj
// ---------------------------------------------------------------------------
__global__ __launch_bounds__(256) void proj_gemm(const float* __restrict__ A,
                                                 const float* __restrict__ W,
                                                 const float* __restrict__ bias,
                                                 float* __restrict__ out) {
  __shared__ float As[8][128];
  __shared__ float Bs[8][128];
  int tid = threadIdx.x;
  int row0 = blockIdx.y * 128, col0 = blockIdx.x * 128;
  int lr = tid >> 1;
  int lk = (tid & 1) * 4;
  int ty = tid >> 4, tx = tid & 15;
  float acc[8][8] = {};

  for (int kb = 0; kb < 1024; kb += 8) {
    float4 a4 = *(const float4*)(A + (size_t)(row0 + lr) * 1024 + kb + lk);
    float4 b4 = *(const float4*)(W + (size_t)(col0 + lr) * 1024 + kb + lk);
    __syncthreads();
    As[lk + 0][lr] = a4.x; As[lk + 1][lr] = a4.y; As[lk + 2][lr] = a4.z; As[lk + 3][lr] = a4.w;
    Bs[lk + 0][lr] = b4.x; Bs[lk + 1][lr] = b4.y; Bs[lk + 2][lr] = b4.z; Bs[lk + 3][lr] = b4.w;
    __syncthreads();
    #pragma unroll
    for (int kk = 0; kk < 8; ++kk) {
      float av[8], bv[8];
      #pragma unroll
      for (int i = 0; i < 8; ++i) av[i] = As[kk][ty * 8 + i];
      #pragma unroll
      for (int j = 0; j < 8; ++j) bv[j] = Bs[kk][tx * 8 + j];
      #pragma unroll
      for (int i = 0; i < 8; ++i)
        #pragma unroll
        for (int j = 0; j < 8; ++j) acc[i][j] += av[i] * bv[j];
    }
  }
  #pragma unroll
  for (int i = 0; i < 8; ++i) {
    int m = row0 + ty * 8 + i;
    #pragma unroll
    for (int j = 0; j < 8; j += 4) {
      int n = col0 + tx * 8 + j;
      *(float4*)(out + (size_t)m * 1024 + n) =
          make_float4(acc[i][j] + bias[n], acc[i][j + 1] + bias[n + 1],
                      acc[i][j + 2] + bias[n + 2], acc[i][j + 3] + bias[n + 3]);
    }
  }
}

// ---------------------------------------------------------------------------
extern "C" void kernel_launch(void* const* d_in, const int* in_sizes, int n_in,
                              void* d_out, int out_size, void* d_ws, size_t ws_size,
                              hipStream_t stream) {
  const float* x      = (const float*)d_in[0];
  const float* w_qkv  = (const float*)d_in[1];
  const float* w_proj = (const float*)d_in[2];
  const float* b_proj = (const float*)d_in[3];
  const float* ps_w1  = (const float*)d_in[4];
  const float* ps_b1  = (const float*)d_in[5];
  const float* ln_g   = (const float*)d_in[6];
  const float* ln_b   = (const float*)d_in[7];
  const float* ps_w2  = (const float*)d_in[8];
  const float* ps_b2  = (const float*)d_in[9];
  const float* ps_w3  = (const float*)d_in[10];
  const float* ps_b3  = (const float*)d_in[11];
  const float* pbias  = (const float*)d_in[12];
  // d_in[13]=sparse_w, d_in[14]=sparse_b: monotone per-row affine -> top-k invariant.

  float* ws = (float*)d_ws;
  float* pooled = ws;                        // 4096 f
  int*   meta   = (int*)(ws + 4096);         // 32 i
  float* qw = ws + 262144;                   // 4M f each
  float* kw = qw + 4194304;
  float* vw = kw + 4194304;
  float* ao = vw + 4194304;
  unsigned short* qh_ = (unsigned short*)(ao + 4194304);  // 4M u16 each
  unsigned short* ql_ = qh_ + 4194304;
  unsigned short* kh_ = ql_ + 4194304;
  unsigned short* kl_ = kh_ + 4194304;
  unsigned short* vth_ = kl_ + 4194304;
  unsigned short* vtl_ = vth_ + 4194304;
  float* out = (float*)d_out;

  const size_t NEED = (size_t)(262144 + 4 * 4194304) * 4 + (size_t)6 * 4194304 * 2;
  bool mfma_ok = ws_size >= NEED;

  pool_kernel<<<16, 256, 0, stream>>>(x, pooled);
  pattern_kernel<<<4, 256, 0, stream>>>(pooled, ps_w1, ps_b1, ln_g, ln_b,
                                        ps_w2, ps_b2, ps_w3, ps_b3, pbias, meta);
  qkv_gemm<<<dim3(24, 32), 256, 0, stream>>>(x, w_qkv, qw, kw, vw);
  if (mfma_ok) {
    prep_qk<<<4096, 256, 0, stream>>>(qw, kw, qh_, ql_, kh_, kl_);
    prep_vt<<<dim3(16, 64), 256, 0, stream>>>(vw, vth_, vtl_);
    attn_flash<<<1024, 256, 0, stream>>>(qh_, ql_, kh_, kl_, vth_, vtl_, vw, meta, ao);
    attn_kernel<<<2048, 256, 0, stream>>>(qw, kw, vw, meta, ao, 0);
  } else {
    attn_kernel<<<2048, 256, 0, stream>>>(qw, kw, vw, meta, ao, 1);
  }
  proj_gemm<<<dim3(8, 32), 256, 0, stream>>>(ao, w_proj, b_proj, out);
}

// Round 3
// 428.394 us; speedup vs baseline: 3.5752x; 2.2889x over previous
//
#include <hip/hip_runtime.h>
#include <math.h>

// Problem constants
#define BB_ 4
#define LL_ 1024
#define DD_ 1024
#define HH_ 16
#define HD_ 64
#define KTOP_ 716
#define SCALE_ 0.125f

typedef float f4v __attribute__((ext_vector_type(4)));
typedef short s8v __attribute__((ext_vector_type(8)));
typedef __bf16 bf8v __attribute__((ext_vector_type(8)));

static __device__ inline unsigned short f2bf(float f) {
  unsigned u = __float_as_uint(f);
  u += 0x7fffu + ((u >> 16) & 1u);
  return (unsigned short)(u >> 16);
}
static __device__ inline float bf2f(unsigned short h) {
  return __uint_as_float((unsigned)h << 16);
}
static __device__ inline f4v mfma16(s8v a, s8v b, f4v c) {
  union { s8v s; bf8v b; } ua, ub;
  ua.s = a; ub.s = b;
  return __builtin_amdgcn_mfma_f32_16x16x32_bf16(ua.b, ub.b, c, 0, 0, 0);
}
// async global->LDS, 16B per lane; lbase must be wave-uniform (HW adds lane*16)
static __device__ inline void gload16(const unsigned short* g, unsigned short* lbase) {
  __builtin_amdgcn_global_load_lds(
      (const __attribute__((address_space(1))) unsigned int*)g,
      (__attribute__((address_space(3))) unsigned int*)lbase, 16, 0, 0);
}

// ---------------------------------------------------------------------------
// pool (2-stage)
// ---------------------------------------------------------------------------
__global__ __launch_bounds__(256) void pool1(const float* __restrict__ x,
                                             float* __restrict__ psum,
                                             float* __restrict__ pmax) {
  int bid = blockIdx.x;            // b*64 + sl
  int b = bid >> 6, sl = bid & 63;
  int t = threadIdx.x;
  float s[4] = {0.f, 0.f, 0.f, 0.f};
  float m[4] = {-INFINITY, -INFINITY, -INFINITY, -INFINITY};
  const float* xb = x + ((size_t)b << 20) + (size_t)sl * 16 * 1024;
  for (int l = 0; l < 16; ++l) {
    #pragma unroll
    for (int dg = 0; dg < 4; ++dg) {
      float v = xb[l * 1024 + dg * 256 + t];
      s[dg] += v;
      m[dg] = fmaxf(m[dg], v);
    }
  }
  #pragma unroll
  for (int dg = 0; dg < 4; ++dg) {
    psum[(size_t)bid * 1024 + dg * 256 + t] = s[dg];
    pmax[(size_t)bid * 1024 + dg * 256 + t] = m[dg];
  }
}

__global__ __launch_bounds__(256) void pool2(const float* __restrict__ psum,
                                             const float* __restrict__ pmax,
                                             float* __restrict__ pooled) {
  int bid = blockIdx.x;            // b*4 + dg
  int b = bid >> 2, dg = bid & 3;
  int d = dg * 256 + threadIdx.x;
  float s = 0.f, m = -INFINITY;
  for (int sl = 0; sl < 64; ++sl) {
    s += psum[((size_t)b * 64 + sl) * 1024 + d];
    m = fmaxf(m, pmax[((size_t)b * 64 + sl) * 1024 + d]);
  }
  pooled[b * 1024 + d] = (s * (1.0f / 1024.0f) + m) * 0.5f;
}

// ---------------------------------------------------------------------------
// pattern selector, staged
// ---------------------------------------------------------------------------
__global__ __launch_bounds__(256) void ps_gemv1(const float* __restrict__ pooled,
                                                const float* __restrict__ w1,
                                                const float* __restrict__ b1,
                                                float* __restrict__ h1) {
  int bid = blockIdx.x;            // b*16 + og
  int b = bid >> 4, og = bid & 15;
  int t = threadIdx.x;
  int ol = t >> 2, ks = t & 3;
  int o = og * 64 + ol;
  const float4* wr = (const float4*)(w1 + (size_t)o * 1024 + ks * 256);
  const float4* pp = (const float4*)(pooled + b * 1024 + ks * 256);
  float acc = 0.f;
  #pragma unroll 8
  for (int j = 0; j < 64; ++j) {
    float4 a = wr[j], p = pp[j];
    acc += a.x * p.x + a.y * p.y + a.z * p.z + a.w * p.w;
  }
  acc += __shfl_xor(acc, 1, 64);
  acc += __shfl_xor(acc, 2, 64);
  if (ks == 0) h1[b * 1024 + o] = acc + b1[o];
}

__global__ __launch_bounds__(256) void ps_ln(float* __restrict__ h1,
                                             const float* __restrict__ lng,
                                             const float* __restrict__ lnb) {
  __shared__ float red[256];
  int b = blockIdx.x, t = threadIdx.x;
  float* hb = h1 + b * 1024;
  float v0[4];
  float ls = 0.f;
  #pragma unroll
  for (int i = 0; i < 4; ++i) { v0[i] = hb[t + 256 * i]; ls += v0[i]; }
  red[t] = ls; __syncthreads();
  for (int s = 128; s > 0; s >>= 1) { if (t < s) red[t] += red[t + s]; __syncthreads(); }
  float mean = red[0] * (1.0f / 1024.0f);
  __syncthreads();
  float lq = 0.f;
  #pragma unroll
  for (int i = 0; i < 4; ++i) { float dv = v0[i] - mean; lq += dv * dv; }
  red[t] = lq; __syncthreads();
  for (int s = 128; s > 0; s >>= 1) { if (t < s) red[t] += red[t + s]; __syncthreads(); }
  float rstd = 1.0f / sqrtf(red[0] * (1.0f / 1024.0f) + 1e-5f);
  #pragma unroll
  for (int i = 0; i < 4; ++i) {
    float v = (v0[i] - mean) * rstd * lng[t + 256 * i] + lnb[t + 256 * i];
    hb[t + 256 * i] = 0.5f * v * (1.0f + erff(v * 0.70710678118654752f));
  }
}

__global__ __launch_bounds__(256) void ps_gemv2(const float* __restrict__ h1,
                                                const float* __restrict__ w2,
                                                const float* __restrict__ b2,
                                                float* __restrict__ h2) {
  int bid = blockIdx.x;            // b*8 + og
  int b = bid >> 3, og = bid & 7;
  int t = threadIdx.x;
  int ol = t >> 2, ks = t & 3;
  int o = og * 64 + ol;
  const float4* wr = (const float4*)(w2 + (size_t)o * 1024 + ks * 256);
  const float4* pp = (const float4*)(h1 + b * 1024 + ks * 256);
  float acc = 0.f;
  #pragma unroll 8
  for (int j = 0; j < 64; ++j) {
    float4 a = wr[j], p = pp[j];
    acc += a.x * p.x + a.y * p.y + a.z * p.z + a.w * p.w;
  }
  acc += __shfl_xor(acc, 1, 64);
  acc += __shfl_xor(acc, 2, 64);
  if (ks == 0) {
    float v = acc + b2[o];
    h2[b * 512 + o] = 0.5f * v * (1.0f + erff(v * 0.70710678118654752f));
  }
}

__global__ __launch_bounds__(256) void ps_logits(const float* __restrict__ h2,
                                                 const float* __restrict__ w3,
                                                 const float* __restrict__ b3,
                                                 const float* __restrict__ pb,
                                                 int* __restrict__ meta) {
  __shared__ float red[256];
  int b = blockIdx.x, t = threadIdx.x;
  float lgv[3];
  for (int c = 0; c < 3; ++c) {
    float p = 0.f;
    for (int i = t; i < 512; i += 256) p += h2[b * 512 + i] * w3[c * 512 + i];
    red[t] = p; __syncthreads();
    for (int s = 128; s > 0; s >>= 1) { if (t < s) red[t] += red[t + s]; __syncthreads(); }
    lgv[c] = red[0] + b3[c] + pb[c];
    __syncthreads();
  }
  if (t == 0) {
    float mx = fmaxf(lgv[0], fmaxf(lgv[1], lgv[2]));
    float e0 = __expf(lgv[0] - mx), e1 = __expf(lgv[1] - mx), e2 = __expf(lgv[2] - mx);
    float inv = 1.0f / (e0 + e1 + e2);
    float p0 = e0 * inv, p1 = e1 * inv, p2 = e2 * inv;
    float c00 = p1;
    float c10 = p0 + p1;
    float c01 = p1 + p2;
    float c11 = (p0 + p1) + p2;
    int t00 = c00 > 0.1f, t10 = c10 > 0.1f, t01 = c01 > 0.1f, t11 = c11 > 0.1f;
    meta[b * 8 + 0] = t00;
    meta[b * 8 + 1] = t10;
    meta[b * 8 + 2] = t01;
    meta[b * 8 + 3] = t11;
    meta[b * 8 + 4] = (t00 != t01) || (t10 != t11);
  }
}

// ---------------------------------------------------------------------------
// prep_split: f32 -> interleaved split-bf16 (out[2i]=hi, out[2i+1]=lo)
// ---------------------------------------------------------------------------
__global__ __launch_bounds__(256) void prep_split(const float* __restrict__ in,
                                                  unsigned short* __restrict__ out2,
                                                  int n4) {
  int i = blockIdx.x * 256 + threadIdx.x;
  if (i >= n4) return;
  float4 v = ((const float4*)in)[i];
  float f[4] = {v.x, v.y, v.z, v.w};
  union { s8v v8; unsigned short u[8]; } o;
  #pragma unroll
  for (int j = 0; j < 4; ++j) {
    unsigned short h = f2bf(f[j]);
    o.u[2 * j] = h;
    o.u[2 * j + 1] = f2bf(f[j] - bf2f(h));
  }
  *(s8v*)(out2 + (size_t)i * 8) = o.v8;
}

// ---------------------------------------------------------------------------
// gemm_sp: C[M][N] = A[M][2048] . B[N][2048] (interleaved split-bf16, K'=2048)
// 128x128 tile, BK=64, 4 waves, global_load_lds + XOR-swizzled LDS
// MODE 0: scatter to q/k/v [B,H,L,64] f32   MODE 1: out = C + bias
// ---------------------------------------------------------------------------
template <int MODE>
__global__ __launch_bounds__(256) void gemm_sp(
    const unsigned short* __restrict__ A, const unsigned short* __restrict__ B,
    const float* __restrict__ bias, float* __restrict__ q, float* __restrict__ k2,
    float* __restrict__ v2, float* __restrict__ out, int Nb) {
  __shared__ unsigned short Asm[128 * 64];
  __shared__ unsigned short Bsm[128 * 64];

  int bid = blockIdx.x;
  int cpx = gridDim.x >> 3;                 // blocks per XCD (grid % 8 == 0)
  int g = (bid & 7) * cpx + (bid >> 3);     // XCD-contiguous panels
  int bm = g / Nb, bn = g % Nb;
  size_t row0 = (size_t)bm * 128, col0 = (size_t)bn * 128;

  int tid = threadIdx.x, lane = tid & 63, wv = tid >> 6;
  int wm = (wv >> 1) << 6, wn = (wv & 1) << 6;
  int rowg = lane >> 4, colc = lane & 15;

  f4v acc[4][4];
  #pragma unroll
  for (int mf = 0; mf < 4; ++mf)
    #pragma unroll
    for (int nf = 0; nf < 4; ++nf) acc[mf][nf] = (f4v){0.f, 0.f, 0.f, 0.f};

  const unsigned short* Abase = A + row0 * 2048;
  const unsigned short* Bbase = B + col0 * 2048;

  // per-lane staging source (swizzled chunk so linear-LDS + swizzled read match)
  int sidx0 = tid;                           // pass p adds 256
  for (int kb = 0; kb < 2048; kb += 64) {
    __syncthreads();
    #pragma unroll
    for (int p = 0; p < 4; ++p) {
      int idx = p * 256 + sidx0;             // 0..1023 (16B chunks)
      int row = idx >> 3;
      int ch = idx & 7;
      int sc = ch ^ (row & 7);
      unsigned short* la = &Asm[(size_t)(p * 256 + wv * 64) * 8];
      unsigned short* lb = &Bsm[(size_t)(p * 256 + wv * 64) * 8];
      gload16(Abase + (size_t)row * 2048 + kb + sc * 8, la);
      gload16(Bbase + (size_t)row * 2048 + kb + sc * 8, lb);
    }
    __syncthreads();
    #pragma unroll
    for (int ks = 0; ks < 2; ++ks) {
      s8v af[4], bf_[4];
      #pragma unroll
      for (int mf = 0; mf < 4; ++mf) {
        int row = wm + mf * 16 + colc;
        int kby = (ks * 64 + rowg * 16) ^ ((row & 7) << 4);
        af[mf] = *(const s8v*)((const char*)Asm + row * 128 + kby);
      }
      #pragma unroll
      for (int nf = 0; nf < 4; ++nf) {
        int row = wn + nf * 16 + colc;
        int kby = (ks * 64 + rowg * 16) ^ ((row & 7) << 4);
        bf_[nf] = *(const s8v*)((const char*)Bsm + row * 128 + kby);
      }
      #pragma unroll
      for (int mf = 0; mf < 4; ++mf)
        #pragma unroll
        for (int nf = 0; nf < 4; ++nf)
          acc[mf][nf] = mfma16(af[mf], bf_[nf], acc[mf][nf]);
    }
  }

  #pragma unroll
  for (int mf = 0; mf < 4; ++mf) {
    #pragma unroll
    for (int r = 0; r < 4; ++r) {
      int m = (int)row0 + wm + mf * 16 + rowg * 4 + r;
      #pragma unroll
      for (int nf = 0; nf < 4; ++nf) {
        int n = (int)col0 + wn + nf * 16 + colc;
        float val = acc[mf][nf][r];
        if (MODE == 0) {
          int bb = m >> 10, l = m & 1023;
          int c = n >> 10, hh = (n >> 6) & 15, hd = n & 63;
          float* base = (c == 0) ? q : (c == 1) ? k2 : v2;
          base[((size_t)(bb * 16 + hh) * 1024 + l) * 64 + hd] = val;
        } else {
          out[(size_t)m * 1024 + n] = val + bias[n];
        }
      }
    }
  }
}

// ---------------------------------------------------------------------------
// prep_qk / prep_vt (attention operand prep, unchanged)
// ---------------------------------------------------------------------------
__global__ __launch_bounds__(256) void prep_qk(const float* __restrict__ qw,
                                               const float* __restrict__ kw,
                                               unsigned short* __restrict__ qh,
                                               unsigned short* __restrict__ ql,
                                               unsigned short* __restrict__ kh,
                                               unsigned short* __restrict__ kl) {
  int i4 = blockIdx.x * 256 + threadIdx.x;
  float4 q = ((const float4*)qw)[i4];
  float4 k = ((const float4*)kw)[i4];
  float qf[4] = {q.x * SCALE_, q.y * SCALE_, q.z * SCALE_, q.w * SCALE_};
  float kf[4] = {k.x, k.y, k.z, k.w};
  ushort4 qh4, ql4, kh4, kl4;
  unsigned short* qhp = (unsigned short*)&qh4;
  unsigned short* qlp = (unsigned short*)&ql4;
  unsigned short* khp = (unsigned short*)&kh4;
  unsigned short* klp = (unsigned short*)&kl4;
  #pragma unroll
  for (int i = 0; i < 4; ++i) {
    unsigned short h = f2bf(qf[i]);
    qhp[i] = h; qlp[i] = f2bf(qf[i] - bf2f(h));
    unsigned short h2 = f2bf(kf[i]);
    khp[i] = h2; klp[i] = f2bf(kf[i] - bf2f(h2));
  }
  *(ushort4*)(qh + 4 * (size_t)i4) = qh4;
  *(ushort4*)(ql + 4 * (size_t)i4) = ql4;
  *(ushort4*)(kh + 4 * (size_t)i4) = kh4;
  *(ushort4*)(kl + 4 * (size_t)i4) = kl4;
}

__global__ __launch_bounds__(256) void prep_vt(const float* __restrict__ vw,
                                               unsigned short* __restrict__ vth,
                                               unsigned short* __restrict__ vtl) {
  __shared__ float t[64][65];
  int bh = blockIdx.y;
  int l0 = blockIdx.x * 64;
  int tid = threadIdx.x;
  int lr = tid >> 4, dc = (tid & 15) * 4;
  #pragma unroll
  for (int it = 0; it < 4; ++it) {
    int ll = lr + it * 16;
    float4 v = *(const float4*)(vw + ((size_t)bh * 1024 + l0 + ll) * 64 + dc);
    t[dc + 0][ll] = v.x; t[dc + 1][ll] = v.y; t[dc + 2][ll] = v.z; t[dc + 3][ll] = v.w;
  }
  __syncthreads();
  int d = tid >> 2, lc = (tid & 3) * 16;
  unsigned short* dsth = vth + ((size_t)bh * 64 + d) * 1024 + l0 + lc;
  unsigned short* dstl = vtl + ((size_t)bh * 64 + d) * 1024 + l0 + lc;
  #pragma unroll
  for (int i = 0; i < 16; i += 4) {
    ushort4 h4, l4;
    unsigned short* hp = (unsigned short*)&h4;
    unsigned short* lp = (unsigned short*)&l4;
    #pragma unroll
    for (int jj = 0; jj < 4; ++jj) {
      float f = t[d][lc + i + jj];
      unsigned short h = f2bf(f);
      hp[jj] = h; lp[jj] = f2bf(f - bf2f(h));
    }
    *(ushort4*)(dsth + i) = h4;
    *(ushort4*)(dstl + i) = l4;
  }
}

// ---------------------------------------------------------------------------
// attn_flash (unchanged from R2)
// ---------------------------------------------------------------------------
__global__ __launch_bounds__(256) void attn_flash(
    const unsigned short* __restrict__ qh, const unsigned short* __restrict__ ql,
    const unsigned short* __restrict__ kh, const unsigned short* __restrict__ kl,
    const unsigned short* __restrict__ vth, const unsigned short* __restrict__ vtl,
    const float* __restrict__ vw, const int* __restrict__ meta,
    float* __restrict__ ao) {
  int n = blockIdx.x;
  int bh = ((n & 7) << 3) | (n >> 7);
  int qt = (n >> 3) & 15;
  int b = bh >> 4, h = bh & 15;
  const int* mb = meta + b * 8;
  if (mb[4]) return;
  int t00 = mb[0], t10 = mb[1];

  int tid = threadIdx.x, lane = tid & 63, wv = tid >> 6;
  int rowg = lane >> 4, colc = lane & 15;
  int q0 = qt * 64 + wv * 16;

  if (!t10) {
    #pragma unroll
    for (int it = 0; it < 4; ++it) {
      int idx = tid + it * 256;
      int r = idx >> 4, dc = (idx & 15) * 4;
      float4 v = *(const float4*)(vw + ((size_t)bh * 1024 + qt * 64 + r) * 64 + dc);
      *(float4*)(ao + ((size_t)b * 1024 + qt * 64 + r) * 1024 + h * 64 + dc) = v;
    }
    return;
  }
  bool local_only = !t00;

  __shared__ unsigned short pls[4][2][16][72];

  const unsigned short* qb_h = qh + ((size_t)bh * 1024 + q0 + colc) * 64 + rowg * 8;
  const unsigned short* qb_l = ql + ((size_t)bh * 1024 + q0 + colc) * 64 + rowg * 8;
  s8v Qh[2], Ql[2];
  Qh[0] = *(const s8v*)(qb_h);      Qh[1] = *(const s8v*)(qb_h + 32);
  Ql[0] = *(const s8v*)(qb_l);      Ql[1] = *(const s8v*)(qb_l + 32);

  f4v O[4];
  #pragma unroll
  for (int df = 0; df < 4; ++df) O[df] = (f4v){0.f, 0.f, 0.f, 0.f};
  float m[4] = {-1e30f, -1e30f, -1e30f, -1e30f};
  float lsum[4] = {0.f, 0.f, 0.f, 0.f};

  const unsigned short* vbh_base = vth + ((size_t)bh * 64 + colc) * 1024;
  const unsigned short* vbl_base = vtl + ((size_t)bh * 64 + colc) * 1024;

  for (int jb = 0; jb < 16; ++jb) {
    int jc0 = jb * 64;
    if (local_only && (jc0 + 63 < q0 - 16 || jc0 > q0 + 31)) continue;

    f4v s[4];
    const unsigned short* kb_h = kh + ((size_t)bh * 1024 + jc0 + colc) * 64 + rowg * 8;
    const unsigned short* kb_l = kl + ((size_t)bh * 1024 + jc0 + colc) * 64 + rowg * 8;
    #pragma unroll
    for (int jf = 0; jf < 4; ++jf) {
      f4v acc = (f4v){0.f, 0.f, 0.f, 0.f};
      const unsigned short* ph_ = kb_h + jf * 16 * 64;
      const unsigned short* pl_ = kb_l + jf * 16 * 64;
      s8v Kh0 = *(const s8v*)(ph_);
      s8v Kh1 = *(const s8v*)(ph_ + 32);
      s8v Kl0 = *(const s8v*)(pl_);
      s8v Kl1 = *(const s8v*)(pl_ + 32);
      acc = mfma16(Qh[0], Kh0, acc);
      acc = mfma16(Qh[1], Kh1, acc);
      acc = mfma16(Qh[0], Kl0, acc);
      acc = mfma16(Qh[1], Kl1, acc);
      acc = mfma16(Ql[0], Kh0, acc);
      acc = mfma16(Ql[1], Kh1, acc);
      s[jf] = acc;
    }

    float cm[4] = {-1e30f, -1e30f, -1e30f, -1e30f};
    #pragma unroll
    for (int jf = 0; jf < 4; ++jf) {
      #pragma unroll
      for (int r = 0; r < 4; ++r) {
        float sv = s[jf][r];
        if (local_only) {
          int i = q0 + rowg * 4 + r;
          int j = jc0 + jf * 16 + colc;
          int dj = i - j;
          if (dj > 16 || dj < -16) { sv = -1e30f; s[jf][r] = sv; }
        }
        cm[r] = fmaxf(cm[r], sv);
      }
    }
    #pragma unroll
    for (int off = 1; off < 16; off <<= 1) {
      #pragma unroll
      for (int r = 0; r < 4; ++r) cm[r] = fmaxf(cm[r], __shfl_xor(cm[r], off, 64));
    }

    float fac[4], psum[4];
    #pragma unroll
    for (int r = 0; r < 4; ++r) {
      float mn = fmaxf(m[r], cm[r]);
      fac[r] = __expf(m[r] - mn);
      m[r] = mn;
      psum[r] = 0.f;
    }

    #pragma unroll
    for (int jf = 0; jf < 4; ++jf) {
      #pragma unroll
      for (int r = 0; r < 4; ++r) {
        float sv = s[jf][r];
        float p = (sv > -1e29f) ? __expf(sv - m[r]) : 0.f;
        psum[r] += p;
        unsigned short ph = f2bf(p);
        unsigned short pl = f2bf(p - bf2f(ph));
        pls[wv][0][rowg * 4 + r][jf * 16 + colc] = ph;
        pls[wv][1][rowg * 4 + r][jf * 16 + colc] = pl;
      }
    }
    #pragma unroll
    for (int off = 1; off < 16; off <<= 1) {
      #pragma unroll
      for (int r = 0; r < 4; ++r) psum[r] += __shfl_xor(psum[r], off, 64);
    }
    #pragma unroll
    for (int r = 0; r < 4; ++r) lsum[r] = lsum[r] * fac[r] + psum[r];
    #pragma unroll
    for (int df = 0; df < 4; ++df) {
      #pragma unroll
      for (int r = 0; r < 4; ++r) O[df][r] *= fac[r];
    }

    s8v Ph[2], Pl[2];
    #pragma unroll
    for (int ks = 0; ks < 2; ++ks) {
      Ph[ks] = *(const s8v*)((const void*)&pls[wv][0][colc][ks * 32 + rowg * 8]);
      Pl[ks] = *(const s8v*)((const void*)&pls[wv][1][colc][ks * 32 + rowg * 8]);
    }
    #pragma unroll
    for (int df = 0; df < 4; ++df) {
      const unsigned short* vph = vbh_base + (size_t)df * 16 * 1024 + jc0 + rowg * 8;
      const unsigned short* vpl = vbl_base + (size_t)df * 16 * 1024 + jc0 + rowg * 8;
      #pragma unroll
      for (int ks = 0; ks < 2; ++ks) {
        s8v Vh = *(const s8v*)(vph + ks * 32);
        s8v Vl = *(const s8v*)(vpl + ks * 32);
        O[df] = mfma16(Ph[ks], Vh, O[df]);
        O[df] = mfma16(Ph[ks], Vl, O[df]);
        O[df] = mfma16(Pl[ks], Vh, O[df]);
      }
    }
  }

  float inv[4];
  #pragma unroll
  for (int r = 0; r < 4; ++r) inv[r] = 1.0f / lsum[r];
  #pragma unroll
  for (int df = 0; df < 4; ++df) {
    #pragma unroll
    for (int r = 0; r < 4; ++r) {
      int i = q0 + rowg * 4 + r;
      ao[((size_t)b * 1024 + i) * 1024 + h * 64 + df * 16 + colc] = O[df][r] * inv[r];
    }
  }
}

// ---------------------------------------------------------------------------
// attn_kernel fallback (sparse top-k regime or small-ws force path)
// ---------------------------------------------------------------------------
__global__ __launch_bounds__(256) void attn_kernel(const float* __restrict__ qw,
                                                   const float* __restrict__ kw,
                                                   const float* __restrict__ vw,
                                                   const int* __restrict__ meta,
                                                   float* __restrict__ ao,
                                                   int force) {
  __shared__ float S[32][1028];
  __shared__ float qs[32][68];
  __shared__ float kc[64][68];
  __shared__ float rowsum_s[32];

  int tid = threadIdx.x;
  int lane = tid & 63;
  int wv = tid >> 6;
  int id = blockIdx.x;
  int rt = id & 31;
  int h = (id >> 5) & 15;
  int b = id >> 9;
  int bh = b * 16 + h;
  int row0 = rt * 32;

  const int* mb = meta + b * 8;
  int t00 = mb[0], t10 = mb[1], t01 = mb[2], t11 = mb[3], needs = mb[4];
  if (!force && !needs) return;

  {
    const float4* qp = (const float4*)(qw + ((size_t)bh * 1024 + row0 + wv * 8) * 64);
    #pragma unroll
    for (int i = 0; i < 2; ++i) {
      int f = lane + 64 * i;
      float4 v = qp[f];
      int r = wv * 8 + (f >> 4);
      int d = (f & 15) << 2;
      qs[r][d] = v.x; qs[r][d + 1] = v.y; qs[r][d + 2] = v.z; qs[r][d + 3] = v.w;
    }
  }

  int lr = lane >> 4, lc = lane & 15;
  int r_a = wv * 8 + lr * 2;
  int r_b = r_a + 1;

  for (int cb = 0; cb < 16; ++cb) {
    __syncthreads();
    const float4* kp = (const float4*)(kw + ((size_t)bh * 1024 + cb * 64) * 64);
    #pragma unroll
    for (int i = 0; i < 4; ++i) {
      int f = tid + 256 * i;
      float4 v = kp[f];
      int c = f >> 4, d = (f & 15) << 2;
      kc[c][d] = v.x; kc[c][d + 1] = v.y; kc[c][d + 2] = v.z; kc[c][d + 3] = v.w;
    }
    __syncthreads();

    float acc0[4] = {0.f, 0.f, 0.f, 0.f};
    float acc1[4] = {0.f, 0.f, 0.f, 0.f};
    for (int dq = 0; dq < 64; dq += 4) {
      float4 qa = *(const float4*)&qs[r_a][dq];
      float4 qb = *(const float4*)&qs[r_b][dq];
      #pragma unroll
      for (int cj = 0; cj < 4; ++cj) {
        float4 kv = *(const float4*)&kc[lc + 16 * cj][dq];
        acc0[cj] += qa.x * kv.x + qa.y * kv.y + qa.z * kv.z + qa.w * kv.w;
        acc1[cj] += qb.x * kv.x + qb.y * kv.y + qb.z * kv.z + qb.w * kv.w;
      }
    }
    #pragma unroll
    for (int cj = 0; cj < 4; ++cj) {
      S[r_a][cb * 64 + lc + 16 * cj] = acc0[cj] * SCALE_;
      S[r_b][cb * 64 + lc + 16 * cj] = acc1[cj] * SCALE_;
    }
  }

  for (int rr = 0; rr < 8; ++rr) {
    int r = wv * 8 + rr;
    int grow = row0 + r;
    float sv[16];
    unsigned kv[16];
    #pragma unroll
    for (int i2 = 0; i2 < 16; ++i2) {
      float s = S[r][lane + 64 * i2];
      sv[i2] = s;
      unsigned u = __float_as_uint(s);
      kv[i2] = (u & 0x80000000u) ? ~u : (u | 0x80000000u);
    }
    unsigned T = 0u;
    if (needs) {
      for (int bit = 31; bit >= 0; --bit) {
        unsigned cand = T | (1u << bit);
        int cnt = 0;
        #pragma unroll
        for (int i2 = 0; i2 < 16; ++i2) cnt += (kv[i2] >= cand) ? 1 : 0;
        for (int off = 32; off; off >>= 1) cnt += __shfl_xor(cnt, off, 64);
        if (cnt >= KTOP_) T = cand;
      }
    }
    float mx = -INFINITY;
    int kept = 0;
    unsigned kmask = 0;
    #pragma unroll
    for (int i2 = 0; i2 < 16; ++i2) {
      int j = lane + 64 * i2;
      int sp = (kv[i2] >= T) ? 1 : 0;
      int dj = grow - j;
      int lo = (dj <= 16 && dj >= -16) ? 1 : 0;
      int keep = sp ? (lo ? t11 : t01) : (lo ? t10 : t00);
      kept += keep;
      if (keep) { kmask |= (1u << i2); mx = fmaxf(mx, sv[i2]); }
    }
    for (int off = 32; off; off >>= 1) {
      mx = fmaxf(mx, __shfl_xor(mx, off, 64));
      kept += __shfl_xor(kept, off, 64);
    }
    if (kept == 0) {
      #pragma unroll
      for (int i2 = 0; i2 < 16; ++i2) {
        int j = lane + 64 * i2;
        S[r][j] = (j == grow) ? 1.0f : 0.0f;
      }
      if (lane == 0) rowsum_s[r] = 1.0f;
    } else {
      float sum = 0.f;
      #pragma unroll
      for (int i2 = 0; i2 < 16; ++i2) {
        float p = ((kmask >> i2) & 1u) ? __expf(sv[i2] - mx) : 0.0f;
        sum += p;
        S[r][lane + 64 * i2] = p;
      }
      for (int off = 32; off; off >>= 1) sum += __shfl_xor(sum, off, 64);
      if (lane == 0) rowsum_s[r] = sum;
    }
  }

  int ld = lane & 15;
  int d0 = ld * 4;
  float4 oa0 = make_float4(0.f, 0.f, 0.f, 0.f);
  float4 oa1 = make_float4(0.f, 0.f, 0.f, 0.f);
  for (int vb = 0; vb < 16; ++vb) {
    __syncthreads();
    const float4* vp = (const float4*)(vw + ((size_t)bh * 1024 + vb * 64) * 64);
    #pragma unroll
    for (int i = 0; i < 4; ++i) {
      int f = tid + 256 * i;
      float4 v = vp[f];
      int c = f >> 4, d = (f & 15) << 2;
      kc[c][d] = v.x; kc[c][d + 1] = v.y; kc[c][d + 2] = v.z; kc[c][d + 3] = v.w;
    }
    __syncthreads();
    for (int cq = 0; cq < 64; cq += 4) {
      float4 pa = *(const float4*)&S[r_a][vb * 64 + cq];
      float4 pb = *(const float4*)&S[r_b][vb * 64 + cq];
      float par[4] = {pa.x, pa.y, pa.z, pa.w};
      float pbr[4] = {pb.x, pb.y, pb.z, pb.w};
      #pragma unroll
      for (int tt = 0; tt < 4; ++tt) {
        float4 vv = *(const float4*)&kc[cq + tt][d0];
        oa0.x += par[tt] * vv.x; oa0.y += par[tt] * vv.y;
        oa0.z += par[tt] * vv.z; oa0.w += par[tt] * vv.w;
        oa1.x += pbr[tt] * vv.x; oa1.y += pbr[tt] * vv.y;
        oa1.z += pbr[tt] * vv.z; oa1.w += pbr[tt] * vv.w;
      }
    }
  }
  float inv0 = 1.0f / rowsum_s[r_a];
  float inv1 = 1.0f / rowsum_s[r_b];
  float* o0 = ao + ((size_t)b * 1024 + row0 + r_a) * 1024 + h * 64 + d0;
  float* o1 = ao + ((size_t)b * 1024 + row0 + r_b) * 1024 + h * 64 + d0;
  *(float4*)o0 = make_float4(oa0.x * inv0, oa0.y * inv0, oa0.z * inv0, oa0.w * inv0);
  *(float4*)o1 = make_float4(oa1.x * inv1, oa1.y * inv1, oa1.z * inv1, oa1.w * inv1);
}

// ---------------------------------------------------------------------------
// Fallback f32 kernels (small-ws path only)
// ---------------------------------------------------------------------------
__global__ __launch_bounds__(256) void pool_kernel(const float* __restrict__ x,
                                                   float* __restrict__ pooled) {
  int g = blockIdx.x * 256 + threadIdx.x;
  int b = g >> 10, d = g & 1023;
  const float* xp = x + ((size_t)b << 20) + d;
  float s = 0.f, m = -INFINITY;
  #pragma unroll 4
  for (int l = 0; l < LL_; ++l) {
    float v = xp[(size_t)l << 10];
    s += v;
    m = fmaxf(m, v);
  }
  pooled[g] = (s * (1.0f / 1024.0f) + m) * 0.5f;
}

__global__ __launch_bounds__(256) void qkv_gemm(const float* __restrict__ X,
                                                const float* __restrict__ W,
                                                float* __restrict__ qw,
                                                float* __restrict__ kw,
                                                float* __restrict__ vw) {
  __shared__ float As[8][128];
  __shared__ float Bs[8][128];
  int tid = threadIdx.x;
  int row0 = blockIdx.y * 128, col0 = blockIdx.x * 128;
  int lr = tid >> 1;
  int lk = (tid & 1) * 4;
  int ty = tid >> 4, tx = tid & 15;
  float acc[8][8] = {};

  for (int kb = 0; kb < 1024; kb += 8) {
    float4 a4 = *(const float4*)(X + (size_t)(row0 + lr) * 1024 + kb + lk);
    float4 b4 = *(const float4*)(W + (size_t)(col0 + lr) * 1024 + kb + lk);
    __syncthreads();
    As[lk + 0][lr] = a4.x; As[lk + 1][lr] = a4.y; As[lk + 2][lr] = a4.z; As[lk + 3][lr] = a4.w;
    Bs[lk + 0][lr] = b4.x; Bs[lk + 1][lr] = b4.y; Bs[lk + 2][lr] = b4.z; Bs[lk + 3][lr] = b4.w;
    __syncthreads();
    #pragma unroll
    for (int kk = 0; kk < 8; ++kk) {
      float av[8], bv[8];
      #pragma unroll
      for (int i = 0; i < 8; ++i) av[i] = As[kk][ty * 8 + i];
      #pragma unroll
      for (int j = 0; j < 8; ++j) bv[j] = Bs[kk][tx * 8 + j];
      #pragma unroll
      for (int i = 0; i < 8; ++i)
        #pragma unroll
        for (int j = 0; j < 8; ++j) acc[i][j] += av[i] * bv[j];
    }
  }
  #pragma unroll
  for (int i = 0; i < 8; ++i) {
    int m = row0 + ty * 8 + i;
    int bb = m >> 10, l = m & 1023;
    #pragma unroll
    for (int j = 0; j < 8; j += 4) {
      int n = col0 + tx * 8 + j;
      int c = n >> 10;
      int hh = (n >> 6) & 15;
      int hd = n & 63;
      float* base = (c == 0) ? qw : (c == 1) ? kw : vw;
      float* dst = base + ((size_t)(bb * 16 + hh) * 1024 + l) * 64 + hd;
      *(float4*)dst = make_float4(acc[i][j], acc[i][j + 1], acc[i][j + 2], acc[i][j + 3]);
    }
  }
}

__global__ __launch_bounds__(256) void proj_gemm(const float* __restrict__ A,
                                                 const float* __restrict__ W,
                                                 const float* __restrict__ bias,
                                                 float* __restrict__ out) {
  __shared__ float As[8][128];
  __shared__ float Bs[8][128];
  int tid = threadIdx.x;
  int row0 = blockIdx.y * 128, col0 = blockIdx.x * 128;
  int lr = tid >> 1;
  int lk = (tid & 1) * 4;
  int ty = tid >> 4, tx = tid & 15;
  float acc[8][8] = {};

  for (int kb = 0; kb < 1024; kb += 8) {
    float4 a4 = *(const float4*)(A + (size_t)(row0 + lr) * 1024 + kb + lk);
    float4 b4 = *(const float4*)(W + (size_t)(col0 + lr) * 1024 + kb + lk);
    __syncthreads();
    As[lk + 0][lr] = a4.x; As[lk + 1][lr] = a4.y; As[lk + 2][lr] = a4.z; As[lk + 3][lr] = a4.w;
    Bs[lk + 0][lr] = b4.x; Bs[lk + 1][lr] = b4.y; Bs[lk + 2][lr] = b4.z; Bs[lk + 3][lr] = b4.w;
    __syncthreads();
    #pragma unroll
    for (int kk = 0; kk < 8; ++kk) {
      float av[8], bv[8];
      #pragma unroll
      for (int i = 0; i < 8; ++i) av[i] = As[kk][ty * 8 + i];
      #pragma unroll
      for (int j = 0; j < 8; ++j) bv[j] = Bs[kk][tx * 8 + j];
      #pragma unroll
      for (int i = 0; i < 8; ++i)
        #pragma unroll
        for (int j = 0; j < 8; ++j) acc[i][j] += av[i] * bv[j];
    }
  }
  #pragma unroll
  for (int i = 0; i < 8; ++i) {
    int m = row0 + ty * 8 + i;
    #pragma unroll
    for (int j = 0; j < 8; j += 4) {
      int n = col0 + tx * 8 + j;
      *(float4*)(out + (size_t)m * 1024 + n) =
          make_float4(acc[i][j] + bias[n], acc[i][j + 1] + bias[n + 1],
                      acc[i][j + 2] + bias[n + 2], acc[i][j + 3] + bias[n + 3]);
    }
  }
}

__global__ __launch_bounds__(256) void pattern_kernel(
    const float* __restrict__ pooled,
    const float* __restrict__ w1, const float* __restrict__ b1,
    const float* __restrict__ lng, const float* __restrict__ lnb,
    const float* __restrict__ w2, const float* __restrict__ b2,
    const float* __restrict__ w3, const float* __restrict__ b3,
    const float* __restrict__ pb, int* __restrict__ meta) {
  __shared__ float pool_s[1024];
  __shared__ float h1[1024];
  __shared__ float h2[512];
  __shared__ float red[256];
  int b = blockIdx.x, t = threadIdx.x;

  for (int i = t; i < 1024; i += 256) pool_s[i] = pooled[b * 1024 + i];
  __syncthreads();
  for (int o = t; o < 1024; o += 256) {
    float acc = b1[o];
    const float* wr = w1 + (size_t)o * 1024;
    for (int k = 0; k < 1024; ++k) acc += pool_s[k] * wr[k];
    h1[o] = acc;
  }
  __syncthreads();
  float ls = 0.f;
  for (int i = t; i < 1024; i += 256) ls += h1[i];
  red[t] = ls; __syncthreads();
  for (int s = 128; s > 0; s >>= 1) { if (t < s) red[t] += red[t + s]; __syncthreads(); }
  float mean = red[0] * (1.0f / 1024.0f);
  __syncthreads();
  float lq = 0.f;
  for (int i = t; i < 1024; i += 256) { float dv = h1[i] - mean; lq += dv * dv; }
  red[t] = lq; __syncthreads();
  for (int s = 128; s > 0; s >>= 1) { if (t < s) red[t] += red[t + s]; __syncthreads(); }
  float var = red[0] * (1.0f / 1024.0f);
  float rstd = 1.0f / sqrtf(var + 1e-5f);
  __syncthreads();
  for (int i = t; i < 1024; i += 256) {
    float v = (h1[i] - mean) * rstd * lng[i] + lnb[i];
    h1[i] = 0.5f * v * (1.0f + erff(v * 0.70710678118654752f));
  }
  __syncthreads();
  for (int o = t; o < 512; o += 256) {
    float acc = b2[o];
    const float* wr = w2 + (size_t)o * 1024;
    for (int k = 0; k < 1024; ++k) acc += h1[k] * wr[k];
    h2[o] = 0.5f * acc * (1.0f + erff(acc * 0.70710678118654752f));
  }
  __syncthreads();
  float lgv[3];
  for (int c = 0; c < 3; ++c) {
    float p = 0.f;
    for (int i = t; i < 512; i += 256) p += h2[i] * w3[c * 512 + i];
    __syncthreads();
    red[t] = p; __syncthreads();
    for (int s = 128; s > 0; s >>= 1) { if (t < s) red[t] += red[t + s]; __syncthreads(); }
    lgv[c] = red[0] + b3[c] + pb[c];
  }
  if (t == 0) {
    float mx = fmaxf(lgv[0], fmaxf(lgv[1], lgv[2]));
    float e0 = __expf(lgv[0] - mx), e1 = __expf(lgv[1] - mx), e2 = __expf(lgv[2] - mx);
    float inv = 1.0f / (e0 + e1 + e2);
    float p0 = e0 * inv, p1 = e1 * inv, p2 = e2 * inv;
    float c00 = p1;
    float c10 = p0 + p1;
    float c01 = p1 + p2;
    float c11 = (p0 + p1) + p2;
    int t00 = c00 > 0.1f, t10 = c10 > 0.1f, t01 = c01 > 0.1f, t11 = c11 > 0.1f;
    meta[b * 8 + 0] = t00;
    meta[b * 8 + 1] = t10;
    meta[b * 8 + 2] = t01;
    meta[b * 8 + 3] = t11;
    meta[b * 8 + 4] = (t00 != t01) || (t10 != t11);
  }
}

// ---------------------------------------------------------------------------
extern "C" void kernel_launch(void* const* d_in, const int* in_sizes, int n_in,
                              void* d_out, int out_size, void* d_ws, size_t ws_size,
                              hipStream_t stream) {
  const float* x      = (const float*)d_in[0];
  const float* w_qkv  = (const float*)d_in[1];
  const float* w_proj = (const float*)d_in[2];
  const float* b_proj = (const float*)d_in[3];
  const float* ps_w1  = (const float*)d_in[4];
  const float* ps_b1  = (const float*)d_in[5];
  const float* ln_g   = (const float*)d_in[6];
  const float* ln_b   = (const float*)d_in[7];
  const float* ps_w2  = (const float*)d_in[8];
  const float* ps_b2  = (const float*)d_in[9];
  const float* ps_w3  = (const float*)d_in[10];
  const float* ps_b3  = (const float*)d_in[11];
  const float* pbias  = (const float*)d_in[12];
  // d_in[13]=sparse_w, d_in[14]=sparse_b: monotone per-row affine -> top-k invariant.

  float* ws = (float*)d_ws;
  float* pooled = ws;                              // 4096
  int*   meta   = (int*)(ws + 4096);               // 32
  float* h1buf  = ws + 8192;                       // 4096
  float* h2buf  = ws + 12288;                      // 2048
  float* ppsum  = ws + 16384;                      // 262144
  float* ppmax  = ws + 278528;                     // 262144
  float* qw = ws + 1048576;                        // 4M each
  float* kw = qw + 4194304;
  float* vw = kw + 4194304;
  float* ao = vw + 4194304;
  unsigned short* u16b = (unsigned short*)(ao + 4194304);
  unsigned short* qh_  = u16b;                     // 4M u16 each
  unsigned short* ql_  = qh_ + 4194304;
  unsigned short* kh_  = ql_ + 4194304;
  unsigned short* kl_  = kh_ + 4194304;
  unsigned short* vth_ = kl_ + 4194304;
  unsigned short* vtl_ = vth_ + 4194304;
  unsigned short* xs   = vtl_ + 4194304;           // [4096][2048]
  unsigned short* wqs  = xs + 8388608;             // [3072][2048]
  unsigned short* wps  = wqs + 6291456;            // [1024][2048]
  unsigned short* aos  = wps + 2097152;            // [4096][2048]
  float* out = (float*)d_out;

  const size_t NEED_FULL = (size_t)(1048576 + 4 * 4194304) * 4 +
                           (size_t)(6 * 4194304 + 8388608 + 6291456 + 2097152 + 8388608) * 2;

  if (ws_size >= NEED_FULL) {
    pool1<<<256, 256, 0, stream>>>(x, ppsum, ppmax);
    pool2<<<16, 256, 0, stream>>>(ppsum, ppmax, pooled);
    ps_gemv1<<<64, 256, 0, stream>>>(pooled, ps_w1, ps_b1, h1buf);
    ps_ln<<<4, 256, 0, stream>>>(h1buf, ln_g, ln_b);
    ps_gemv2<<<32, 256, 0, stream>>>(h1buf, ps_w2, ps_b2, h2buf);
    ps_logits<<<4, 256, 0, stream>>>(h2buf, ps_w3, ps_b3, pbias, meta);

    prep_split<<<4096, 256, 0, stream>>>(x, xs, 1048576);
    prep_split<<<3072, 256, 0, stream>>>(w_qkv, wqs, 786432);
    prep_split<<<1024, 256, 0, stream>>>(w_proj, wps, 262144);
    gemm_sp<0><<<768, 256, 0, stream>>>(xs, wqs, nullptr, qw, kw, vw, nullptr, 24);

    prep_qk<<<4096, 256, 0, stream>>>(qw, kw, qh_, ql_, kh_, kl_);
    prep_vt<<<dim3(16, 64), 256, 0, stream>>>(vw, vth_, vtl_);
    attn_flash<<<1024, 256, 0, stream>>>(qh_, ql_, kh_, kl_, vth_, vtl_, vw, meta, ao);
    attn_kernel<<<2048, 256, 0, stream>>>(qw, kw, vw, meta, ao, 0);

    prep_split<<<4096, 256, 0, stream>>>(ao, aos, 1048576);
    gemm_sp<1><<<256, 256, 0, stream>>>(aos, wps, b_proj, nullptr, nullptr, nullptr, out, 8);
  } else {
    // fallback: f32 path (needs only qw..ao region)
    pool_kernel<<<16, 256, 0, stream>>>(x, pooled);
    pattern_kernel<<<4, 256, 0, stream>>>(pooled, ps_w1, ps_b1, ln_g, ln_b,
                                          ps_w2, ps_b2, ps_w3, ps_b3, pbias, meta);
    qkv_gemm<<<dim3(24, 32), 256, 0, stream>>>(x, w_qkv, qw, kw, vw);
    attn_kernel<<<2048, 256, 0, stream>>>(qw, kw, vw, meta, ao, 1);
    proj_gemm<<<dim3(8, 32), 256, 0, stream>>>(ao, w_proj, b_proj, out);
  }
}

// Round 4
// 420.983 us; speedup vs baseline: 3.6381x; 1.0176x over previous
//
#include <hip/hip_runtime.h>
#include <math.h>

// Problem constants
#define BB_ 4
#define LL_ 1024
#define DD_ 1024
#define HH_ 16
#define HD_ 64
#define KTOP_ 716
#define SCALE_ 0.125f
#define QSCALE_ 0.1803368801111731f   // 0.125 * log2(e): softmax in exp2 domain

typedef float f4v __attribute__((ext_vector_type(4)));
typedef short s8v __attribute__((ext_vector_type(8)));
typedef __bf16 bf8v __attribute__((ext_vector_type(8)));

static __device__ inline unsigned short f2bf(float f) {
  unsigned u = __float_as_uint(f);
  u += 0x7fffu + ((u >> 16) & 1u);
  return (unsigned short)(u >> 16);
}
static __device__ inline float bf2f(unsigned short h) {
  return __uint_as_float((unsigned)h << 16);
}
static __device__ inline f4v mfma16(s8v a, s8v b, f4v c) {
  union { s8v s; bf8v b; } ua, ub;
  ua.s = a; ub.s = b;
  return __builtin_amdgcn_mfma_f32_16x16x32_bf16(ua.b, ub.b, c, 0, 0, 0);
}
static __device__ inline void gload16(const unsigned short* g, unsigned short* lbase) {
  __builtin_amdgcn_global_load_lds(
      (const __attribute__((address_space(1))) unsigned int*)g,
      (__attribute__((address_space(3))) unsigned int*)lbase, 16, 0, 0);
}

// ---------------------------------------------------------------------------
// pool (2-stage)
// ---------------------------------------------------------------------------
__global__ __launch_bounds__(256) void pool1(const float* __restrict__ x,
                                             float* __restrict__ psum,
                                             float* __restrict__ pmax) {
  int bid = blockIdx.x;            // b*64 + sl
  int b = bid >> 6, sl = bid & 63;
  int t = threadIdx.x;
  float s[4] = {0.f, 0.f, 0.f, 0.f};
  float m[4] = {-INFINITY, -INFINITY, -INFINITY, -INFINITY};
  const float* xb = x + ((size_t)b << 20) + (size_t)sl * 16 * 1024;
  for (int l = 0; l < 16; ++l) {
    #pragma unroll
    for (int dg = 0; dg < 4; ++dg) {
      float v = xb[l * 1024 + dg * 256 + t];
      s[dg] += v;
      m[dg] = fmaxf(m[dg], v);
    }
  }
  #pragma unroll
  for (int dg = 0; dg < 4; ++dg) {
    psum[(size_t)bid * 1024 + dg * 256 + t] = s[dg];
    pmax[(size_t)bid * 1024 + dg * 256 + t] = m[dg];
  }
}

__global__ __launch_bounds__(256) void pool2(const float* __restrict__ psum,
                                             const float* __restrict__ pmax,
                                             float* __restrict__ pooled) {
  int bid = blockIdx.x;            // b*4 + dg
  int b = bid >> 2, dg = bid & 3;
  int d = dg * 256 + threadIdx.x;
  float s = 0.f, m = -INFINITY;
  for (int sl = 0; sl < 64; ++sl) {
    s += psum[((size_t)b * 64 + sl) * 1024 + d];
    m = fmaxf(m, pmax[((size_t)b * 64 + sl) * 1024 + d]);
  }
  pooled[b * 1024 + d] = (s * (1.0f / 1024.0f) + m) * 0.5f;
}

// ---------------------------------------------------------------------------
// pattern selector, staged
// ---------------------------------------------------------------------------
__global__ __launch_bounds__(256) void ps_gemv1(const float* __restrict__ pooled,
                                                const float* __restrict__ w1,
                                                const float* __restrict__ b1,
                                                float* __restrict__ h1) {
  int bid = blockIdx.x;            // b*16 + og
  int b = bid >> 4, og = bid & 15;
  int t = threadIdx.x;
  int ol = t >> 2, ks = t & 3;
  int o = og * 64 + ol;
  const float4* wr = (const float4*)(w1 + (size_t)o * 1024 + ks * 256);
  const float4* pp = (const float4*)(pooled + b * 1024 + ks * 256);
  float acc = 0.f;
  #pragma unroll 8
  for (int j = 0; j < 64; ++j) {
    float4 a = wr[j], p = pp[j];
    acc += a.x * p.x + a.y * p.y + a.z * p.z + a.w * p.w;
  }
  acc += __shfl_xor(acc, 1, 64);
  acc += __shfl_xor(acc, 2, 64);
  if (ks == 0) h1[b * 1024 + o] = acc + b1[o];
}

__global__ __launch_bounds__(256) void ps_ln(float* __restrict__ h1,
                                             const float* __restrict__ lng,
                                             const float* __restrict__ lnb) {
  __shared__ float red[256];
  int b = blockIdx.x, t = threadIdx.x;
  float* hb = h1 + b * 1024;
  float v0[4];
  float ls = 0.f;
  #pragma unroll
  for (int i = 0; i < 4; ++i) { v0[i] = hb[t + 256 * i]; ls += v0[i]; }
  red[t] = ls; __syncthreads();
  for (int s = 128; s > 0; s >>= 1) { if (t < s) red[t] += red[t + s]; __syncthreads(); }
  float mean = red[0] * (1.0f / 1024.0f);
  __syncthreads();
  float lq = 0.f;
  #pragma unroll
  for (int i = 0; i < 4; ++i) { float dv = v0[i] - mean; lq += dv * dv; }
  red[t] = lq; __syncthreads();
  for (int s = 128; s > 0; s >>= 1) { if (t < s) red[t] += red[t + s]; __syncthreads(); }
  float rstd = 1.0f / sqrtf(red[0] * (1.0f / 1024.0f) + 1e-5f);
  #pragma unroll
  for (int i = 0; i < 4; ++i) {
    float v = (v0[i] - mean) * rstd * lng[t + 256 * i] + lnb[t + 256 * i];
    hb[t + 256 * i] = 0.5f * v * (1.0f + erff(v * 0.70710678118654752f));
  }
}

__global__ __launch_bounds__(256) void ps_gemv2(const float* __restrict__ h1,
                                                const float* __restrict__ w2,
                                                const float* __restrict__ b2,
                                                float* __restrict__ h2) {
  int bid = blockIdx.x;            // b*8 + og
  int b = bid >> 3, og = bid & 7;
  int t = threadIdx.x;
  int ol = t >> 2, ks = t & 3;
  int o = og * 64 + ol;
  const float4* wr = (const float4*)(w2 + (size_t)o * 1024 + ks * 256);
  const float4* pp = (const float4*)(h1 + b * 1024 + ks * 256);
  float acc = 0.f;
  #pragma unroll 8
  for (int j = 0; j < 64; ++j) {
    float4 a = wr[j], p = pp[j];
    acc += a.x * p.x + a.y * p.y + a.z * p.z + a.w * p.w;
  }
  acc += __shfl_xor(acc, 1, 64);
  acc += __shfl_xor(acc, 2, 64);
  if (ks == 0) {
    float v = acc + b2[o];
    h2[b * 512 + o] = 0.5f * v * (1.0f + erff(v * 0.70710678118654752f));
  }
}

__global__ __launch_bounds__(256) void ps_logits(const float* __restrict__ h2,
                                                 const float* __restrict__ w3,
                                                 const float* __restrict__ b3,
                                                 const float* __restrict__ pb,
                                                 int* __restrict__ meta) {
  __shared__ float red[256];
  int b = blockIdx.x, t = threadIdx.x;
  float lgv[3];
  for (int c = 0; c < 3; ++c) {
    float p = 0.f;
    for (int i = t; i < 512; i += 256) p += h2[b * 512 + i] * w3[c * 512 + i];
    red[t] = p; __syncthreads();
    for (int s = 128; s > 0; s >>= 1) { if (t < s) red[t] += red[t + s]; __syncthreads(); }
    lgv[c] = red[0] + b3[c] + pb[c];
    __syncthreads();
  }
  if (t == 0) {
    float mx = fmaxf(lgv[0], fmaxf(lgv[1], lgv[2]));
    float e0 = __expf(lgv[0] - mx), e1 = __expf(lgv[1] - mx), e2 = __expf(lgv[2] - mx);
    float inv = 1.0f / (e0 + e1 + e2);
    float p0 = e0 * inv, p1 = e1 * inv, p2 = e2 * inv;
    float c00 = p1;
    float c10 = p0 + p1;
    float c01 = p1 + p2;
    float c11 = (p0 + p1) + p2;
    int t00 = c00 > 0.1f, t10 = c10 > 0.1f, t01 = c01 > 0.1f, t11 = c11 > 0.1f;
    meta[b * 8 + 0] = t00;
    meta[b * 8 + 1] = t10;
    meta[b * 8 + 2] = t01;
    meta[b * 8 + 3] = t11;
    meta[b * 8 + 4] = (t00 != t01) || (t10 != t11);
  }
}

// ---------------------------------------------------------------------------
// prep_split: f32 -> interleaved split-bf16 (out[2i]=hi, out[2i+1]=lo)
// ---------------------------------------------------------------------------
__global__ __launch_bounds__(256) void prep_split(const float* __restrict__ in,
                                                  unsigned short* __restrict__ out2,
                                                  int n4) {
  int i = blockIdx.x * 256 + threadIdx.x;
  if (i >= n4) return;
  float4 v = ((const float4*)in)[i];
  float f[4] = {v.x, v.y, v.z, v.w};
  union { s8v v8; unsigned short u[8]; } o;
  #pragma unroll
  for (int j = 0; j < 4; ++j) {
    unsigned short h = f2bf(f[j]);
    o.u[2 * j] = h;
    o.u[2 * j + 1] = f2bf(f[j] - bf2f(h));
  }
  *(s8v*)(out2 + (size_t)i * 8) = o.v8;
}

// ---------------------------------------------------------------------------
// gemm_sp: C[M][N] = A[M][2048] . B[N][2048] (interleaved split-bf16, K'=2048)
// ---------------------------------------------------------------------------
template <int MODE>
__global__ __launch_bounds__(256) void gemm_sp(
    const unsigned short* __restrict__ A, const unsigned short* __restrict__ B,
    const float* __restrict__ bias, float* __restrict__ q, float* __restrict__ k2,
    float* __restrict__ v2, float* __restrict__ out, int Nb) {
  __shared__ unsigned short Asm[128 * 64];
  __shared__ unsigned short Bsm[128 * 64];

  int bid = blockIdx.x;
  int cpx = gridDim.x >> 3;
  int g = (bid & 7) * cpx + (bid >> 3);
  int bm = g / Nb, bn = g % Nb;
  size_t row0 = (size_t)bm * 128, col0 = (size_t)bn * 128;

  int tid = threadIdx.x, lane = tid & 63, wv = tid >> 6;
  int wm = (wv >> 1) << 6, wn = (wv & 1) << 6;
  int rowg = lane >> 4, colc = lane & 15;

  f4v acc[4][4];
  #pragma unroll
  for (int mf = 0; mf < 4; ++mf)
    #pragma unroll
    for (int nf = 0; nf < 4; ++nf) acc[mf][nf] = (f4v){0.f, 0.f, 0.f, 0.f};

  const unsigned short* Abase = A + row0 * 2048;
  const unsigned short* Bbase = B + col0 * 2048;

  int sidx0 = tid;
  for (int kb = 0; kb < 2048; kb += 64) {
    __syncthreads();
    #pragma unroll
    for (int p = 0; p < 4; ++p) {
      int idx = p * 256 + sidx0;
      int row = idx >> 3;
      int ch = idx & 7;
      int sc = ch ^ (row & 7);
      unsigned short* la = &Asm[(size_t)(p * 256 + wv * 64) * 8];
      unsigned short* lb = &Bsm[(size_t)(p * 256 + wv * 64) * 8];
      gload16(Abase + (size_t)row * 2048 + kb + sc * 8, la);
      gload16(Bbase + (size_t)row * 2048 + kb + sc * 8, lb);
    }
    __syncthreads();
    #pragma unroll
    for (int ks = 0; ks < 2; ++ks) {
      s8v af[4], bf_[4];
      #pragma unroll
      for (int mf = 0; mf < 4; ++mf) {
        int row = wm + mf * 16 + colc;
        int kby = (ks * 64 + rowg * 16) ^ ((row & 7) << 4);
        af[mf] = *(const s8v*)((const char*)Asm + row * 128 + kby);
      }
      #pragma unroll
      for (int nf = 0; nf < 4; ++nf) {
        int row = wn + nf * 16 + colc;
        int kby = (ks * 64 + rowg * 16) ^ ((row & 7) << 4);
        bf_[nf] = *(const s8v*)((const char*)Bsm + row * 128 + kby);
      }
      #pragma unroll
      for (int mf = 0; mf < 4; ++mf)
        #pragma unroll
        for (int nf = 0; nf < 4; ++nf)
          acc[mf][nf] = mfma16(af[mf], bf_[nf], acc[mf][nf]);
    }
  }

  #pragma unroll
  for (int mf = 0; mf < 4; ++mf) {
    #pragma unroll
    for (int r = 0; r < 4; ++r) {
      int m = (int)row0 + wm + mf * 16 + rowg * 4 + r;
      #pragma unroll
      for (int nf = 0; nf < 4; ++nf) {
        int n = (int)col0 + wn + nf * 16 + colc;
        float val = acc[mf][nf][r];
        if (MODE == 0) {
          int bb = m >> 10, l = m & 1023;
          int c = n >> 10, hh = (n >> 6) & 15, hd = n & 63;
          float* base = (c == 0) ? q : (c == 1) ? k2 : v2;
          base[((size_t)(bb * 16 + hh) * 1024 + l) * 64 + hd] = val;
        } else {
          out[(size_t)m * 1024 + n] = val + bias[n];
        }
      }
    }
  }
}

// ---------------------------------------------------------------------------
// prep_qk: q scaled by SCALE*log2e (exp2-domain softmax); split hi/lo
// ---------------------------------------------------------------------------
__global__ __launch_bounds__(256) void prep_qk(const float* __restrict__ qw,
                                               const float* __restrict__ kw,
                                               unsigned short* __restrict__ qh,
                                               unsigned short* __restrict__ ql,
                                               unsigned short* __restrict__ kh,
                                               unsigned short* __restrict__ kl) {
  int i4 = blockIdx.x * 256 + threadIdx.x;
  float4 q = ((const float4*)qw)[i4];
  float4 k = ((const float4*)kw)[i4];
  float qf[4] = {q.x * QSCALE_, q.y * QSCALE_, q.z * QSCALE_, q.w * QSCALE_};
  float kf[4] = {k.x, k.y, k.z, k.w};
  ushort4 qh4, ql4, kh4, kl4;
  unsigned short* qhp = (unsigned short*)&qh4;
  unsigned short* qlp = (unsigned short*)&ql4;
  unsigned short* khp = (unsigned short*)&kh4;
  unsigned short* klp = (unsigned short*)&kl4;
  #pragma unroll
  for (int i = 0; i < 4; ++i) {
    unsigned short h = f2bf(qf[i]);
    qhp[i] = h; qlp[i] = f2bf(qf[i] - bf2f(h));
    unsigned short h2 = f2bf(kf[i]);
    khp[i] = h2; klp[i] = f2bf(kf[i] - bf2f(h2));
  }
  *(ushort4*)(qh + 4 * (size_t)i4) = qh4;
  *(ushort4*)(ql + 4 * (size_t)i4) = ql4;
  *(ushort4*)(kh + 4 * (size_t)i4) = kh4;
  *(ushort4*)(kl + 4 * (size_t)i4) = kl4;
}

__global__ __launch_bounds__(256) void prep_vt(const float* __restrict__ vw,
                                               unsigned short* __restrict__ vth,
                                               unsigned short* __restrict__ vtl) {
  __shared__ float t[64][65];
  int bh = blockIdx.y;
  int l0 = blockIdx.x * 64;
  int tid = threadIdx.x;
  int lr = tid >> 4, dc = (tid & 15) * 4;
  #pragma unroll
  for (int it = 0; it < 4; ++it) {
    int ll = lr + it * 16;
    float4 v = *(const float4*)(vw + ((size_t)bh * 1024 + l0 + ll) * 64 + dc);
    t[dc + 0][ll] = v.x; t[dc + 1][ll] = v.y; t[dc + 2][ll] = v.z; t[dc + 3][ll] = v.w;
  }
  __syncthreads();
  int d = tid >> 2, lc = (tid & 3) * 16;
  unsigned short* dsth = vth + ((size_t)bh * 64 + d) * 1024 + l0 + lc;
  unsigned short* dstl = vtl + ((size_t)bh * 64 + d) * 1024 + l0 + lc;
  #pragma unroll
  for (int i = 0; i < 16; i += 4) {
    ushort4 h4, l4;
    unsigned short* hp = (unsigned short*)&h4;
    unsigned short* lp = (unsigned short*)&l4;
    #pragma unroll
    for (int jj = 0; jj < 4; ++jj) {
      float f = t[d][lc + i + jj];
      unsigned short h = f2bf(f);
      hp[jj] = h; lp[jj] = f2bf(f - bf2f(h));
    }
    *(ushort4*)(dsth + i) = h4;
    *(ushort4*)(dstl + i) = l4;
  }
}

// ---------------------------------------------------------------------------
// attn_flash v2: swapped QK^T (S^T = K.Q^T) -> per-lane row softmax.
// Lane (g=lane>>4, i=lane&15) owns q-row q0+i; 16 j-values in regs.
// P staged [i][j] interleaved hi4|lo4 per 4-j block: b128 writes, b64 reads.
// Output written directly as interleaved split-bf16 (aos) for proj GEMM.
// ---------------------------------------------------------------------------
__global__ __launch_bounds__(256) void attn_flash(
    const unsigned short* __restrict__ qh, const unsigned short* __restrict__ ql,
    const unsigned short* __restrict__ kh, const unsigned short* __restrict__ kl,
    const unsigned short* __restrict__ vth, const unsigned short* __restrict__ vtl,
    const float* __restrict__ vw, const int* __restrict__ meta,
    unsigned int* __restrict__ aou) {
  int n = blockIdx.x;
  int bh = ((n & 7) << 3) | (n >> 7);   // XCD swizzle: one bh per XCD group
  int qt = (n >> 3) & 15;
  int b = bh >> 4, h = bh & 15;
  const int* mb = meta + b * 8;
  if (mb[4]) return;  // sparse regime -> fallback kernel owns this batch
  int t00 = mb[0], t10 = mb[1];

  int tid = threadIdx.x, lane = tid & 63, wv = tid >> 6;
  int g = lane >> 4, colc = lane & 15;
  int q0 = qt * 64 + wv * 16;

  if (!t10) {
    // self-only regime: out row = v row (split-bf16)
    #pragma unroll
    for (int it = 0; it < 4; ++it) {
      int idx = tid + it * 256;
      int r = idx >> 4, dc = (idx & 15) * 4;
      float4 v = *(const float4*)(vw + ((size_t)bh * 1024 + qt * 64 + r) * 64 + dc);
      float f[4] = {v.x, v.y, v.z, v.w};
      uint4 o;
      unsigned* op = (unsigned*)&o;
      #pragma unroll
      for (int j = 0; j < 4; ++j) {
        unsigned short hi = f2bf(f[j]);
        op[j] = (unsigned)hi | ((unsigned)f2bf(f[j] - bf2f(hi)) << 16);
      }
      *(uint4*)(aou + ((size_t)b * 1024 + qt * 64 + r) * 1024 + h * 64 + dc) = o;
    }
    return;
  }
  bool local_only = !t00;

  // P staging: [wave][i(16)][block(16)+pad][hi4,lo4]
  __shared__ __align__(16) unsigned short pls[4][16][17][8];

  // Q fragments (B operand: row=i=colc, k=d=g*8+e, 2 k-steps)
  const unsigned short* qb_h = qh + ((size_t)bh * 1024 + q0 + colc) * 64 + g * 8;
  const unsigned short* qb_l = ql + ((size_t)bh * 1024 + q0 + colc) * 64 + g * 8;
  s8v Qh[2], Ql[2];
  Qh[0] = *(const s8v*)(qb_h);      Qh[1] = *(const s8v*)(qb_h + 32);
  Ql[0] = *(const s8v*)(qb_l);      Ql[1] = *(const s8v*)(qb_l + 32);

  f4v O[4];
  #pragma unroll
  for (int df = 0; df < 4; ++df) O[df] = (f4v){0.f, 0.f, 0.f, 0.f};
  float m = -1e30f, lsum = 0.f;   // per-lane scalars: row i = q0+colc

  const unsigned short* vbh_base = vth + ((size_t)bh * 64 + colc) * 1024;
  const unsigned short* vbl_base = vtl + ((size_t)bh * 64 + colc) * 1024;

  for (int jb = 0; jb < 16; ++jb) {
    int jc0 = jb * 64;
    if (local_only && (jc0 + 63 < q0 - 16 || jc0 > q0 + 31)) continue;

    // ---- S^T chunk: s[jf][r] = S[j = jc0+jf*16+4g+r][i = q0+colc] ----
    f4v s[4];
    const unsigned short* kb_h = kh + ((size_t)bh * 1024 + jc0 + colc) * 64 + g * 8;
    const unsigned short* kb_l = kl + ((size_t)bh * 1024 + jc0 + colc) * 64 + g * 8;
    #pragma unroll
    for (int jf = 0; jf < 4; ++jf) {
      f4v acc = (f4v){0.f, 0.f, 0.f, 0.f};
      const unsigned short* ph_ = kb_h + jf * 16 * 64;
      const unsigned short* pl_ = kb_l + jf * 16 * 64;
      s8v Kh0 = *(const s8v*)(ph_);
      s8v Kh1 = *(const s8v*)(ph_ + 32);
      s8v Kl0 = *(const s8v*)(pl_);
      s8v Kl1 = *(const s8v*)(pl_ + 32);
      acc = mfma16(Kh0, Qh[0], acc);
      acc = mfma16(Kh1, Qh[1], acc);
      acc = mfma16(Kl0, Qh[0], acc);
      acc = mfma16(Kl1, Qh[1], acc);
      acc = mfma16(Kh0, Ql[0], acc);
      acc = mfma16(Kh1, Ql[1], acc);
      s[jf] = acc;
    }

    // ---- mask + per-row (per-lane) max ----
    float cm = -1e30f;
    #pragma unroll
    for (int jf = 0; jf < 4; ++jf) {
      #pragma unroll
      for (int r = 0; r < 4; ++r) {
        float sv = s[jf][r];
        if (local_only) {
          int j = jc0 + jf * 16 + 4 * g + r;
          int i = q0 + colc;
          int dj = i - j;
          if (dj > 16 || dj < -16) { sv = -1e30f; s[jf][r] = sv; }
        }
        cm = fmaxf(cm, sv);
      }
    }
    cm = fmaxf(cm, __shfl_xor(cm, 16, 64));
    cm = fmaxf(cm, __shfl_xor(cm, 32, 64));

    bool grow = __any(cm > m);
    float fac = 1.0f;
    if (grow) {
      float mn = fmaxf(m, cm);
      fac = __builtin_amdgcn_exp2f(m - mn);
      m = mn;
    }

    // ---- P = exp2(s - m), split bf16 hi/lo, staged [i][j] contiguous ----
    float psum = 0.f;
    #pragma unroll
    for (int jf = 0; jf < 4; ++jf) {
      union { s8v v; unsigned short u[8]; } pk;
      #pragma unroll
      for (int r = 0; r < 4; ++r) {
        float sv = s[jf][r];
        float p = (sv > -1e29f) ? __builtin_amdgcn_exp2f(sv - m) : 0.f;
        psum += p;
        unsigned short hi = f2bf(p);
        pk.u[r] = hi;
        pk.u[4 + r] = f2bf(p - bf2f(hi));
      }
      *(s8v*)&pls[wv][colc][jf * 4 + g][0] = pk.v;   // ds_write_b128
    }
    psum += __shfl_xor(psum, 16, 64);
    psum += __shfl_xor(psum, 32, 64);

    if (grow) {
      lsum = lsum * fac + psum;
      float fo[4];
      #pragma unroll
      for (int r = 0; r < 4; ++r)
        fo[r] = __shfl(fac, (lane & 48) + g * 4 + r, 64);
      #pragma unroll
      for (int df = 0; df < 4; ++df) {
        #pragma unroll
        for (int r = 0; r < 4; ++r) O[df][r] *= fo[r];
      }
    } else {
      lsum += psum;
    }

    // ---- PV: A = P[i][j] (b64 reads), B = VT fragments ----
    s8v Ph[2], Pl[2];
    {
      const ushort4* pw = (const ushort4*)&pls[wv][colc][0][0];
      #pragma unroll
      for (int ks = 0; ks < 2; ++ks) {
        int b0 = 8 * ks + 2 * g;
        union { s8v v; ushort4 q[2]; } uh, ul;
        uh.q[0] = pw[2 * b0];     ul.q[0] = pw[2 * b0 + 1];
        uh.q[1] = pw[2 * b0 + 2]; ul.q[1] = pw[2 * b0 + 3];
        Ph[ks] = uh.v; Pl[ks] = ul.v;
      }
    }
    #pragma unroll
    for (int df = 0; df < 4; ++df) {
      const unsigned short* vph = vbh_base + (size_t)df * 16 * 1024 + jc0 + g * 8;
      const unsigned short* vpl = vbl_base + (size_t)df * 16 * 1024 + jc0 + g * 8;
      #pragma unroll
      for (int ks = 0; ks < 2; ++ks) {
        s8v Vh = *(const s8v*)(vph + ks * 32);
        s8v Vl = *(const s8v*)(vpl + ks * 32);
        O[df] = mfma16(Ph[ks], Vh, O[df]);
        O[df] = mfma16(Ph[ks], Vl, O[df]);
        O[df] = mfma16(Pl[ks], Vh, O[df]);
      }
    }
  }

  // ---- epilogue: gather lsum per C-row, normalize, write split-bf16 ----
  float linv[4];
  #pragma unroll
  for (int r = 0; r < 4; ++r)
    linv[r] = 1.0f / __shfl(lsum, (lane & 48) + g * 4 + r, 64);
  #pragma unroll
  for (int df = 0; df < 4; ++df) {
    #pragma unroll
    for (int r = 0; r < 4; ++r) {
      int i = q0 + g * 4 + r;
      float val = O[df][r] * linv[r];
      unsigned short hi = f2bf(val);
      unsigned o = (unsigned)hi | ((unsigned)f2bf(val - bf2f(hi)) << 16);
      aou[((size_t)b * 1024 + i) * 1024 + h * 64 + df * 16 + colc] = o;
    }
  }
}

// ---------------------------------------------------------------------------
// attn_kernel fallback (sparse topk regime, or small-ws force path)
// write_split: 1 -> write interleaved split-bf16 aos; 0 -> write f32 ao
// ---------------------------------------------------------------------------
__global__ __launch_bounds__(256) void attn_kernel(const float* __restrict__ qw,
                                                   const float* __restrict__ kw,
                                                   const float* __restrict__ vw,
                                                   const int* __restrict__ meta,
                                                   float* __restrict__ ao,
                                                   unsigned int* __restrict__ aou,
                                                   int force, int write_split) {
  __shared__ float S[32][1028];
  __shared__ float qs[32][68];
  __shared__ float kc[64][68];
  __shared__ float rowsum_s[32];

  int tid = threadIdx.x;
  int lane = tid & 63;
  int wv = tid >> 6;
  int id = blockIdx.x;
  int rt = id & 31;
  int h = (id >> 5) & 15;
  int b = id >> 9;
  int bh = b * 16 + h;
  int row0 = rt * 32;

  const int* mb = meta + b * 8;
  int t00 = mb[0], t10 = mb[1], t01 = mb[2], t11 = mb[3], needs = mb[4];
  if (!force && !needs) return;

  {
    const float4* qp = (const float4*)(qw + ((size_t)bh * 1024 + row0 + wv * 8) * 64);
    #pragma unroll
    for (int i = 0; i < 2; ++i) {
      int f = lane + 64 * i;
      float4 v = qp[f];
      int r = wv * 8 + (f >> 4);
      int d = (f & 15) << 2;
      qs[r][d] = v.x; qs[r][d + 1] = v.y; qs[r][d + 2] = v.z; qs[r][d + 3] = v.w;
    }
  }

  int lr = lane >> 4, lc = lane & 15;
  int r_a = wv * 8 + lr * 2;
  int r_b = r_a + 1;

  for (int cb = 0; cb < 16; ++cb) {
    __syncthreads();
    const float4* kp = (const float4*)(kw + ((size_t)bh * 1024 + cb * 64) * 64);
    #pragma unroll
    for (int i = 0; i < 4; ++i) {
      int f = tid + 256 * i;
      float4 v = kp[f];
      int c = f >> 4, d = (f & 15) << 2;
      kc[c][d] = v.x; kc[c][d + 1] = v.y; kc[c][d + 2] = v.z; kc[c][d + 3] = v.w;
    }
    __syncthreads();

    float acc0[4] = {0.f, 0.f, 0.f, 0.f};
    float acc1[4] = {0.f, 0.f, 0.f, 0.f};
    for (int dq = 0; dq < 64; dq += 4) {
      float4 qa = *(const float4*)&qs[r_a][dq];
      float4 qb = *(const float4*)&qs[r_b][dq];
      #pragma unroll
      for (int cj = 0; cj < 4; ++cj) {
        float4 kv = *(const float4*)&kc[lc + 16 * cj][dq];
        acc0[cj] += qa.x * kv.x + qa.y * kv.y + qa.z * kv.z + qa.w * kv.w;
        acc1[cj] += qb.x * kv.x + qb.y * kv.y + qb.z * kv.z + qb.w * kv.w;
      }
    }
    #pragma unroll
    for (int cj = 0; cj < 4; ++cj) {
      S[r_a][cb * 64 + lc + 16 * cj] = acc0[cj] * SCALE_;
      S[r_b][cb * 64 + lc + 16 * cj] = acc1[cj] * SCALE_;
    }
  }

  for (int rr = 0; rr < 8; ++rr) {
    int r = wv * 8 + rr;
    int grow = row0 + r;
    float sv[16];
    unsigned kv[16];
    #pragma unroll
    for (int i2 = 0; i2 < 16; ++i2) {
      float s = S[r][lane + 64 * i2];
      sv[i2] = s;
      unsigned u = __float_as_uint(s);
      kv[i2] = (u & 0x80000000u) ? ~u : (u | 0x80000000u);
    }
    unsigned T = 0u;
    if (needs) {
      for (int bit = 31; bit >= 0; --bit) {
        unsigned cand = T | (1u << bit);
        int cnt = 0;
        #pragma unroll
        for (int i2 = 0; i2 < 16; ++i2) cnt += (kv[i2] >= cand) ? 1 : 0;
        for (int off = 32; off; off >>= 1) cnt += __shfl_xor(cnt, off, 64);
        if (cnt >= KTOP_) T = cand;
      }
    }
    float mx = -INFINITY;
    int kept = 0;
    unsigned kmask = 0;
    #pragma unroll
    for (int i2 = 0; i2 < 16; ++i2) {
      int j = lane + 64 * i2;
      int sp = (kv[i2] >= T) ? 1 : 0;
      int dj = grow - j;
      int lo = (dj <= 16 && dj >= -16) ? 1 : 0;
      int keep = sp ? (lo ? t11 : t01) : (lo ? t10 : t00);
      kept += keep;
      if (keep) { kmask |= (1u << i2); mx = fmaxf(mx, sv[i2]); }
    }
    for (int off = 32; off; off >>= 1) {
      mx = fmaxf(mx, __shfl_xor(mx, off, 64));
      kept += __shfl_xor(kept, off, 64);
    }
    if (kept == 0) {
      #pragma unroll
      for (int i2 = 0; i2 < 16; ++i2) {
        int j = lane + 64 * i2;
        S[r][j] = (j == grow) ? 1.0f : 0.0f;
      }
      if (lane == 0) rowsum_s[r] = 1.0f;
    } else {
      float sum = 0.f;
      #pragma unroll
      for (int i2 = 0; i2 < 16; ++i2) {
        float p = ((kmask >> i2) & 1u) ? __expf(sv[i2] - mx) : 0.0f;
        sum += p;
        S[r][lane + 64 * i2] = p;
      }
      for (int off = 32; off; off >>= 1) sum += __shfl_xor(sum, off, 64);
      if (lane == 0) rowsum_s[r] = sum;
    }
  }

  int ld = lane & 15;
  int d0 = ld * 4;
  float4 oa0 = make_float4(0.f, 0.f, 0.f, 0.f);
  float4 oa1 = make_float4(0.f, 0.f, 0.f, 0.f);
  for (int vb = 0; vb < 16; ++vb) {
    __syncthreads();
    const float4* vp = (const float4*)(vw + ((size_t)bh * 1024 + vb * 64) * 64);
    #pragma unroll
    for (int i = 0; i < 4; ++i) {
      int f = tid + 256 * i;
      float4 v = vp[f];
      int c = f >> 4, d = (f & 15) << 2;
      kc[c][d] = v.x; kc[c][d + 1] = v.y; kc[c][d + 2] = v.z; kc[c][d + 3] = v.w;
    }
    __syncthreads();
    for (int cq = 0; cq < 64; cq += 4) {
      float4 pa = *(const float4*)&S[r_a][vb * 64 + cq];
      float4 pb = *(const float4*)&S[r_b][vb * 64 + cq];
      float par[4] = {pa.x, pa.y, pa.z, pa.w};
      float pbr[4] = {pb.x, pb.y, pb.z, pb.w};
      #pragma unroll
      for (int tt = 0; tt < 4; ++tt) {
        float4 vv = *(const float4*)&kc[cq + tt][d0];
        oa0.x += par[tt] * vv.x; oa0.y += par[tt] * vv.y;
        oa0.z += par[tt] * vv.z; oa0.w += par[tt] * vv.w;
        oa1.x += pbr[tt] * vv.x; oa1.y += pbr[tt] * vv.y;
        oa1.z += pbr[tt] * vv.z; oa1.w += pbr[tt] * vv.w;
      }
    }
  }
  float inv0 = 1.0f / rowsum_s[r_a];
  float inv1 = 1.0f / rowsum_s[r_b];
  float v0[4] = {oa0.x * inv0, oa0.y * inv0, oa0.z * inv0, oa0.w * inv0};
  float v1[4] = {oa1.x * inv1, oa1.y * inv1, oa1.z * inv1, oa1.w * inv1};
  if (write_split) {
    uint4 o0, o1;
    unsigned* o0p = (unsigned*)&o0;
    unsigned* o1p = (unsigned*)&o1;
    #pragma unroll
    for (int j = 0; j < 4; ++j) {
      unsigned short h0 = f2bf(v0[j]);
      o0p[j] = (unsigned)h0 | ((unsigned)f2bf(v0[j] - bf2f(h0)) << 16);
      unsigned short h1 = f2bf(v1[j]);
      o1p[j] = (unsigned)h1 | ((unsigned)f2bf(v1[j] - bf2f(h1)) << 16);
    }
    *(uint4*)(aou + ((size_t)b * 1024 + row0 + r_a) * 1024 + h * 64 + d0) = o0;
    *(uint4*)(aou + ((size_t)b * 1024 + row0 + r_b) * 1024 + h * 64 + d0) = o1;
  } else {
    float* p0 = ao + ((size_t)b * 1024 + row0 + r_a) * 1024 + h * 64 + d0;
    float* p1 = ao + ((size_t)b * 1024 + row0 + r_b) * 1024 + h * 64 + d0;
    *(float4*)p0 = make_float4(v0[0], v0[1], v0[2], v0[3]);
    *(float4*)p1 = make_float4(v1[0], v1[1], v1[2], v1[3]);
  }
}

// ---------------------------------------------------------------------------
// Fallback f32 kernels (small-ws path only)
// ---------------------------------------------------------------------------
__global__ __launch_bounds__(256) void pool_kernel(const float* __restrict__ x,
                                                   float* __restrict__ pooled) {
  int g = blockIdx.x * 256 + threadIdx.x;
  int b = g >> 10, d = g & 1023;
  const float* xp = x + ((size_t)b << 20) + d;
  float s = 0.f, m = -INFINITY;
  #pragma unroll 4
  for (int l = 0; l < LL_; ++l) {
    float v = xp[(size_t)l << 10];
    s += v;
    m = fmaxf(m, v);
  }
  pooled[g] = (s * (1.0f / 1024.0f) + m) * 0.5f;
}

__global__ __launch_bounds__(256) void qkv_gemm(const float* __restrict__ X,
                                                const float* __restrict__ W,
                                                float* __restrict__ qw,
                                                float* __restrict__ kw,
                                                float* __restrict__ vw) {
  __shared__ float As[8][128];
  __shared__ float Bs[8][128];
  int tid = threadIdx.x;
  int row0 = blockIdx.y * 128, col0 = blockIdx.x * 128;
  int lr = tid >> 1;
  int lk = (tid & 1) * 4;
  int ty = tid >> 4, tx = tid & 15;
  float acc[8][8] = {};

  for (int kb = 0; kb < 1024; kb += 8) {
    float4 a4 = *(const float4*)(X + (size_t)(row0 + lr) * 1024 + kb + lk);
    float4 b4 = *(const float4*)(W + (size_t)(col0 + lr) * 1024 + kb + lk);
    __syncthreads();
    As[lk + 0][lr] = a4.x; As[lk + 1][lr] = a4.y; As[lk + 2][lr] = a4.z; As[lk + 3][lr] = a4.w;
    Bs[lk + 0][lr] = b4.x; Bs[lk + 1][lr] = b4.y; Bs[lk + 2][lr] = b4.z; Bs[lk + 3][lr] = b4.w;
    __syncthreads();
    #pragma unroll
    for (int kk = 0; kk < 8; ++kk) {
      float av[8], bv[8];
      #pragma unroll
      for (int i = 0; i < 8; ++i) av[i] = As[kk][ty * 8 + i];
      #pragma unroll
      for (int j = 0; j < 8; ++j) bv[j] = Bs[kk][tx * 8 + j];
      #pragma unroll
      for (int i = 0; i < 8; ++i)
        #pragma unroll
        for (int j = 0; j < 8; ++j) acc[i][j] += av[i] * bv[j];
    }
  }
  #pragma unroll
  for (int i = 0; i < 8; ++i) {
    int m = row0 + ty * 8 + i;
    int bb = m >> 10, l = m & 1023;
    #pragma unroll
    for (int j = 0; j < 8; j += 4) {
      int n = col0 + tx * 8 + j;
      int c = n >> 10;
      int hh = (n >> 6) & 15;
      int hd = n & 63;
      float* base = (c == 0) ? qw : (c == 1) ? kw : vw;
      float* dst = base + ((size_t)(bb * 16 + hh) * 1024 + l) * 64 + hd;
      *(float4*)dst = make_float4(acc[i][j], acc[i][j + 1], acc[i][j + 2], acc[i][j + 3]);
    }
  }
}

__global__ __launch_bounds__(256) void proj_gemm(const float* __restrict__ A,
                                                 const float* __restrict__ W,
                                                 const float* __restrict__ bias,
                                                 float* __restrict__ out) {
  __shared__ float As[8][128];
  __shared__ float Bs[8][128];
  int tid = threadIdx.x;
  int row0 = blockIdx.y * 128, col0 = blockIdx.x * 128;
  int lr = tid >> 1;
  int lk = (tid & 1) * 4;
  int ty = tid >> 4, tx = tid & 15;
  float acc[8][8] = {};

  for (int kb = 0; kb < 1024; kb += 8) {
    float4 a4 = *(const float4*)(A + (size_t)(row0 + lr) * 1024 + kb + lk);
    float4 b4 = *(const float4*)(W + (size_t)(col0 + lr) * 1024 + kb + lk);
    __syncthreads();
    As[lk + 0][lr] = a4.x; As[lk + 1][lr] = a4.y; As[lk + 2][lr] = a4.z; As[lk + 3][lr] = a4.w;
    Bs[lk + 0][lr] = b4.x; Bs[lk + 1][lr] = b4.y; Bs[lk + 2][lr] = b4.z; Bs[lk + 3][lr] = b4.w;
    __syncthreads();
    #pragma unroll
    for (int kk = 0; kk < 8; ++kk) {
      float av[8], bv[8];
      #pragma unroll
      for (int i = 0; i < 8; ++i) av[i] = As[kk][ty * 8 + i];
      #pragma unroll
      for (int j = 0; j < 8; ++j) bv[j] = Bs[kk][tx * 8 + j];
      #pragma unroll
      for (int i = 0; i < 8; ++i)
        #pragma unroll
        for (int j = 0; j < 8; ++j) acc[i][j] += av[i] * bv[j];
    }
  }
  #pragma unroll
  for (int i = 0; i < 8; ++i) {
    int m = row0 + ty * 8 + i;
    #pragma unroll
    for (int j = 0; j < 8; j += 4) {
      int n = col0 + tx * 8 + j;
      *(float4*)(out + (size_t)m * 1024 + n) =
          make_float4(acc[i][j] + bias[n], acc[i][j + 1] + bias[n + 1],
                      acc[i][j + 2] + bias[n + 2], acc[i][j + 3] + bias[n + 3]);
    }
  }
}

__global__ __launch_bounds__(256) void pattern_kernel(
    const float* __restrict__ pooled,
    const float* __restrict__ w1, const float* __restrict__ b1,
    const float* __restrict__ lng, const float* __restrict__ lnb,
    const float* __restrict__ w2, const float* __restrict__ b2,
    const float* __restrict__ w3, const float* __restrict__ b3,
    const float* __restrict__ pb, int* __restrict__ meta) {
  __shared__ float pool_s[1024];
  __shared__ float h1[1024];
  __shared__ float h2[512];
  __shared__ float red[256];
  int b = blockIdx.x, t = threadIdx.x;

  for (int i = t; i < 1024; i += 256) pool_s[i] = pooled[b * 1024 + i];
  __syncthreads();
  for (int o = t; o < 1024; o += 256) {
    float acc = b1[o];
    const float* wr = w1 + (size_t)o * 1024;
    for (int k = 0; k < 1024; ++k) acc += pool_s[k] * wr[k];
    h1[o] = acc;
  }
  __syncthreads();
  float ls = 0.f;
  for (int i = t; i < 1024; i += 256) ls += h1[i];
  red[t] = ls; __syncthreads();
  for (int s = 128; s > 0; s >>= 1) { if (t < s) red[t] += red[t + s]; __syncthreads(); }
  float mean = red[0] * (1.0f / 1024.0f);
  __syncthreads();
  float lq = 0.f;
  for (int i = t; i < 1024; i += 256) { float dv = h1[i] - mean; lq += dv * dv; }
  red[t] = lq; __syncthreads();
  for (int s = 128; s > 0; s >>= 1) { if (t < s) red[t] += red[t + s]; __syncthreads(); }
  float var = red[0] * (1.0f / 1024.0f);
  float rstd = 1.0f / sqrtf(var + 1e-5f);
  __syncthreads();
  for (int i = t; i < 1024; i += 256) {
    float v = (h1[i] - mean) * rstd * lng[i] + lnb[i];
    h1[i] = 0.5f * v * (1.0f + erff(v * 0.70710678118654752f));
  }
  __syncthreads();
  for (int o = t; o < 512; o += 256) {
    float acc = b2[o];
    const float* wr = w2 + (size_t)o * 1024;
    for (int k = 0; k < 1024; ++k) acc += h1[k] * wr[k];
    h2[o] = 0.5f * acc * (1.0f + erff(acc * 0.70710678118654752f));
  }
  __syncthreads();
  float lgv[3];
  for (int c = 0; c < 3; ++c) {
    float p = 0.f;
    for (int i = t; i < 512; i += 256) p += h2[i] * w3[c * 512 + i];
    __syncthreads();
    red[t] = p; __syncthreads();
    for (int s = 128; s > 0; s >>= 1) { if (t < s) red[t] += red[t + s]; __syncthreads(); }
    lgv[c] = red[0] + b3[c] + pb[c];
  }
  if (t == 0) {
    float mx = fmaxf(lgv[0], fmaxf(lgv[1], lgv[2]));
    float e0 = __expf(lgv[0] - mx), e1 = __expf(lgv[1] - mx), e2 = __expf(lgv[2] - mx);
    float inv = 1.0f / (e0 + e1 + e2);
    float p0 = e0 * inv, p1 = e1 * inv, p2 = e2 * inv;
    float c00 = p1;
    float c10 = p0 + p1;
    float c01 = p1 + p2;
    float c11 = (p0 + p1) + p2;
    int t00 = c00 > 0.1f, t10 = c10 > 0.1f, t01 = c01 > 0.1f, t11 = c11 > 0.1f;
    meta[b * 8 + 0] = t00;
    meta[b * 8 + 1] = t10;
    meta[b * 8 + 2] = t01;
    meta[b * 8 + 3] = t11;
    meta[b * 8 + 4] = (t00 != t01) || (t10 != t11);
  }
}

// ---------------------------------------------------------------------------
extern "C" void kernel_launch(void* const* d_in, const int* in_sizes, int n_in,
                              void* d_out, int out_size, void* d_ws, size_t ws_size,
                              hipStream_t stream) {
  const float* x      = (const float*)d_in[0];
  const float* w_qkv  = (const float*)d_in[1];
  const float* w_proj = (const float*)d_in[2];
  const float* b_proj = (const float*)d_in[3];
  const float* ps_w1  = (const float*)d_in[4];
  const float* ps_b1  = (const float*)d_in[5];
  const float* ln_g   = (const float*)d_in[6];
  const float* ln_b   = (const float*)d_in[7];
  const float* ps_w2  = (const float*)d_in[8];
  const float* ps_b2  = (const float*)d_in[9];
  const float* ps_w3  = (const float*)d_in[10];
  const float* ps_b3  = (const float*)d_in[11];
  const float* pbias  = (const float*)d_in[12];
  // d_in[13]=sparse_w, d_in[14]=sparse_b: monotone per-row affine -> top-k invariant.

  float* ws = (float*)d_ws;
  float* pooled = ws;                              // 4096
  int*   meta   = (int*)(ws + 4096);               // 32
  float* h1buf  = ws + 8192;                       // 4096
  float* h2buf  = ws + 12288;                      // 2048
  float* ppsum  = ws + 16384;                      // 262144
  float* ppmax  = ws + 278528;                     // 262144
  float* qw = ws + 1048576;                        // 4M each
  float* kw = qw + 4194304;
  float* vw = kw + 4194304;
  float* ao = vw + 4194304;
  unsigned short* u16b = (unsigned short*)(ao + 4194304);
  unsigned short* qh_  = u16b;                     // 4M u16 each
  unsigned short* ql_  = qh_ + 4194304;
  unsigned short* kh_  = ql_ + 4194304;
  unsigned short* kl_  = kh_ + 4194304;
  unsigned short* vth_ = kl_ + 4194304;
  unsigned short* vtl_ = vth_ + 4194304;
  unsigned short* xs   = vtl_ + 4194304;           // [4096][2048]
  unsigned short* wqs  = xs + 8388608;             // [3072][2048]
  unsigned short* wps  = wqs + 6291456;            // [1024][2048]
  unsigned short* aos  = wps + 2097152;            // [4096][2048]
  float* out = (float*)d_out;

  const size_t NEED_FULL = (size_t)(1048576 + 4 * 4194304) * 4 +
                           (size_t)(6 * 4194304 + 8388608 + 6291456 + 2097152 + 8388608) * 2;

  if (ws_size >= NEED_FULL) {
    pool1<<<256, 256, 0, stream>>>(x, ppsum, ppmax);
    pool2<<<16, 256, 0, stream>>>(ppsum, ppmax, pooled);
    ps_gemv1<<<64, 256, 0, stream>>>(pooled, ps_w1, ps_b1, h1buf);
    ps_ln<<<4, 256, 0, stream>>>(h1buf, ln_g, ln_b);
    ps_gemv2<<<32, 256, 0, stream>>>(h1buf, ps_w2, ps_b2, h2buf);
    ps_logits<<<4, 256, 0, stream>>>(h2buf, ps_w3, ps_b3, pbias, meta);

    prep_split<<<4096, 256, 0, stream>>>(x, xs, 1048576);
    prep_split<<<3072, 256, 0, stream>>>(w_qkv, wqs, 786432);
    prep_split<<<1024, 256, 0, stream>>>(w_proj, wps, 262144);
    gemm_sp<0><<<768, 256, 0, stream>>>(xs, wqs, nullptr, qw, kw, vw, nullptr, 24);

    prep_qk<<<4096, 256, 0, stream>>>(qw, kw, qh_, ql_, kh_, kl_);
    prep_vt<<<dim3(16, 64), 256, 0, stream>>>(vw, vth_, vtl_);
    attn_flash<<<1024, 256, 0, stream>>>(qh_, ql_, kh_, kl_, vth_, vtl_, vw, meta,
                                         (unsigned int*)aos);
    attn_kernel<<<2048, 256, 0, stream>>>(qw, kw, vw, meta, ao,
                                          (unsigned int*)aos, 0, 1);

    gemm_sp<1><<<256, 256, 0, stream>>>(aos, wps, b_proj, nullptr, nullptr, nullptr, out, 8);
  } else {
    // fallback: f32 path (needs only qw..ao region)
    pool_kernel<<<16, 256, 0, stream>>>(x, pooled);
    pattern_kernel<<<4, 256, 0, stream>>>(pooled, ps_w1, ps_b1, ln_g, ln_b,
                                          ps_w2, ps_b2, ps_w3, ps_b3, pbias, meta);
    qkv_gemm<<<dim3(24, 32), 256, 0, stream>>>(x, w_qkv, qw, kw, vw);
    attn_kernel<<<2048, 256, 0, stream>>>(qw, kw, vw, meta, ao, nullptr, 1, 0);
    proj_gemm<<<dim3(8, 32), 256, 0, stream>>>(ao, w_proj, b_proj, out);
  }
}

// Round 5
// 280.661 us; speedup vs baseline: 5.4571x; 1.5000x over previous
//
#include <hip/hip_runtime.h>
#include <math.h>

// Problem constants
#define BB_ 4
#define LL_ 1024
#define DD_ 1024
#define HH_ 16
#define HD_ 64
#define KTOP_ 716
#define SCALE_ 0.125f
#define QSCALE_ 0.1803368801111731f   // 0.125 * log2(e): softmax in exp2 domain

typedef float f4v __attribute__((ext_vector_type(4)));
typedef short s8v __attribute__((ext_vector_type(8)));
typedef __bf16 bf8v __attribute__((ext_vector_type(8)));

static __device__ inline unsigned short f2bf(float f) {
  unsigned u = __float_as_uint(f);
  u += 0x7fffu + ((u >> 16) & 1u);
  return (unsigned short)(u >> 16);
}
static __device__ inline float bf2f(unsigned short h) {
  return __uint_as_float((unsigned)h << 16);
}
static __device__ inline f4v mfma16(s8v a, s8v b, f4v c) {
  union { s8v s; bf8v b; } ua, ub;
  ua.s = a; ub.s = b;
  return __builtin_amdgcn_mfma_f32_16x16x32_bf16(ua.b, ub.b, c, 0, 0, 0);
}
static __device__ inline void gload16(const unsigned short* g, unsigned short* lbase) {
  __builtin_amdgcn_global_load_lds(
      (const __attribute__((address_space(1))) unsigned int*)g,
      (__attribute__((address_space(3))) unsigned int*)lbase, 16, 0, 0);
}

// ---------------------------------------------------------------------------
// pool (2-stage)
// ---------------------------------------------------------------------------
__global__ __launch_bounds__(256) void pool1(const float* __restrict__ x,
                                             float* __restrict__ psum,
                                             float* __restrict__ pmax) {
  int bid = blockIdx.x;            // b*64 + sl
  int b = bid >> 6, sl = bid & 63;
  int t = threadIdx.x;
  float s[4] = {0.f, 0.f, 0.f, 0.f};
  float m[4] = {-INFINITY, -INFINITY, -INFINITY, -INFINITY};
  const float* xb = x + ((size_t)b << 20) + (size_t)sl * 16 * 1024;
  for (int l = 0; l < 16; ++l) {
    #pragma unroll
    for (int dg = 0; dg < 4; ++dg) {
      float v = xb[l * 1024 + dg * 256 + t];
      s[dg] += v;
      m[dg] = fmaxf(m[dg], v);
    }
  }
  #pragma unroll
  for (int dg = 0; dg < 4; ++dg) {
    psum[(size_t)bid * 1024 + dg * 256 + t] = s[dg];
    pmax[(size_t)bid * 1024 + dg * 256 + t] = m[dg];
  }
}

__global__ __launch_bounds__(256) void pool2(const float* __restrict__ psum,
                                             const float* __restrict__ pmax,
                                             float* __restrict__ pooled) {
  int bid = blockIdx.x;            // b*4 + dg
  int b = bid >> 2, dg = bid & 3;
  int d = dg * 256 + threadIdx.x;
  float s = 0.f, m = -INFINITY;
  for (int sl = 0; sl < 64; ++sl) {
    s += psum[((size_t)b * 64 + sl) * 1024 + d];
    m = fmaxf(m, pmax[((size_t)b * 64 + sl) * 1024 + d]);
  }
  pooled[b * 1024 + d] = (s * (1.0f / 1024.0f) + m) * 0.5f;
}

// ---------------------------------------------------------------------------
// pattern selector, staged
// ---------------------------------------------------------------------------
__global__ __launch_bounds__(256) void ps_gemv1(const float* __restrict__ pooled,
                                                const float* __restrict__ w1,
                                                const float* __restrict__ b1,
                                                float* __restrict__ h1) {
  int bid = blockIdx.x;            // b*16 + og
  int b = bid >> 4, og = bid & 15;
  int t = threadIdx.x;
  int ol = t >> 2, ks = t & 3;
  int o = og * 64 + ol;
  const float4* wr = (const float4*)(w1 + (size_t)o * 1024 + ks * 256);
  const float4* pp = (const float4*)(pooled + b * 1024 + ks * 256);
  float acc = 0.f;
  #pragma unroll 8
  for (int j = 0; j < 64; ++j) {
    float4 a = wr[j], p = pp[j];
    acc += a.x * p.x + a.y * p.y + a.z * p.z + a.w * p.w;
  }
  acc += __shfl_xor(acc, 1, 64);
  acc += __shfl_xor(acc, 2, 64);
  if (ks == 0) h1[b * 1024 + o] = acc + b1[o];
}

__global__ __launch_bounds__(256) void ps_ln(float* __restrict__ h1,
                                             const float* __restrict__ lng,
                                             const float* __restrict__ lnb) {
  __shared__ float red[256];
  int b = blockIdx.x, t = threadIdx.x;
  float* hb = h1 + b * 1024;
  float v0[4];
  float ls = 0.f;
  #pragma unroll
  for (int i = 0; i < 4; ++i) { v0[i] = hb[t + 256 * i]; ls += v0[i]; }
  red[t] = ls; __syncthreads();
  for (int s = 128; s > 0; s >>= 1) { if (t < s) red[t] += red[t + s]; __syncthreads(); }
  float mean = red[0] * (1.0f / 1024.0f);
  __syncthreads();
  float lq = 0.f;
  #pragma unroll
  for (int i = 0; i < 4; ++i) { float dv = v0[i] - mean; lq += dv * dv; }
  red[t] = lq; __syncthreads();
  for (int s = 128; s > 0; s >>= 1) { if (t < s) red[t] += red[t + s]; __syncthreads(); }
  float rstd = 1.0f / sqrtf(red[0] * (1.0f / 1024.0f) + 1e-5f);
  #pragma unroll
  for (int i = 0; i < 4; ++i) {
    float v = (v0[i] - mean) * rstd * lng[t + 256 * i] + lnb[t + 256 * i];
    hb[t + 256 * i] = 0.5f * v * (1.0f + erff(v * 0.70710678118654752f));
  }
}

__global__ __launch_bounds__(256) void ps_gemv2(const float* __restrict__ h1,
                                                const float* __restrict__ w2,
                                                const float* __restrict__ b2,
                                                float* __restrict__ h2) {
  int bid = blockIdx.x;            // b*8 + og
  int b = bid >> 3, og = bid & 7;
  int t = threadIdx.x;
  int ol = t >> 2, ks = t & 3;
  int o = og * 64 + ol;
  const float4* wr = (const float4*)(w2 + (size_t)o * 1024 + ks * 256);
  const float4* pp = (const float4*)(h1 + b * 1024 + ks * 256);
  float acc = 0.f;
  #pragma unroll 8
  for (int j = 0; j < 64; ++j) {
    float4 a = wr[j], p = pp[j];
    acc += a.x * p.x + a.y * p.y + a.z * p.z + a.w * p.w;
  }
  acc += __shfl_xor(acc, 1, 64);
  acc += __shfl_xor(acc, 2, 64);
  if (ks == 0) {
    float v = acc + b2[o];
    h2[b * 512 + o] = 0.5f * v * (1.0f + erff(v * 0.70710678118654752f));
  }
}

__global__ __launch_bounds__(256) void ps_logits(const float* __restrict__ h2,
                                                 const float* __restrict__ w3,
                                                 const float* __restrict__ b3,
                                                 const float* __restrict__ pb,
                                                 int* __restrict__ meta) {
  __shared__ float red[256];
  int b = blockIdx.x, t = threadIdx.x;
  float lgv[3];
  for (int c = 0; c < 3; ++c) {
    float p = 0.f;
    for (int i = t; i < 512; i += 256) p += h2[b * 512 + i] * w3[c * 512 + i];
    red[t] = p; __syncthreads();
    for (int s = 128; s > 0; s >>= 1) { if (t < s) red[t] += red[t + s]; __syncthreads(); }
    lgv[c] = red[0] + b3[c] + pb[c];
    __syncthreads();
  }
  if (t == 0) {
    float mx = fmaxf(lgv[0], fmaxf(lgv[1], lgv[2]));
    float e0 = __expf(lgv[0] - mx), e1 = __expf(lgv[1] - mx), e2 = __expf(lgv[2] - mx);
    float inv = 1.0f / (e0 + e1 + e2);
    float p0 = e0 * inv, p1 = e1 * inv, p2 = e2 * inv;
    float c00 = p1;
    float c10 = p0 + p1;
    float c01 = p1 + p2;
    float c11 = (p0 + p1) + p2;
    int t00 = c00 > 0.1f, t10 = c10 > 0.1f, t01 = c01 > 0.1f, t11 = c11 > 0.1f;
    meta[b * 8 + 0] = t00;
    meta[b * 8 + 1] = t10;
    meta[b * 8 + 2] = t01;
    meta[b * 8 + 3] = t11;
    meta[b * 8 + 4] = (t00 != t01) || (t10 != t11);
  }
}

// ---------------------------------------------------------------------------
// prep_split: f32 -> interleaved split-bf16 (out[2i]=hi, out[2i+1]=lo)
// ---------------------------------------------------------------------------
__global__ __launch_bounds__(256) void prep_split(const float* __restrict__ in,
                                                  unsigned short* __restrict__ out2,
                                                  int n4) {
  int i = blockIdx.x * 256 + threadIdx.x;
  if (i >= n4) return;
  float4 v = ((const float4*)in)[i];
  float f[4] = {v.x, v.y, v.z, v.w};
  union { s8v v8; unsigned short u[8]; } o;
  #pragma unroll
  for (int j = 0; j < 4; ++j) {
    unsigned short h = f2bf(f[j]);
    o.u[2 * j] = h;
    o.u[2 * j + 1] = f2bf(f[j] - bf2f(h));
  }
  *(s8v*)(out2 + (size_t)i * 8) = o.v8;
}

// ---------------------------------------------------------------------------
// gemm_sp: C[M][N] = A[M][2048] . B[N][2048] (interleaved split-bf16, K'=2048)
// MODE 0: scatter to q/k/v f32 [B,H,L,64] + split qh/ql, kh/kl (q pre-scaled
//         by QSCALE), transposed split vth/vtl  (folds the old prep passes)
// MODE 1: out = C + bias
// ---------------------------------------------------------------------------
template <int MODE>
__global__ __launch_bounds__(256) void gemm_sp(
    const unsigned short* __restrict__ A, const unsigned short* __restrict__ B,
    const float* __restrict__ bias, float* __restrict__ q, float* __restrict__ k2,
    float* __restrict__ v2,
    unsigned short* __restrict__ qh, unsigned short* __restrict__ ql,
    unsigned short* __restrict__ kh, unsigned short* __restrict__ kl,
    unsigned short* __restrict__ vth, unsigned short* __restrict__ vtl,
    float* __restrict__ out, int Nb) {
  __shared__ unsigned short Asm[128 * 64];
  __shared__ unsigned short Bsm[128 * 64];

  int bid = blockIdx.x;
  int cpx = gridDim.x >> 3;
  int g = (bid & 7) * cpx + (bid >> 3);
  int bm = g / Nb, bn = g % Nb;
  size_t row0 = (size_t)bm * 128, col0 = (size_t)bn * 128;

  int tid = threadIdx.x, lane = tid & 63, wv = tid >> 6;
  int wm = (wv >> 1) << 6, wn = (wv & 1) << 6;
  int rowg = lane >> 4, colc = lane & 15;

  f4v acc[4][4];
  #pragma unroll
  for (int mf = 0; mf < 4; ++mf)
    #pragma unroll
    for (int nf = 0; nf < 4; ++nf) acc[mf][nf] = (f4v){0.f, 0.f, 0.f, 0.f};

  const unsigned short* Abase = A + row0 * 2048;
  const unsigned short* Bbase = B + col0 * 2048;

  int sidx0 = tid;
  for (int kb = 0; kb < 2048; kb += 64) {
    __syncthreads();
    #pragma unroll
    for (int p = 0; p < 4; ++p) {
      int idx = p * 256 + sidx0;
      int row = idx >> 3;
      int ch = idx & 7;
      int sc = ch ^ (row & 7);
      unsigned short* la = &Asm[(size_t)(p * 256 + wv * 64) * 8];
      unsigned short* lb = &Bsm[(size_t)(p * 256 + wv * 64) * 8];
      gload16(Abase + (size_t)row * 2048 + kb + sc * 8, la);
      gload16(Bbase + (size_t)row * 2048 + kb + sc * 8, lb);
    }
    __syncthreads();
    #pragma unroll
    for (int ks = 0; ks < 2; ++ks) {
      s8v af[4], bf_[4];
      #pragma unroll
      for (int mf = 0; mf < 4; ++mf) {
        int row = wm + mf * 16 + colc;
        int kby = (ks * 64 + rowg * 16) ^ ((row & 7) << 4);
        af[mf] = *(const s8v*)((const char*)Asm + row * 128 + kby);
      }
      #pragma unroll
      for (int nf = 0; nf < 4; ++nf) {
        int row = wn + nf * 16 + colc;
        int kby = (ks * 64 + rowg * 16) ^ ((row & 7) << 4);
        bf_[nf] = *(const s8v*)((const char*)Bsm + row * 128 + kby);
      }
      #pragma unroll
      for (int mf = 0; mf < 4; ++mf)
        #pragma unroll
        for (int nf = 0; nf < 4; ++nf)
          acc[mf][nf] = mfma16(af[mf], bf_[nf], acc[mf][nf]);
    }
  }

  if (MODE == 0) {
    int c = (int)(col0 >> 10);   // tile never straddles a 1024 boundary
    #pragma unroll
    for (int mf = 0; mf < 4; ++mf) {
      int m0 = (int)row0 + wm + mf * 16 + rowg * 4;
      int bb = m0 >> 10, l0 = m0 & 1023;   // 4 consecutive l, no wrap
      #pragma unroll
      for (int nf = 0; nf < 4; ++nf) {
        int n = (int)col0 + wn + nf * 16 + colc;
        int hh = (n >> 6) & 15, hd = n & 63;
        int bhl = bb * 16 + hh;
        size_t fbase = ((size_t)bhl * 1024 + l0) * 64 + hd;
        float vals[4];
        #pragma unroll
        for (int r = 0; r < 4; ++r) vals[r] = acc[mf][nf][r];
        float* fdst = (c == 0) ? q : (c == 1) ? k2 : v2;
        #pragma unroll
        for (int r = 0; r < 4; ++r) fdst[fbase + (size_t)r * 64] = vals[r];
        if (c == 2) {
          ushort4 h4, l4;
          #pragma unroll
          for (int r = 0; r < 4; ++r) {
            float f = vals[r];
            unsigned short hi = f2bf(f);
            ((unsigned short*)&h4)[r] = hi;
            ((unsigned short*)&l4)[r] = f2bf(f - bf2f(hi));
          }
          size_t vt = ((size_t)bhl * 64 + hd) * 1024 + l0;
          *(ushort4*)(vth + vt) = h4;
          *(ushort4*)(vtl + vt) = l4;
        } else {
          unsigned short* dh = (c == 0) ? qh : kh;
          unsigned short* dl = (c == 0) ? ql : kl;
          float sc_ = (c == 0) ? QSCALE_ : 1.0f;
          #pragma unroll
          for (int r = 0; r < 4; ++r) {
            float f = vals[r] * sc_;
            unsigned short hi = f2bf(f);
            dh[fbase + (size_t)r * 64] = hi;
            dl[fbase + (size_t)r * 64] = f2bf(f - bf2f(hi));
          }
        }
      }
    }
  } else {
    #pragma unroll
    for (int mf = 0; mf < 4; ++mf) {
      #pragma unroll
      for (int r = 0; r < 4; ++r) {
        int m = (int)row0 + wm + mf * 16 + rowg * 4 + r;
        #pragma unroll
        for (int nf = 0; nf < 4; ++nf) {
          int n = (int)col0 + wn + nf * 16 + colc;
          out[(size_t)m * 1024 + n] = acc[mf][nf][r] + bias[n];
        }
      }
    }
  }
}

// ---------------------------------------------------------------------------
// attn_flash v3: swapped QK^T + per-lane softmax + LDS-staged K/V tiles.
// Per jb, the block cooperatively stages K(hi,lo) and V^T(hi,lo) 64-tiles into
// LDS via global_load_lds with pre-swizzled source; all 4 waves read frags
// with matching XOR-swizzled ds_read_b128 (kills the 4x duplicated L2 reads).
// ---------------------------------------------------------------------------
__global__ __launch_bounds__(256) void attn_flash(
    const unsigned short* __restrict__ qh, const unsigned short* __restrict__ ql,
    const unsigned short* __restrict__ kh, const unsigned short* __restrict__ kl,
    const unsigned short* __restrict__ vth, const unsigned short* __restrict__ vtl,
    const float* __restrict__ vw, const int* __restrict__ meta,
    unsigned int* __restrict__ aou) {
  int n = blockIdx.x;
  int bh = ((n & 7) << 3) | (n >> 7);   // XCD swizzle: one bh per XCD group
  int qt = (n >> 3) & 15;
  int b = bh >> 4, h = bh & 15;
  const int* mb = meta + b * 8;
  if (mb[4]) return;  // sparse regime -> fallback kernel owns this batch
  int t00 = mb[0], t10 = mb[1];

  int tid = threadIdx.x, lane = tid & 63, wv = tid >> 6;
  int g = lane >> 4, colc = lane & 15;
  int q0 = qt * 64 + wv * 16;

  if (!t10) {
    // self-only regime: out row = v row (split-bf16)
    #pragma unroll
    for (int it = 0; it < 4; ++it) {
      int idx = tid + it * 256;
      int r = idx >> 4, dc = (idx & 15) * 4;
      float4 v = *(const float4*)(vw + ((size_t)bh * 1024 + qt * 64 + r) * 64 + dc);
      float f[4] = {v.x, v.y, v.z, v.w};
      uint4 o;
      unsigned* op = (unsigned*)&o;
      #pragma unroll
      for (int j = 0; j < 4; ++j) {
        unsigned short hi = f2bf(f[j]);
        op[j] = (unsigned)hi | ((unsigned)f2bf(f[j] - bf2f(hi)) << 16);
      }
      *(uint4*)(aou + ((size_t)b * 1024 + qt * 64 + r) * 1024 + h * 64 + dc) = o;
    }
    return;
  }
  bool local_only = !t00;

  __shared__ __align__(16) unsigned short Ksm[2][4096];   // [hi/lo][64 rows x 128B]
  __shared__ __align__(16) unsigned short Vsm[2][4096];   // [hi/lo][64 d-rows x 128B]
  __shared__ __align__(16) unsigned short pls[4][16][17][8];

  // Q fragments (B operand: row=i=colc, k=d=g*8+e, 2 k-steps)
  const unsigned short* qb_h = qh + ((size_t)bh * 1024 + q0 + colc) * 64 + g * 8;
  const unsigned short* qb_l = ql + ((size_t)bh * 1024 + q0 + colc) * 64 + g * 8;
  s8v Qh[2], Ql[2];
  Qh[0] = *(const s8v*)(qb_h);      Qh[1] = *(const s8v*)(qb_h + 32);
  Ql[0] = *(const s8v*)(qb_l);      Ql[1] = *(const s8v*)(qb_l + 32);

  f4v O[4];
  #pragma unroll
  for (int df = 0; df < 4; ++df) O[df] = (f4v){0.f, 0.f, 0.f, 0.f};
  float m = -1e30f, lsum = 0.f;   // per-lane scalars: row i = q0+colc

  const unsigned short* khb = kh + ((size_t)bh << 10) * 64;
  const unsigned short* klb = kl + ((size_t)bh << 10) * 64;
  const unsigned short* vhb = vth + ((size_t)bh << 16);
  const unsigned short* vlb = vtl + ((size_t)bh << 16);
  int bq0 = qt * 64;

  for (int jb = 0; jb < 16; ++jb) {
    int jc0 = jb * 64;
    // block-uniform skip (covers all 4 waves' windows)
    if (local_only && (jc0 + 63 < bq0 - 16 || jc0 > bq0 + 79)) continue;

    __syncthreads();   // previous iteration's LDS reads done
    #pragma unroll
    for (int p = 0; p < 2; ++p) {
      int cidx = p * 256 + tid;
      int row = cidx >> 3;
      int sc = (cidx & 7) ^ (row & 7);
      unsigned short* lkh = &Ksm[0][(size_t)(p * 256 + wv * 64) * 8];
      unsigned short* lkl = &Ksm[1][(size_t)(p * 256 + wv * 64) * 8];
      unsigned short* lvh = &Vsm[0][(size_t)(p * 256 + wv * 64) * 8];
      unsigned short* lvl = &Vsm[1][(size_t)(p * 256 + wv * 64) * 8];
      gload16(khb + (size_t)(jc0 + row) * 64 + sc * 8, lkh);
      gload16(klb + (size_t)(jc0 + row) * 64 + sc * 8, lkl);
      gload16(vhb + (size_t)row * 1024 + jc0 + sc * 8, lvh);
      gload16(vlb + (size_t)row * 1024 + jc0 + sc * 8, lvl);
    }
    __syncthreads();   // drains vmcnt -> tiles visible

    bool wact = !(local_only && (jc0 + 63 < q0 - 16 || jc0 > q0 + 31));
    if (wact) {
      // ---- S^T chunk from LDS K: s[jf][r] = S[j=jc0+jf*16+4g+r][i=q0+colc] ----
      f4v s[4];
      #pragma unroll
      for (int jf = 0; jf < 4; ++jf) {
        int row = jf * 16 + colc;
        int sw = (row & 7) << 4;
        const char* kp0 = (const char*)&Ksm[0][0] + row * 128;
        const char* kp1 = (const char*)&Ksm[1][0] + row * 128;
        s8v Kh0 = *(const s8v*)(kp0 + ((g * 16) ^ sw));
        s8v Kh1 = *(const s8v*)(kp0 + ((64 + g * 16) ^ sw));
        s8v Kl0 = *(const s8v*)(kp1 + ((g * 16) ^ sw));
        s8v Kl1 = *(const s8v*)(kp1 + ((64 + g * 16) ^ sw));
        f4v acc = (f4v){0.f, 0.f, 0.f, 0.f};
        acc = mfma16(Kh0, Qh[0], acc);
        acc = mfma16(Kh1, Qh[1], acc);
        acc = mfma16(Kl0, Qh[0], acc);
        acc = mfma16(Kl1, Qh[1], acc);
        acc = mfma16(Kh0, Ql[0], acc);
        acc = mfma16(Kh1, Ql[1], acc);
        s[jf] = acc;
      }

      // ---- mask + per-row (per-lane) max ----
      float cm = -1e30f;
      #pragma unroll
      for (int jf = 0; jf < 4; ++jf) {
        #pragma unroll
        for (int r = 0; r < 4; ++r) {
          float sv = s[jf][r];
          if (local_only) {
            int j = jc0 + jf * 16 + 4 * g + r;
            int i = q0 + colc;
            int dj = i - j;
            if (dj > 16 || dj < -16) { sv = -1e30f; s[jf][r] = sv; }
          }
          cm = fmaxf(cm, sv);
        }
      }
      cm = fmaxf(cm, __shfl_xor(cm, 16, 64));
      cm = fmaxf(cm, __shfl_xor(cm, 32, 64));

      bool grow = __any(cm > m);
      float fac = 1.0f;
      if (grow) {
        float mn = fmaxf(m, cm);
        fac = __builtin_amdgcn_exp2f(m - mn);
        m = mn;
      }

      // ---- P = exp2(s - m), split bf16 hi/lo, staged [i][j] contiguous ----
      float psum = 0.f;
      #pragma unroll
      for (int jf = 0; jf < 4; ++jf) {
        union { s8v v; unsigned short u[8]; } pk;
        #pragma unroll
        for (int r = 0; r < 4; ++r) {
          float sv = s[jf][r];
          float p = (sv > -1e29f) ? __builtin_amdgcn_exp2f(sv - m) : 0.f;
          psum += p;
          unsigned short hi = f2bf(p);
          pk.u[r] = hi;
          pk.u[4 + r] = f2bf(p - bf2f(hi));
        }
        *(s8v*)&pls[wv][colc][jf * 4 + g][0] = pk.v;   // ds_write_b128
      }
      psum += __shfl_xor(psum, 16, 64);
      psum += __shfl_xor(psum, 32, 64);

      if (grow) {
        lsum = lsum * fac + psum;
        float fo[4];
        #pragma unroll
        for (int r = 0; r < 4; ++r)
          fo[r] = __shfl(fac, (lane & 48) + g * 4 + r, 64);
        #pragma unroll
        for (int df = 0; df < 4; ++df) {
          #pragma unroll
          for (int r = 0; r < 4; ++r) O[df][r] *= fo[r];
        }
      } else {
        lsum += psum;
      }

      // ---- PV: A = P[i][j], B = V^T fragments from LDS ----
      s8v Ph[2], Pl[2];
      {
        const ushort4* pw = (const ushort4*)&pls[wv][colc][0][0];
        #pragma unroll
        for (int ks = 0; ks < 2; ++ks) {
          int b0 = 8 * ks + 2 * g;
          union { s8v v; ushort4 q[2]; } uh, ul;
          uh.q[0] = pw[2 * b0];     ul.q[0] = pw[2 * b0 + 1];
          uh.q[1] = pw[2 * b0 + 2]; ul.q[1] = pw[2 * b0 + 3];
          Ph[ks] = uh.v; Pl[ks] = ul.v;
        }
      }
      #pragma unroll
      for (int df = 0; df < 4; ++df) {
        int row = df * 16 + colc;
        int sw = (row & 7) << 4;
        const char* vp0 = (const char*)&Vsm[0][0] + row * 128;
        const char* vp1 = (const char*)&Vsm[1][0] + row * 128;
        #pragma unroll
        for (int ks = 0; ks < 2; ++ks) {
          s8v Vh = *(const s8v*)(vp0 + ((ks * 64 + g * 16) ^ sw));
          s8v Vl = *(const s8v*)(vp1 + ((ks * 64 + g * 16) ^ sw));
          O[df] = mfma16(Ph[ks], Vh, O[df]);
          O[df] = mfma16(Ph[ks], Vl, O[df]);
          O[df] = mfma16(Pl[ks], Vh, O[df]);
        }
      }
    }
  }

  // ---- epilogue: gather lsum per C-row, normalize, write split-bf16 ----
  float linv[4];
  #pragma unroll
  for (int r = 0; r < 4; ++r)
    linv[r] = 1.0f / __shfl(lsum, (lane & 48) + g * 4 + r, 64);
  #pragma unroll
  for (int df = 0; df < 4; ++df) {
    #pragma unroll
    for (int r = 0; r < 4; ++r) {
      int i = q0 + g * 4 + r;
      float val = O[df][r] * linv[r];
      unsigned short hi = f2bf(val);
      unsigned o = (unsigned)hi | ((unsigned)f2bf(val - bf2f(hi)) << 16);
      aou[((size_t)b * 1024 + i) * 1024 + h * 64 + df * 16 + colc] = o;
    }
  }
}

// ---------------------------------------------------------------------------
// attn_kernel fallback (sparse topk regime, or small-ws force path)
// ---------------------------------------------------------------------------
__global__ __launch_bounds__(256) void attn_kernel(const float* __restrict__ qw,
                                                   const float* __restrict__ kw,
                                                   const float* __restrict__ vw,
                                                   const int* __restrict__ meta,
                                                   float* __restrict__ ao,
                                                   unsigned int* __restrict__ aou,
                                                   int force, int write_split) {
  __shared__ float S[32][1028];
  __shared__ float qs[32][68];
  __shared__ float kc[64][68];
  __shared__ float rowsum_s[32];

  int tid = threadIdx.x;
  int lane = tid & 63;
  int wv = tid >> 6;
  int id = blockIdx.x;
  int rt = id & 31;
  int h = (id >> 5) & 15;
  int b = id >> 9;
  int bh = b * 16 + h;
  int row0 = rt * 32;

  const int* mb = meta + b * 8;
  int t00 = mb[0], t10 = mb[1], t01 = mb[2], t11 = mb[3], needs = mb[4];
  if (!force && !needs) return;

  {
    const float4* qp = (const float4*)(qw + ((size_t)bh * 1024 + row0 + wv * 8) * 64);
    #pragma unroll
    for (int i = 0; i < 2; ++i) {
      int f = lane + 64 * i;
      float4 v = qp[f];
      int r = wv * 8 + (f >> 4);
      int d = (f & 15) << 2;
      qs[r][d] = v.x; qs[r][d + 1] = v.y; qs[r][d + 2] = v.z; qs[r][d + 3] = v.w;
    }
  }

  int lr = lane >> 4, lc = lane & 15;
  int r_a = wv * 8 + lr * 2;
  int r_b = r_a + 1;

  for (int cb = 0; cb < 16; ++cb) {
    __syncthreads();
    const float4* kp = (const float4*)(kw + ((size_t)bh * 1024 + cb * 64) * 64);
    #pragma unroll
    for (int i = 0; i < 4; ++i) {
      int f = tid + 256 * i;
      float4 v = kp[f];
      int c = f >> 4, d = (f & 15) << 2;
      kc[c][d] = v.x; kc[c][d + 1] = v.y; kc[c][d + 2] = v.z; kc[c][d + 3] = v.w;
    }
    __syncthreads();

    float acc0[4] = {0.f, 0.f, 0.f, 0.f};
    float acc1[4] = {0.f, 0.f, 0.f, 0.f};
    for (int dq = 0; dq < 64; dq += 4) {
      float4 qa = *(const float4*)&qs[r_a][dq];
      float4 qb = *(const float4*)&qs[r_b][dq];
      #pragma unroll
      for (int cj = 0; cj < 4; ++cj) {
        float4 kv = *(const float4*)&kc[lc + 16 * cj][dq];
        acc0[cj] += qa.x * kv.x + qa.y * kv.y + qa.z * kv.z + qa.w * kv.w;
        acc1[cj] += qb.x * kv.x + qb.y * kv.y + qb.z * kv.z + qb.w * kv.w;
      }
    }
    #pragma unroll
    for (int cj = 0; cj < 4; ++cj) {
      S[r_a][cb * 64 + lc + 16 * cj] = acc0[cj] * SCALE_;
      S[r_b][cb * 64 + lc + 16 * cj] = acc1[cj] * SCALE_;
    }
  }

  for (int rr = 0; rr < 8; ++rr) {
    int r = wv * 8 + rr;
    int grow = row0 + r;
    float sv[16];
    unsigned kv[16];
    #pragma unroll
    for (int i2 = 0; i2 < 16; ++i2) {
      float s = S[r][lane + 64 * i2];
      sv[i2] = s;
      unsigned u = __float_as_uint(s);
      kv[i2] = (u & 0x80000000u) ? ~u : (u | 0x80000000u);
    }
    unsigned T = 0u;
    if (needs) {
      for (int bit = 31; bit >= 0; --bit) {
        unsigned cand = T | (1u << bit);
        int cnt = 0;
        #pragma unroll
        for (int i2 = 0; i2 < 16; ++i2) cnt += (kv[i2] >= cand) ? 1 : 0;
        for (int off = 32; off; off >>= 1) cnt += __shfl_xor(cnt, off, 64);
        if (cnt >= KTOP_) T = cand;
      }
    }
    float mx = -INFINITY;
    int kept = 0;
    unsigned kmask = 0;
    #pragma unroll
    for (int i2 = 0; i2 < 16; ++i2) {
      int j = lane + 64 * i2;
      int sp = (kv[i2] >= T) ? 1 : 0;
      int dj = grow - j;
      int lo = (dj <= 16 && dj >= -16) ? 1 : 0;
      int keep = sp ? (lo ? t11 : t01) : (lo ? t10 : t00);
      kept += keep;
      if (keep) { kmask |= (1u << i2); mx = fmaxf(mx, sv[i2]); }
    }
    for (int off = 32; off; off >>= 1) {
      mx = fmaxf(mx, __shfl_xor(mx, off, 64));
      kept += __shfl_xor(kept, off, 64);
    }
    if (kept == 0) {
      #pragma unroll
      for (int i2 = 0; i2 < 16; ++i2) {
        int j = lane + 64 * i2;
        S[r][j] = (j == grow) ? 1.0f : 0.0f;
      }
      if (lane == 0) rowsum_s[r] = 1.0f;
    } else {
      float sum = 0.f;
      #pragma unroll
      for (int i2 = 0; i2 < 16; ++i2) {
        float p = ((kmask >> i2) & 1u) ? __expf(sv[i2] - mx) : 0.0f;
        sum += p;
        S[r][lane + 64 * i2] = p;
      }
      for (int off = 32; off; off >>= 1) sum += __shfl_xor(sum, off, 64);
      if (lane == 0) rowsum_s[r] = sum;
    }
  }

  int ld = lane & 15;
  int d0 = ld * 4;
  float4 oa0 = make_float4(0.f, 0.f, 0.f, 0.f);
  float4 oa1 = make_float4(0.f, 0.f, 0.f, 0.f);
  for (int vb = 0; vb < 16; ++vb) {
    __syncthreads();
    const float4* vp = (const float4*)(vw + ((size_t)bh * 1024 + vb * 64) * 64);
    #pragma unroll
    for (int i = 0; i < 4; ++i) {
      int f = tid + 256 * i;
      float4 v = vp[f];
      int c = f >> 4, d = (f & 15) << 2;
      kc[c][d] = v.x; kc[c][d + 1] = v.y; kc[c][d + 2] = v.z; kc[c][d + 3] = v.w;
    }
    __syncthreads();
    for (int cq = 0; cq < 64; cq += 4) {
      float4 pa = *(const float4*)&S[r_a][vb * 64 + cq];
      float4 pb = *(const float4*)&S[r_b][vb * 64 + cq];
      float par[4] = {pa.x, pa.y, pa.z, pa.w};
      float pbr[4] = {pb.x, pb.y, pb.z, pb.w};
      #pragma unroll
      for (int tt = 0; tt < 4; ++tt) {
        float4 vv = *(const float4*)&kc[cq + tt][d0];
        oa0.x += par[tt] * vv.x; oa0.y += par[tt] * vv.y;
        oa0.z += par[tt] * vv.z; oa0.w += par[tt] * vv.w;
        oa1.x += pbr[tt] * vv.x; oa1.y += pbr[tt] * vv.y;
        oa1.z += pbr[tt] * vv.z; oa1.w += pbr[tt] * vv.w;
      }
    }
  }
  float inv0 = 1.0f / rowsum_s[r_a];
  float inv1 = 1.0f / rowsum_s[r_b];
  float v0[4] = {oa0.x * inv0, oa0.y * inv0, oa0.z * inv0, oa0.w * inv0};
  float v1[4] = {oa1.x * inv1, oa1.y * inv1, oa1.z * inv1, oa1.w * inv1};
  if (write_split) {
    uint4 o0, o1;
    unsigned* o0p = (unsigned*)&o0;
    unsigned* o1p = (unsigned*)&o1;
    #pragma unroll
    for (int j = 0; j < 4; ++j) {
      unsigned short h0 = f2bf(v0[j]);
      o0p[j] = (unsigned)h0 | ((unsigned)f2bf(v0[j] - bf2f(h0)) << 16);
      unsigned short h1 = f2bf(v1[j]);
      o1p[j] = (unsigned)h1 | ((unsigned)f2bf(v1[j] - bf2f(h1)) << 16);
    }
    *(uint4*)(aou + ((size_t)b * 1024 + row0 + r_a) * 1024 + h * 64 + d0) = o0;
    *(uint4*)(aou + ((size_t)b * 1024 + row0 + r_b) * 1024 + h * 64 + d0) = o1;
  } else {
    float* p0 = ao + ((size_t)b * 1024 + row0 + r_a) * 1024 + h * 64 + d0;
    float* p1 = ao + ((size_t)b * 1024 + row0 + r_b) * 1024 + h * 64 + d0;
    *(float4*)p0 = make_float4(v0[0], v0[1], v0[2], v0[3]);
    *(float4*)p1 = make_float4(v1[0], v1[1], v1[2], v1[3]);
  }
}

// ---------------------------------------------------------------------------
// Fallback f32 kernels (small-ws path only)
// ---------------------------------------------------------------------------
__global__ __launch_bounds__(256) void pool_kernel(const float* __restrict__ x,
                                                   float* __restrict__ pooled) {
  int g = blockIdx.x * 256 + threadIdx.x;
  int b = g >> 10, d = g & 1023;
  const float* xp = x + ((size_t)b << 20) + d;
  float s = 0.f, m = -INFINITY;
  #pragma unroll 4
  for (int l = 0; l < LL_; ++l) {
    float v = xp[(size_t)l << 10];
    s += v;
    m = fmaxf(m, v);
  }
  pooled[g] = (s * (1.0f / 1024.0f) + m) * 0.5f;
}

__global__ __launch_bounds__(256) void qkv_gemm(const float* __restrict__ X,
                                                const float* __restrict__ W,
                                                float* __restrict__ qw,
                                                float* __restrict__ kw,
                                                float* __restrict__ vw) {
  __shared__ float As[8][128];
  __shared__ float Bs[8][128];
  int tid = threadIdx.x;
  int row0 = blockIdx.y * 128, col0 = blockIdx.x * 128;
  int lr = tid >> 1;
  int lk = (tid & 1) * 4;
  int ty = tid >> 4, tx = tid & 15;
  float acc[8][8] = {};

  for (int kb = 0; kb < 1024; kb += 8) {
    float4 a4 = *(const float4*)(X + (size_t)(row0 + lr) * 1024 + kb + lk);
    float4 b4 = *(const float4*)(W + (size_t)(col0 + lr) * 1024 + kb + lk);
    __syncthreads();
    As[lk + 0][lr] = a4.x; As[lk + 1][lr] = a4.y; As[lk + 2][lr] = a4.z; As[lk + 3][lr] = a4.w;
    Bs[lk + 0][lr] = b4.x; Bs[lk + 1][lr] = b4.y; Bs[lk + 2][lr] = b4.z; Bs[lk + 3][lr] = b4.w;
    __syncthreads();
    #pragma unroll
    for (int kk = 0; kk < 8; ++kk) {
      float av[8], bv[8];
      #pragma unroll
      for (int i = 0; i < 8; ++i) av[i] = As[kk][ty * 8 + i];
      #pragma unroll
      for (int j = 0; j < 8; ++j) bv[j] = Bs[kk][tx * 8 + j];
      #pragma unroll
      for (int i = 0; i < 8; ++i)
        #pragma unroll
        for (int j = 0; j < 8; ++j) acc[i][j] += av[i] * bv[j];
    }
  }
  #pragma unroll
  for (int i = 0; i < 8; ++i) {
    int m = row0 + ty * 8 + i;
    int bb = m >> 10, l = m & 1023;
    #pragma unroll
    for (int j = 0; j < 8; j += 4) {
      int n = col0 + tx * 8 + j;
      int c = n >> 10;
      int hh = (n >> 6) & 15;
      int hd = n & 63;
      float* base = (c == 0) ? qw : (c == 1) ? kw : vw;
      float* dst = base + ((size_t)(bb * 16 + hh) * 1024 + l) * 64 + hd;
      *(float4*)dst = make_float4(acc[i][j], acc[i][j + 1], acc[i][j + 2], acc[i][j + 3]);
    }
  }
}

__global__ __launch_bounds__(256) void proj_gemm(const float* __restrict__ A,
                                                 const float* __restrict__ W,
                                                 const float* __restrict__ bias,
                                                 float* __restrict__ out) {
  __shared__ float As[8][128];
  __shared__ float Bs[8][128];
  int tid = threadIdx.x;
  int row0 = blockIdx.y * 128, col0 = blockIdx.x * 128;
  int lr = tid >> 1;
  int lk = (tid & 1) * 4;
  int ty = tid >> 4, tx = tid & 15;
  float acc[8][8] = {};

  for (int kb = 0; kb < 1024; kb += 8) {
    float4 a4 = *(const float4*)(A + (size_t)(row0 + lr) * 1024 + kb + lk);
    float4 b4 = *(const float4*)(W + (size_t)(col0 + lr) * 1024 + kb + lk);
    __syncthreads();
    As[lk + 0][lr] = a4.x; As[lk + 1][lr] = a4.y; As[lk + 2][lr] = a4.z; As[lk + 3][lr] = a4.w;
    Bs[lk + 0][lr] = b4.x; Bs[lk + 1][lr] = b4.y; Bs[lk + 2][lr] = b4.z; Bs[lk + 3][lr] = b4.w;
    __syncthreads();
    #pragma unroll
    for (int kk = 0; kk < 8; ++kk) {
      float av[8], bv[8];
      #pragma unroll
      for (int i = 0; i < 8; ++i) av[i] = As[kk][ty * 8 + i];
      #pragma unroll
      for (int j = 0; j < 8; ++j) bv[j] = Bs[kk][tx * 8 + j];
      #pragma unroll
      for (int i = 0; i < 8; ++i)
        #pragma unroll
        for (int j = 0; j < 8; ++j) acc[i][j] += av[i] * bv[j];
    }
  }
  #pragma unroll
  for (int i = 0; i < 8; ++i) {
    int m = row0 + ty * 8 + i;
    #pragma unroll
    for (int j = 0; j < 8; j += 4) {
      int n = col0 + tx * 8 + j;
      *(float4*)(out + (size_t)m * 1024 + n) =
          make_float4(acc[i][j] + bias[n], acc[i][j + 1] + bias[n + 1],
                      acc[i][j + 2] + bias[n + 2], acc[i][j + 3] + bias[n + 3]);
    }
  }
}

__global__ __launch_bounds__(256) void pattern_kernel(
    const float* __restrict__ pooled,
    const float* __restrict__ w1, const float* __restrict__ b1,
    const float* __restrict__ lng, const float* __restrict__ lnb,
    const float* __restrict__ w2, const float* __restrict__ b2,
    const float* __restrict__ w3, const float* __restrict__ b3,
    const float* __restrict__ pb, int* __restrict__ meta) {
  __shared__ float pool_s[1024];
  __shared__ float h1[1024];
  __shared__ float h2[512];
  __shared__ float red[256];
  int b = blockIdx.x, t = threadIdx.x;

  for (int i = t; i < 1024; i += 256) pool_s[i] = pooled[b * 1024 + i];
  __syncthreads();
  for (int o = t; o < 1024; o += 256) {
    float acc = b1[o];
    const float* wr = w1 + (size_t)o * 1024;
    for (int k = 0; k < 1024; ++k) acc += pool_s[k] * wr[k];
    h1[o] = acc;
  }
  __syncthreads();
  float ls = 0.f;
  for (int i = t; i < 1024; i += 256) ls += h1[i];
  red[t] = ls; __syncthreads();
  for (int s = 128; s > 0; s >>= 1) { if (t < s) red[t] += red[t + s]; __syncthreads(); }
  float mean = red[0] * (1.0f / 1024.0f);
  __syncthreads();
  float lq = 0.f;
  for (int i = t; i < 1024; i += 256) { float dv = h1[i] - mean; lq += dv * dv; }
  red[t] = lq; __syncthreads();
  for (int s = 128; s > 0; s >>= 1) { if (t < s) red[t] += red[t + s]; __syncthreads(); }
  float var = red[0] * (1.0f / 1024.0f);
  float rstd = 1.0f / sqrtf(var + 1e-5f);
  __syncthreads();
  for (int i = t; i < 1024; i += 256) {
    float v = (h1[i] - mean) * rstd * lng[i] + lnb[i];
    h1[i] = 0.5f * v * (1.0f + erff(v * 0.70710678118654752f));
  }
  __syncthreads();
  for (int o = t; o < 512; o += 256) {
    float acc = b2[o];
    const float* wr = w2 + (size_t)o * 1024;
    for (int k = 0; k < 1024; ++k) acc += h1[k] * wr[k];
    h2[o] = 0.5f * acc * (1.0f + erff(acc * 0.70710678118654752f));
  }
  __syncthreads();
  float lgv[3];
  for (int c = 0; c < 3; ++c) {
    float p = 0.f;
    for (int i = t; i < 512; i += 256) p += h2[i] * w3[c * 512 + i];
    __syncthreads();
    red[t] = p; __syncthreads();
    for (int s = 128; s > 0; s >>= 1) { if (t < s) red[t] += red[t + s]; __syncthreads(); }
    lgv[c] = red[0] + b3[c] + pb[c];
  }
  if (t == 0) {
    float mx = fmaxf(lgv[0], fmaxf(lgv[1], lgv[2]));
    float e0 = __expf(lgv[0] - mx), e1 = __expf(lgv[1] - mx), e2 = __expf(lgv[2] - mx);
    float inv = 1.0f / (e0 + e1 + e2);
    float p0 = e0 * inv, p1 = e1 * inv, p2 = e2 * inv;
    float c00 = p1;
    float c10 = p0 + p1;
    float c01 = p1 + p2;
    float c11 = (p0 + p1) + p2;
    int t00 = c00 > 0.1f, t10 = c10 > 0.1f, t01 = c01 > 0.1f, t11 = c11 > 0.1f;
    meta[b * 8 + 0] = t00;
    meta[b * 8 + 1] = t10;
    meta[b * 8 + 2] = t01;
    meta[b * 8 + 3] = t11;
    meta[b * 8 + 4] = (t00 != t01) || (t10 != t11);
  }
}

// ---------------------------------------------------------------------------
extern "C" void kernel_launch(void* const* d_in, const int* in_sizes, int n_in,
                              void* d_out, int out_size, void* d_ws, size_t ws_size,
                              hipStream_t stream) {
  const float* x      = (const float*)d_in[0];
  const float* w_qkv  = (const float*)d_in[1];
  const float* w_proj = (const float*)d_in[2];
  const float* b_proj = (const float*)d_in[3];
  const float* ps_w1  = (const float*)d_in[4];
  const float* ps_b1  = (const float*)d_in[5];
  const float* ln_g   = (const float*)d_in[6];
  const float* ln_b   = (const float*)d_in[7];
  const float* ps_w2  = (const float*)d_in[8];
  const float* ps_b2  = (const float*)d_in[9];
  const float* ps_w3  = (const float*)d_in[10];
  const float* ps_b3  = (const float*)d_in[11];
  const float* pbias  = (const float*)d_in[12];
  // d_in[13]=sparse_w, d_in[14]=sparse_b: monotone per-row affine -> top-k invariant.

  float* ws = (float*)d_ws;
  float* pooled = ws;                              // 4096
  int*   meta   = (int*)(ws + 4096);               // 32
  float* h1buf  = ws + 8192;                       // 4096
  float* h2buf  = ws + 12288;                      // 2048
  float* ppsum  = ws + 16384;                      // 262144
  float* ppmax  = ws + 278528;                     // 262144
  float* qw = ws + 1048576;                        // 4M each
  float* kw = qw + 4194304;
  float* vw = kw + 4194304;
  float* ao = vw + 4194304;
  unsigned short* u16b = (unsigned short*)(ao + 4194304);
  unsigned short* qh_  = u16b;                     // 4M u16 each
  unsigned short* ql_  = qh_ + 4194304;
  unsigned short* kh_  = ql_ + 4194304;
  unsigned short* kl_  = kh_ + 4194304;
  unsigned short* vth_ = kl_ + 4194304;
  unsigned short* vtl_ = vth_ + 4194304;
  unsigned short* xs   = vtl_ + 4194304;           // [4096][2048]
  unsigned short* wqs  = xs + 8388608;             // [3072][2048]
  unsigned short* wps  = wqs + 6291456;            // [1024][2048]
  unsigned short* aos  = wps + 2097152;            // [4096][2048]
  float* out = (float*)d_out;

  const size_t NEED_FULL = (size_t)(1048576 + 4 * 4194304) * 4 +
                           (size_t)(6 * 4194304 + 8388608 + 6291456 + 2097152 + 8388608) * 2;

  if (ws_size >= NEED_FULL) {
    pool1<<<256, 256, 0, stream>>>(x, ppsum, ppmax);
    pool2<<<16, 256, 0, stream>>>(ppsum, ppmax, pooled);
    ps_gemv1<<<64, 256, 0, stream>>>(pooled, ps_w1, ps_b1, h1buf);
    ps_ln<<<4, 256, 0, stream>>>(h1buf, ln_g, ln_b);
    ps_gemv2<<<32, 256, 0, stream>>>(h1buf, ps_w2, ps_b2, h2buf);
    ps_logits<<<4, 256, 0, stream>>>(h2buf, ps_w3, ps_b3, pbias, meta);

    prep_split<<<4096, 256, 0, stream>>>(x, xs, 1048576);
    prep_split<<<3072, 256, 0, stream>>>(w_qkv, wqs, 786432);
    prep_split<<<1024, 256, 0, stream>>>(w_proj, wps, 262144);
    gemm_sp<0><<<768, 256, 0, stream>>>(xs, wqs, nullptr, qw, kw, vw,
                                        qh_, ql_, kh_, kl_, vth_, vtl_, nullptr, 24);

    attn_flash<<<1024, 256, 0, stream>>>(qh_, ql_, kh_, kl_, vth_, vtl_, vw, meta,
                                         (unsigned int*)aos);
    attn_kernel<<<2048, 256, 0, stream>>>(qw, kw, vw, meta, ao,
                                          (unsigned int*)aos, 0, 1);

    gemm_sp<1><<<256, 256, 0, stream>>>(aos, wps, b_proj, nullptr, nullptr, nullptr,
                                        nullptr, nullptr, nullptr, nullptr, nullptr,
                                        nullptr, out, 8);
  } else {
    // fallback: f32 path (needs only qw..ao region)
    pool_kernel<<<16, 256, 0, stream>>>(x, pooled);
    pattern_kernel<<<4, 256, 0, stream>>>(pooled, ps_w1, ps_b1, ln_g, ln_b,
                                          ps_w2, ps_b2, ps_w3, ps_b3, pbias, meta);
    qkv_gemm<<<dim3(24, 32), 256, 0, stream>>>(x, w_qkv, qw, kw, vw);
    attn_kernel<<<2048, 256, 0, stream>>>(qw, kw, vw, meta, ao, nullptr, 1, 0);
    proj_gemm<<<dim3(8, 32), 256, 0, stream>>>(ao, w_proj, b_proj, out);
  }
}

// Round 6
// 265.064 us; speedup vs baseline: 5.7782x; 1.0588x over previous
//
#include <hip/hip_runtime.h>
#include <math.h>

// Problem constants
#define BB_ 4
#define LL_ 1024
#define DD_ 1024
#define HH_ 16
#define HD_ 64
#define KTOP_ 716
#define SCALE_ 0.125f
#define QSCALE_ 0.1803368801111731f   // 0.125 * log2(e): softmax in exp2 domain
#define LN2_ 0.6931471805599453f

typedef float f4v __attribute__((ext_vector_type(4)));
typedef short s8v __attribute__((ext_vector_type(8)));
typedef __bf16 bf8v __attribute__((ext_vector_type(8)));

static __device__ inline unsigned short f2bf(float f) {
  unsigned u = __float_as_uint(f);
  u += 0x7fffu + ((u >> 16) & 1u);
  return (unsigned short)(u >> 16);
}
static __device__ inline float bf2f(unsigned short h) {
  return __uint_as_float((unsigned)h << 16);
}
static __device__ inline float pair2f(unsigned u) {
  return bf2f((unsigned short)(u & 0xffff)) + bf2f((unsigned short)(u >> 16));
}
static __device__ inline unsigned f2pair(float f) {
  unsigned short hi = f2bf(f);
  return (unsigned)hi | ((unsigned)f2bf(f - bf2f(hi)) << 16);
}
static __device__ inline f4v mfma16(s8v a, s8v b, f4v c) {
  union { s8v s; bf8v b; } ua, ub;
  ua.s = a; ub.s = b;
  return __builtin_amdgcn_mfma_f32_16x16x32_bf16(ua.b, ub.b, c, 0, 0, 0);
}
static __device__ inline void gload16(const unsigned short* g, unsigned short* lbase) {
  __builtin_amdgcn_global_load_lds(
      (const __attribute__((address_space(1))) unsigned int*)g,
      (__attribute__((address_space(3))) unsigned int*)lbase, 16, 0, 0);
}

// ---------------------------------------------------------------------------
// pool1 (fused: also emits xs = interleaved split of x) + pool2
// ---------------------------------------------------------------------------
__global__ __launch_bounds__(256) void pool1(const float* __restrict__ x,
                                             float* __restrict__ psum,
                                             float* __restrict__ pmax,
                                             unsigned* __restrict__ xsu) {
  int bid = blockIdx.x;            // b*64 + sl
  int b = bid >> 6, sl = bid & 63;
  int t = threadIdx.x;
  float s[4] = {0.f, 0.f, 0.f, 0.f};
  float m[4] = {-INFINITY, -INFINITY, -INFINITY, -INFINITY};
  const float* xb = x + ((size_t)b << 20) + (size_t)sl * 16 * 1024;
  unsigned* xo = xsu + ((size_t)(b * 1024 + sl * 16)) * 1024;
  for (int l = 0; l < 16; ++l) {
    #pragma unroll
    for (int dg = 0; dg < 4; ++dg) {
      float v = xb[l * 1024 + dg * 256 + t];
      s[dg] += v;
      m[dg] = fmaxf(m[dg], v);
      xo[(size_t)l * 1024 + dg * 256 + t] = f2pair(v);
    }
  }
  #pragma unroll
  for (int dg = 0; dg < 4; ++dg) {
    psum[(size_t)bid * 1024 + dg * 256 + t] = s[dg];
    pmax[(size_t)bid * 1024 + dg * 256 + t] = m[dg];
  }
}

__global__ __launch_bounds__(256) void pool2(const float* __restrict__ psum,
                                             const float* __restrict__ pmax,
                                             float* __restrict__ pooled) {
  int bid = blockIdx.x;            // b*4 + dg
  int b = bid >> 2, dg = bid & 3;
  int d = dg * 256 + threadIdx.x;
  float s = 0.f, m = -INFINITY;
  for (int sl = 0; sl < 64; ++sl) {
    s += psum[((size_t)b * 64 + sl) * 1024 + d];
    m = fmaxf(m, pmax[((size_t)b * 64 + sl) * 1024 + d]);
  }
  pooled[b * 1024 + d] = (s * (1.0f / 1024.0f) + m) * 0.5f;
}

// ---------------------------------------------------------------------------
// pattern selector, staged
// ---------------------------------------------------------------------------
__global__ __launch_bounds__(256) void ps_gemv1(const float* __restrict__ pooled,
                                                const float* __restrict__ w1,
                                                const float* __restrict__ b1,
                                                float* __restrict__ h1) {
  int bid = blockIdx.x;            // b*16 + og
  int b = bid >> 4, og = bid & 15;
  int t = threadIdx.x;
  int ol = t >> 2, ks = t & 3;
  int o = og * 64 + ol;
  const float4* wr = (const float4*)(w1 + (size_t)o * 1024 + ks * 256);
  const float4* pp = (const float4*)(pooled + b * 1024 + ks * 256);
  float acc = 0.f;
  #pragma unroll 8
  for (int j = 0; j < 64; ++j) {
    float4 a = wr[j], p = pp[j];
    acc += a.x * p.x + a.y * p.y + a.z * p.z + a.w * p.w;
  }
  acc += __shfl_xor(acc, 1, 64);
  acc += __shfl_xor(acc, 2, 64);
  if (ks == 0) h1[b * 1024 + o] = acc + b1[o];
}

__global__ __launch_bounds__(256) void ps_ln(float* __restrict__ h1,
                                             const float* __restrict__ lng,
                                             const float* __restrict__ lnb) {
  __shared__ float red[256];
  int b = blockIdx.x, t = threadIdx.x;
  float* hb = h1 + b * 1024;
  float v0[4];
  float ls = 0.f;
  #pragma unroll
  for (int i = 0; i < 4; ++i) { v0[i] = hb[t + 256 * i]; ls += v0[i]; }
  red[t] = ls; __syncthreads();
  for (int s = 128; s > 0; s >>= 1) { if (t < s) red[t] += red[t + s]; __syncthreads(); }
  float mean = red[0] * (1.0f / 1024.0f);
  __syncthreads();
  float lq = 0.f;
  #pragma unroll
  for (int i = 0; i < 4; ++i) { float dv = v0[i] - mean; lq += dv * dv; }
  red[t] = lq; __syncthreads();
  for (int s = 128; s > 0; s >>= 1) { if (t < s) red[t] += red[t + s]; __syncthreads(); }
  float rstd = 1.0f / sqrtf(red[0] * (1.0f / 1024.0f) + 1e-5f);
  #pragma unroll
  for (int i = 0; i < 4; ++i) {
    float v = (v0[i] - mean) * rstd * lng[t + 256 * i] + lnb[t + 256 * i];
    hb[t + 256 * i] = 0.5f * v * (1.0f + erff(v * 0.70710678118654752f));
  }
}

__global__ __launch_bounds__(256) void ps_gemv2(const float* __restrict__ h1,
                                                const float* __restrict__ w2,
                                                const float* __restrict__ b2,
                                                float* __restrict__ h2) {
  int bid = blockIdx.x;            // b*8 + og
  int b = bid >> 3, og = bid & 7;
  int t = threadIdx.x;
  int ol = t >> 2, ks = t & 3;
  int o = og * 64 + ol;
  const float4* wr = (const float4*)(w2 + (size_t)o * 1024 + ks * 256);
  const float4* pp = (const float4*)(h1 + b * 1024 + ks * 256);
  float acc = 0.f;
  #pragma unroll 8
  for (int j = 0; j < 64; ++j) {
    float4 a = wr[j], p = pp[j];
    acc += a.x * p.x + a.y * p.y + a.z * p.z + a.w * p.w;
  }
  acc += __shfl_xor(acc, 1, 64);
  acc += __shfl_xor(acc, 2, 64);
  if (ks == 0) {
    float v = acc + b2[o];
    h2[b * 512 + o] = 0.5f * v * (1.0f + erff(v * 0.70710678118654752f));
  }
}

__global__ __launch_bounds__(256) void ps_logits(const float* __restrict__ h2,
                                                 const float* __restrict__ w3,
                                                 const float* __restrict__ b3,
                                                 const float* __restrict__ pb,
                                                 int* __restrict__ meta) {
  __shared__ float red[256];
  int b = blockIdx.x, t = threadIdx.x;
  float lgv[3];
  for (int c = 0; c < 3; ++c) {
    float p = 0.f;
    for (int i = t; i < 512; i += 256) p += h2[b * 512 + i] * w3[c * 512 + i];
    red[t] = p; __syncthreads();
    for (int s = 128; s > 0; s >>= 1) { if (t < s) red[t] += red[t + s]; __syncthreads(); }
    lgv[c] = red[0] + b3[c] + pb[c];
    __syncthreads();
  }
  if (t == 0) {
    float mx = fmaxf(lgv[0], fmaxf(lgv[1], lgv[2]));
    float e0 = __expf(lgv[0] - mx), e1 = __expf(lgv[1] - mx), e2 = __expf(lgv[2] - mx);
    float inv = 1.0f / (e0 + e1 + e2);
    float p0 = e0 * inv, p1 = e1 * inv, p2 = e2 * inv;
    float c00 = p1;
    float c10 = p0 + p1;
    float c01 = p1 + p2;
    float c11 = (p0 + p1) + p2;
    int t00 = c00 > 0.1f, t10 = c10 > 0.1f, t01 = c01 > 0.1f, t11 = c11 > 0.1f;
    meta[b * 8 + 0] = t00;
    meta[b * 8 + 1] = t10;
    meta[b * 8 + 2] = t01;
    meta[b * 8 + 3] = t11;
    meta[b * 8 + 4] = (t00 != t01) || (t10 != t11);
  }
}

// ---------------------------------------------------------------------------
// prep_split: f32 -> interleaved split-bf16 (weights)
// ---------------------------------------------------------------------------
__global__ __launch_bounds__(256) void prep_split(const float* __restrict__ in,
                                                  unsigned short* __restrict__ out2,
                                                  int n4) {
  int i = blockIdx.x * 256 + threadIdx.x;
  if (i >= n4) return;
  float4 v = ((const float4*)in)[i];
  float f[4] = {v.x, v.y, v.z, v.w};
  union { s8v v8; unsigned u[4]; } o;
  #pragma unroll
  for (int j = 0; j < 4; ++j) o.u[j] = f2pair(f[j]);
  *(s8v*)(out2 + (size_t)i * 8) = o.v8;
}

// ---------------------------------------------------------------------------
// gemm_sp: C[M][N] = A[M][2048] . B[N][2048] (interleaved split-bf16, K'=2048)
// MODE 0: write qx/kx (interleaved split, q pre-scaled by QSCALE, layout
//         [bh][l][128]) and vx (transposed [bh][d][2048])
// MODE 1: out = C + bias (f32)
// ---------------------------------------------------------------------------
template <int MODE>
__global__ __launch_bounds__(256) void gemm_sp(
    const unsigned short* __restrict__ A, const unsigned short* __restrict__ B,
    const float* __restrict__ bias,
    unsigned* __restrict__ qxu, unsigned* __restrict__ kxu,
    unsigned short* __restrict__ vxo,
    float* __restrict__ out, int Nb) {
  __shared__ unsigned short Asm[128 * 64];
  __shared__ unsigned short Bsm[128 * 64];

  int bid = blockIdx.x;
  int cpx = gridDim.x >> 3;
  int g = (bid & 7) * cpx + (bid >> 3);
  int bm = g / Nb, bn = g % Nb;
  size_t row0 = (size_t)bm * 128, col0 = (size_t)bn * 128;

  int tid = threadIdx.x, lane = tid & 63, wv = tid >> 6;
  int wm = (wv >> 1) << 6, wn = (wv & 1) << 6;
  int rowg = lane >> 4, colc = lane & 15;

  f4v acc[4][4];
  #pragma unroll
  for (int mf = 0; mf < 4; ++mf)
    #pragma unroll
    for (int nf = 0; nf < 4; ++nf) acc[mf][nf] = (f4v){0.f, 0.f, 0.f, 0.f};

  const unsigned short* Abase = A + row0 * 2048;
  const unsigned short* Bbase = B + col0 * 2048;

  int sidx0 = tid;
  for (int kb = 0; kb < 2048; kb += 64) {
    __syncthreads();
    #pragma unroll
    for (int p = 0; p < 4; ++p) {
      int idx = p * 256 + sidx0;
      int row = idx >> 3;
      int ch = idx & 7;
      int sc = ch ^ (row & 7);
      unsigned short* la = &Asm[(size_t)(p * 256 + wv * 64) * 8];
      unsigned short* lb = &Bsm[(size_t)(p * 256 + wv * 64) * 8];
      gload16(Abase + (size_t)row * 2048 + kb + sc * 8, la);
      gload16(Bbase + (size_t)row * 2048 + kb + sc * 8, lb);
    }
    __syncthreads();
    #pragma unroll
    for (int ks = 0; ks < 2; ++ks) {
      s8v af[4], bf_[4];
      #pragma unroll
      for (int mf = 0; mf < 4; ++mf) {
        int row = wm + mf * 16 + colc;
        int kby = (ks * 64 + rowg * 16) ^ ((row & 7) << 4);
        af[mf] = *(const s8v*)((const char*)Asm + row * 128 + kby);
      }
      #pragma unroll
      for (int nf = 0; nf < 4; ++nf) {
        int row = wn + nf * 16 + colc;
        int kby = (ks * 64 + rowg * 16) ^ ((row & 7) << 4);
        bf_[nf] = *(const s8v*)((const char*)Bsm + row * 128 + kby);
      }
      #pragma unroll
      for (int mf = 0; mf < 4; ++mf)
        #pragma unroll
        for (int nf = 0; nf < 4; ++nf)
          acc[mf][nf] = mfma16(af[mf], bf_[nf], acc[mf][nf]);
    }
  }

  if (MODE == 0) {
    int c = (int)(col0 >> 10);   // 0=q 1=k 2=v (tiles never straddle)
    #pragma unroll
    for (int mf = 0; mf < 4; ++mf) {
      int m0 = (int)row0 + wm + mf * 16 + rowg * 4;
      int bb = m0 >> 10, l0 = m0 & 1023;   // l0 % 4 == 0
      #pragma unroll
      for (int nf = 0; nf < 4; ++nf) {
        int n = (int)col0 + wn + nf * 16 + colc;
        int hh = (n >> 6) & 15, hd = n & 63;
        int bhl = bb * 16 + hh;
        if (c == 2) {
          union { s8v v; unsigned short u[8]; } pk;
          #pragma unroll
          for (int r = 0; r < 4; ++r) {
            float f = acc[mf][nf][r];
            unsigned short hi = f2bf(f);
            pk.u[2 * r] = hi;
            pk.u[2 * r + 1] = f2bf(f - bf2f(hi));
          }
          *(s8v*)(vxo + ((size_t)bhl * 64 + hd) * 2048 + 2 * l0) = pk.v;
        } else {
          unsigned* dst = ((c == 0) ? qxu : kxu) + ((size_t)bhl * 1024 + l0) * 64 + hd;
          float sc_ = (c == 0) ? QSCALE_ : 1.0f;
          #pragma unroll
          for (int r = 0; r < 4; ++r)
            dst[(size_t)r * 64] = f2pair(acc[mf][nf][r] * sc_);
        }
      }
    }
  } else {
    #pragma unroll
    for (int mf = 0; mf < 4; ++mf) {
      #pragma unroll
      for (int r = 0; r < 4; ++r) {
        int m = (int)row0 + wm + mf * 16 + rowg * 4 + r;
        #pragma unroll
        for (int nf = 0; nf < 4; ++nf) {
          int n = (int)col0 + wn + nf * 16 + colc;
          out[(size_t)m * 1024 + n] = acc[mf][nf][r] + bias[n];
        }
      }
    }
  }
}

// ---------------------------------------------------------------------------
// attn_flash v4: interleaved-split operands (K'=128 per 64-d / 64-j chunk).
// 16 MFMA per QK chunk + 16 per PV chunk (exact 4-term products).
// ---------------------------------------------------------------------------
__global__ __launch_bounds__(256) void attn_flash(
    const unsigned short* __restrict__ qx, const unsigned short* __restrict__ kx,
    const unsigned short* __restrict__ vx, const int* __restrict__ meta,
    unsigned int* __restrict__ aou) {
  int n = blockIdx.x;
  int bh = ((n & 7) << 3) | (n >> 7);   // XCD swizzle
  int qt = (n >> 3) & 15;
  int b = bh >> 4, h = bh & 15;
  const int* mb = meta + b * 8;
  if (mb[4]) return;  // sparse regime -> attn_sparse owns this batch
  int t00 = mb[0], t10 = mb[1];

  int tid = threadIdx.x, lane = tid & 63, wv = tid >> 6;
  int g = lane >> 4, colc = lane & 15;
  int q0 = qt * 64 + wv * 16;

  if (!t10) {
    // self-only: out row = v row; vx pairs are already the aou format
    const unsigned* vxu = (const unsigned*)vx;
    #pragma unroll
    for (int it = 0; it < 4; ++it) {
      int idx = tid + it * 256;
      int r = idx >> 4, dc = (idx & 15) * 4;
      unsigned o0 = vxu[((size_t)bh * 64 + dc + 0) * 1024 + qt * 64 + r];
      unsigned o1 = vxu[((size_t)bh * 64 + dc + 1) * 1024 + qt * 64 + r];
      unsigned o2 = vxu[((size_t)bh * 64 + dc + 2) * 1024 + qt * 64 + r];
      unsigned o3 = vxu[((size_t)bh * 64 + dc + 3) * 1024 + qt * 64 + r];
      *(uint4*)(aou + ((size_t)b * 1024 + qt * 64 + r) * 1024 + h * 64 + dc) =
          make_uint4(o0, o1, o2, o3);
    }
    return;
  }
  bool local_only = !t00;

  __shared__ __align__(16) unsigned short Ksm[64 * 128];   // 64 j-rows x 256B
  __shared__ __align__(16) unsigned short Vsm[64 * 128];   // 64 d-rows x 256B
  __shared__ __align__(16) unsigned short px[4][16][136];  // P interleaved + pad

  // Q fragments (B operand: row=i=colc, 4 k-steps cover K'=128)
  const unsigned short* qb = qx + ((size_t)bh * 1024 + q0 + colc) * 128 + g * 8;
  s8v Q[4];
  #pragma unroll
  for (int ks = 0; ks < 4; ++ks) Q[ks] = *(const s8v*)(qb + ks * 32);

  f4v O[4];
  #pragma unroll
  for (int df = 0; df < 4; ++df) O[df] = (f4v){0.f, 0.f, 0.f, 0.f};
  float m = -1e30f, lsum = 0.f;   // per-lane: row i = q0+colc

  const unsigned short* kxb = kx + ((size_t)bh << 10) * 128;
  const unsigned short* vxb = vx + ((size_t)(bh * 64)) * 2048;
  int bq0 = qt * 64;

  for (int jb = 0; jb < 16; ++jb) {
    int jc0 = jb * 64;
    if (local_only && (jc0 + 63 < bq0 - 16 || jc0 > bq0 + 79)) continue;

    __syncthreads();
    #pragma unroll
    for (int p = 0; p < 4; ++p) {
      int cidx = p * 256 + tid;           // 1024 chunks of 16B per array
      int row = cidx >> 4, ch = cidx & 15;
      int sc = ch ^ (row & 15);
      unsigned short* lk = &Ksm[(size_t)(p * 256 + wv * 64) * 8];
      unsigned short* lv = &Vsm[(size_t)(p * 256 + wv * 64) * 8];
      gload16(kxb + (size_t)(jc0 + row) * 128 + sc * 8, lk);
      gload16(vxb + (size_t)row * 2048 + 2 * jc0 + sc * 8, lv);
    }
    __syncthreads();

    bool wact = !(local_only && (jc0 + 63 < q0 - 16 || jc0 > q0 + 31));
    if (wact) {
      // ---- S^T chunk: s[jf][r] = S[j=jc0+jf*16+4g+r][i=q0+colc] ----
      f4v s[4];
      #pragma unroll
      for (int jf = 0; jf < 4; ++jf) {
        int row = jf * 16 + colc;
        int sw = (row & 15) << 4;
        const char* kp = (const char*)Ksm + row * 256;
        f4v acc = (f4v){0.f, 0.f, 0.f, 0.f};
        #pragma unroll
        for (int ks = 0; ks < 4; ++ks) {
          s8v Kf = *(const s8v*)(kp + ((ks * 64 + g * 16) ^ sw));
          acc = mfma16(Kf, Q[ks], acc);
        }
        s[jf] = acc;
      }

      // ---- mask + per-row (per-lane) max ----
      float cm = -1e30f;
      #pragma unroll
      for (int jf = 0; jf < 4; ++jf) {
        #pragma unroll
        for (int r = 0; r < 4; ++r) {
          float sv = s[jf][r];
          if (local_only) {
            int j = jc0 + jf * 16 + 4 * g + r;
            int i = q0 + colc;
            int dj = i - j;
            if (dj > 16 || dj < -16) { sv = -1e30f; s[jf][r] = sv; }
          }
          cm = fmaxf(cm, sv);
        }
      }
      cm = fmaxf(cm, __shfl_xor(cm, 16, 64));
      cm = fmaxf(cm, __shfl_xor(cm, 32, 64));

      bool grow = __any(cm > m);
      float fac = 1.0f;
      if (grow) {
        float mn = fmaxf(m, cm);
        fac = __builtin_amdgcn_exp2f(m - mn);
        m = mn;
      }

      // ---- P = exp2(s - m), interleaved (hi,lo) pairs along j ----
      float psum = 0.f;
      #pragma unroll
      for (int jf = 0; jf < 4; ++jf) {
        union { s8v v; unsigned short u[8]; } pk;
        #pragma unroll
        for (int r = 0; r < 4; ++r) {
          float sv = s[jf][r];
          float p = (sv > -1e29f) ? __builtin_amdgcn_exp2f(sv - m) : 0.f;
          psum += p;
          unsigned short hi = f2bf(p);
          pk.u[2 * r] = hi;
          pk.u[2 * r + 1] = f2bf(p - bf2f(hi));
        }
        *(s8v*)&px[wv][colc][2 * (jf * 16 + 4 * g)] = pk.v;   // ds_write_b128
      }
      psum += __shfl_xor(psum, 16, 64);
      psum += __shfl_xor(psum, 32, 64);

      if (grow) {
        lsum = lsum * fac + psum;
        float fo[4];
        #pragma unroll
        for (int r = 0; r < 4; ++r)
          fo[r] = __shfl(fac, (lane & 48) + g * 4 + r, 64);
        #pragma unroll
        for (int df = 0; df < 4; ++df) {
          #pragma unroll
          for (int r = 0; r < 4; ++r) O[df][r] *= fo[r];
        }
      } else {
        lsum += psum;
      }

      // ---- PV: A = P interleaved, B = V^T interleaved fragments ----
      s8v Pf[4];
      #pragma unroll
      for (int ks = 0; ks < 4; ++ks)
        Pf[ks] = *(const s8v*)&px[wv][colc][ks * 32 + g * 8];
      #pragma unroll
      for (int df = 0; df < 4; ++df) {
        int row = df * 16 + colc;
        int sw = (row & 15) << 4;
        const char* vp = (const char*)Vsm + row * 256;
        #pragma unroll
        for (int ks = 0; ks < 4; ++ks) {
          s8v Vf = *(const s8v*)(vp + ((ks * 64 + g * 16) ^ sw));
          O[df] = mfma16(Pf[ks], Vf, O[df]);
        }
      }
    }
  }

  // ---- epilogue ----
  float linv[4];
  #pragma unroll
  for (int r = 0; r < 4; ++r)
    linv[r] = 1.0f / __shfl(lsum, (lane & 48) + g * 4 + r, 64);
  #pragma unroll
  for (int df = 0; df < 4; ++df) {
    #pragma unroll
    for (int r = 0; r < 4; ++r) {
      int i = q0 + g * 4 + r;
      aou[((size_t)b * 1024 + i) * 1024 + h * 64 + df * 16 + colc] =
          f2pair(O[df][r] * linv[r]);
    }
  }
}

// ---------------------------------------------------------------------------
// attn_sparse: top-k regime fallback (full path). Reads interleaved qx/kx/vx,
// reconstructs f32 (scores rescaled by ln2 -> exact reference e-domain math).
// ---------------------------------------------------------------------------
__global__ __launch_bounds__(256) void attn_sparse(
    const unsigned short* __restrict__ qx, const unsigned short* __restrict__ kx,
    const unsigned short* __restrict__ vx, const int* __restrict__ meta,
    unsigned int* __restrict__ aou) {
  __shared__ float S[32][1028];
  __shared__ float qs[32][68];
  __shared__ float kc[64][68];
  __shared__ float rowsum_s[32];

  int tid = threadIdx.x;
  int lane = tid & 63;
  int wv = tid >> 6;
  int id = blockIdx.x;
  int rt = id & 31;
  int h = (id >> 5) & 15;
  int b = id >> 9;
  int bh = b * 16 + h;
  int row0 = rt * 32;

  const int* mb = meta + b * 8;
  int t00 = mb[0], t10 = mb[1], t01 = mb[2], t11 = mb[3], needs = mb[4];
  if (!needs) return;

  const unsigned* qxu = (const unsigned*)qx;
  const unsigned* kxu = (const unsigned*)kx;
  const unsigned* vxu = (const unsigned*)vx;

  // qs stage: 32 rows x 64 d
  #pragma unroll
  for (int i = 0; i < 8; ++i) {
    int idx = tid + 256 * i;
    int r = idx >> 6, d = idx & 63;
    qs[r][d] = pair2f(qxu[((size_t)bh * 1024 + row0 + r) * 64 + d]);
  }

  int lr = lane >> 4, lc = lane & 15;
  int r_a = wv * 8 + lr * 2;
  int r_b = r_a + 1;

  for (int cb = 0; cb < 16; ++cb) {
    __syncthreads();
    #pragma unroll
    for (int i = 0; i < 4; ++i) {
      int idx = tid + 256 * i;          // 1024 uint4
      int cc = idx >> 4, d0 = (idx & 15) * 4;
      uint4 u4 = *(const uint4*)(kxu + ((size_t)bh * 1024 + cb * 64 + cc) * 64 + d0);
      kc[cc][d0 + 0] = pair2f(u4.x);
      kc[cc][d0 + 1] = pair2f(u4.y);
      kc[cc][d0 + 2] = pair2f(u4.z);
      kc[cc][d0 + 3] = pair2f(u4.w);
    }
    __syncthreads();

    float acc0[4] = {0.f, 0.f, 0.f, 0.f};
    float acc1[4] = {0.f, 0.f, 0.f, 0.f};
    for (int dq = 0; dq < 64; dq += 4) {
      float4 qa = *(const float4*)&qs[r_a][dq];
      float4 qb = *(const float4*)&qs[r_b][dq];
      #pragma unroll
      for (int cj = 0; cj < 4; ++cj) {
        float4 kv = *(const float4*)&kc[lc + 16 * cj][dq];
        acc0[cj] += qa.x * kv.x + qa.y * kv.y + qa.z * kv.z + qa.w * kv.w;
        acc1[cj] += qb.x * kv.x + qb.y * kv.y + qb.z * kv.z + qb.w * kv.w;
      }
    }
    // q was pre-scaled by QSCALE (0.125*log2e); *ln2 restores reference scores
    #pragma unroll
    for (int cj = 0; cj < 4; ++cj) {
      S[r_a][cb * 64 + lc + 16 * cj] = acc0[cj] * LN2_;
      S[r_b][cb * 64 + lc + 16 * cj] = acc1[cj] * LN2_;
    }
  }

  for (int rr = 0; rr < 8; ++rr) {
    int r = wv * 8 + rr;
    int grow = row0 + r;
    float sv[16];
    unsigned kv[16];
    #pragma unroll
    for (int i2 = 0; i2 < 16; ++i2) {
      float s = S[r][lane + 64 * i2];
      sv[i2] = s;
      unsigned u = __float_as_uint(s);
      kv[i2] = (u & 0x80000000u) ? ~u : (u | 0x80000000u);
    }
    unsigned T = 0u;
    for (int bit = 31; bit >= 0; --bit) {
      unsigned cand = T | (1u << bit);
      int cnt = 0;
      #pragma unroll
      for (int i2 = 0; i2 < 16; ++i2) cnt += (kv[i2] >= cand) ? 1 : 0;
      for (int off = 32; off; off >>= 1) cnt += __shfl_xor(cnt, off, 64);
      if (cnt >= KTOP_) T = cand;
    }
    float mx = -INFINITY;
    int kept = 0;
    unsigned kmask = 0;
    #pragma unroll
    for (int i2 = 0; i2 < 16; ++i2) {
      int j = lane + 64 * i2;
      int sp = (kv[i2] >= T) ? 1 : 0;
      int dj = grow - j;
      int lo = (dj <= 16 && dj >= -16) ? 1 : 0;
      int keep = sp ? (lo ? t11 : t01) : (lo ? t10 : t00);
      kept += keep;
      if (keep) { kmask |= (1u << i2); mx = fmaxf(mx, sv[i2]); }
    }
    for (int off = 32; off; off >>= 1) {
      mx = fmaxf(mx, __shfl_xor(mx, off, 64));
      kept += __shfl_xor(kept, off, 64);
    }
    if (kept == 0) {
      #pragma unroll
      for (int i2 = 0; i2 < 16; ++i2) {
        int j = lane + 64 * i2;
        S[r][j] = (j == grow) ? 1.0f : 0.0f;
      }
      if (lane == 0) rowsum_s[r] = 1.0f;
    } else {
      float sum = 0.f;
      #pragma unroll
      for (int i2 = 0; i2 < 16; ++i2) {
        float p = ((kmask >> i2) & 1u) ? __expf(sv[i2] - mx) : 0.0f;
        sum += p;
        S[r][lane + 64 * i2] = p;
      }
      for (int off = 32; off; off >>= 1) sum += __shfl_xor(sum, off, 64);
      if (lane == 0) rowsum_s[r] = sum;
    }
  }

  int ld = lane & 15;
  int d0 = ld * 4;
  float4 oa0 = make_float4(0.f, 0.f, 0.f, 0.f);
  float4 oa1 = make_float4(0.f, 0.f, 0.f, 0.f);
  for (int vb = 0; vb < 16; ++vb) {
    __syncthreads();
    #pragma unroll
    for (int i = 0; i < 4; ++i) {
      int idx = tid + 256 * i;          // 1024 uint4 (transposed source)
      int d = idx >> 4, c0 = (idx & 15) * 4;
      uint4 u4 = *(const uint4*)(vxu + ((size_t)bh * 64 + d) * 1024 + vb * 64 + c0);
      kc[c0 + 0][d] = pair2f(u4.x);
      kc[c0 + 1][d] = pair2f(u4.y);
      kc[c0 + 2][d] = pair2f(u4.z);
      kc[c0 + 3][d] = pair2f(u4.w);
    }
    __syncthreads();
    for (int cq = 0; cq < 64; cq += 4) {
      float4 pa = *(const float4*)&S[r_a][vb * 64 + cq];
      float4 pb = *(const float4*)&S[r_b][vb * 64 + cq];
      float par[4] = {pa.x, pa.y, pa.z, pa.w};
      float pbr[4] = {pb.x, pb.y, pb.z, pb.w};
      #pragma unroll
      for (int tt = 0; tt < 4; ++tt) {
        float4 vv = *(const float4*)&kc[cq + tt][d0];
        oa0.x += par[tt] * vv.x; oa0.y += par[tt] * vv.y;
        oa0.z += par[tt] * vv.z; oa0.w += par[tt] * vv.w;
        oa1.x += pbr[tt] * vv.x; oa1.y += pbr[tt] * vv.y;
        oa1.z += pbr[tt] * vv.z; oa1.w += pbr[tt] * vv.w;
      }
    }
  }
  float inv0 = 1.0f / rowsum_s[r_a];
  float inv1 = 1.0f / rowsum_s[r_b];
  uint4 o0, o1;
  unsigned* o0p = (unsigned*)&o0;
  unsigned* o1p = (unsigned*)&o1;
  float v0[4] = {oa0.x * inv0, oa0.y * inv0, oa0.z * inv0, oa0.w * inv0};
  float v1[4] = {oa1.x * inv1, oa1.y * inv1, oa1.z * inv1, oa1.w * inv1};
  #pragma unroll
  for (int j = 0; j < 4; ++j) {
    o0p[j] = f2pair(v0[j]);
    o1p[j] = f2pair(v1[j]);
  }
  *(uint4*)(aou + ((size_t)b * 1024 + row0 + r_a) * 1024 + h * 64 + d0) = o0;
  *(uint4*)(aou + ((size_t)b * 1024 + row0 + r_b) * 1024 + h * 64 + d0) = o1;
}

// ---------------------------------------------------------------------------
// Fallback f32 kernels (small-ws force path only)
// ---------------------------------------------------------------------------
__global__ __launch_bounds__(256) void pool_kernel(const float* __restrict__ x,
                                                   float* __restrict__ pooled) {
  int g = blockIdx.x * 256 + threadIdx.x;
  int b = g >> 10, d = g & 1023;
  const float* xp = x + ((size_t)b << 20) + d;
  float s = 0.f, m = -INFINITY;
  #pragma unroll 4
  for (int l = 0; l < LL_; ++l) {
    float v = xp[(size_t)l << 10];
    s += v;
    m = fmaxf(m, v);
  }
  pooled[g] = (s * (1.0f / 1024.0f) + m) * 0.5f;
}

__global__ __launch_bounds__(256) void qkv_gemm(const float* __restrict__ X,
                                                const float* __restrict__ W,
                                                float* __restrict__ qw,
                                                float* __restrict__ kw,
                                                float* __restrict__ vw) {
  __shared__ float As[8][128];
  __shared__ float Bs[8][128];
  int tid = threadIdx.x;
  int row0 = blockIdx.y * 128, col0 = blockIdx.x * 128;
  int lr = tid >> 1;
  int lk = (tid & 1) * 4;
  int ty = tid >> 4, tx = tid & 15;
  float acc[8][8] = {};

  for (int kb = 0; kb < 1024; kb += 8) {
    float4 a4 = *(const float4*)(X + (size_t)(row0 + lr) * 1024 + kb + lk);
    float4 b4 = *(const float4*)(W + (size_t)(col0 + lr) * 1024 + kb + lk);
    __syncthreads();
    As[lk + 0][lr] = a4.x; As[lk + 1][lr] = a4.y; As[lk + 2][lr] = a4.z; As[lk + 3][lr] = a4.w;
    Bs[lk + 0][lr] = b4.x; Bs[lk + 1][lr] = b4.y; Bs[lk + 2][lr] = b4.z; Bs[lk + 3][lr] = b4.w;
    __syncthreads();
    #pragma unroll
    for (int kk = 0; kk < 8; ++kk) {
      float av[8], bv[8];
      #pragma unroll
      for (int i = 0; i < 8; ++i) av[i] = As[kk][ty * 8 + i];
      #pragma unroll
      for (int j = 0; j < 8; ++j) bv[j] = Bs[kk][tx * 8 + j];
      #pragma unroll
      for (int i = 0; i < 8; ++i)
        #pragma unroll
        for (int j = 0; j < 8; ++j) acc[i][j] += av[i] * bv[j];
    }
  }
  #pragma unroll
  for (int i = 0; i < 8; ++i) {
    int m = row0 + ty * 8 + i;
    int bb = m >> 10, l = m & 1023;
    #pragma unroll
    for (int j = 0; j < 8; j += 4) {
      int n = col0 + tx * 8 + j;
      int c = n >> 10;
      int hh = (n >> 6) & 15;
      int hd = n & 63;
      float* base = (c == 0) ? qw : (c == 1) ? kw : vw;
      float* dst = base + ((size_t)(bb * 16 + hh) * 1024 + l) * 64 + hd;
      *(float4*)dst = make_float4(acc[i][j], acc[i][j + 1], acc[i][j + 2], acc[i][j + 3]);
    }
  }
}

__global__ __launch_bounds__(256) void proj_gemm(const float* __restrict__ A,
                                                 const float* __restrict__ W,
                                                 const float* __restrict__ bias,
                                                 float* __restrict__ out) {
  __shared__ float As[8][128];
  __shared__ float Bs[8][128];
  int tid = threadIdx.x;
  int row0 = blockIdx.y * 128, col0 = blockIdx.x * 128;
  int lr = tid >> 1;
  int lk = (tid & 1) * 4;
  int ty = tid >> 4, tx = tid & 15;
  float acc[8][8] = {};

  for (int kb = 0; kb < 1024; kb += 8) {
    float4 a4 = *(const float4*)(A + (size_t)(row0 + lr) * 1024 + kb + lk);
    float4 b4 = *(const float4*)(W + (size_t)(col0 + lr) * 1024 + kb + lk);
    __syncthreads();
    As[lk + 0][lr] = a4.x; As[lk + 1][lr] = a4.y; As[lk + 2][lr] = a4.z; As[lk + 3][lr] = a4.w;
    Bs[lk + 0][lr] = b4.x; Bs[lk + 1][lr] = b4.y; Bs[lk + 2][lr] = b4.z; Bs[lk + 3][lr] = b4.w;
    __syncthreads();
    #pragma unroll
    for (int kk = 0; kk < 8; ++kk) {
      float av[8], bv[8];
      #pragma unroll
      for (int i = 0; i < 8; ++i) av[i] = As[kk][ty * 8 + i];
      #pragma unroll
      for (int j = 0; j < 8; ++j) bv[j] = Bs[kk][tx * 8 + j];
      #pragma unroll
      for (int i = 0; i < 8; ++i)
        #pragma unroll
        for (int j = 0; j < 8; ++j) acc[i][j] += av[i] * bv[j];
    }
  }
  #pragma unroll
  for (int i = 0; i < 8; ++i) {
    int m = row0 + ty * 8 + i;
    #pragma unroll
    for (int j = 0; j < 8; j += 4) {
      int n = col0 + tx * 8 + j;
      *(float4*)(out + (size_t)m * 1024 + n) =
          make_float4(acc[i][j] + bias[n], acc[i][j + 1] + bias[n + 1],
                      acc[i][j + 2] + bias[n + 2], acc[i][j + 3] + bias[n + 3]);
    }
  }
}

__global__ __launch_bounds__(256) void pattern_kernel(
    const float* __restrict__ pooled,
    const float* __restrict__ w1, const float* __restrict__ b1,
    const float* __restrict__ lng, const float* __restrict__ lnb,
    const float* __restrict__ w2, const float* __restrict__ b2,
    const float* __restrict__ w3, const float* __restrict__ b3,
    const float* __restrict__ pb, int* __restrict__ meta) {
  __shared__ float pool_s[1024];
  __shared__ float h1[1024];
  __shared__ float h2[512];
  __shared__ float red[256];
  int b = blockIdx.x, t = threadIdx.x;

  for (int i = t; i < 1024; i += 256) pool_s[i] = pooled[b * 1024 + i];
  __syncthreads();
  for (int o = t; o < 1024; o += 256) {
    float acc = b1[o];
    const float* wr = w1 + (size_t)o * 1024;
    for (int k = 0; k < 1024; ++k) acc += pool_s[k] * wr[k];
    h1[o] = acc;
  }
  __syncthreads();
  float ls = 0.f;
  for (int i = t; i < 1024; i += 256) ls += h1[i];
  red[t] = ls; __syncthreads();
  for (int s = 128; s > 0; s >>= 1) { if (t < s) red[t] += red[t + s]; __syncthreads(); }
  float mean = red[0] * (1.0f / 1024.0f);
  __syncthreads();
  float lq = 0.f;
  for (int i = t; i < 1024; i += 256) { float dv = h1[i] - mean; lq += dv * dv; }
  red[t] = lq; __syncthreads();
  for (int s = 128; s > 0; s >>= 1) { if (t < s) red[t] += red[t + s]; __syncthreads(); }
  float var = red[0] * (1.0f / 1024.0f);
  float rstd = 1.0f / sqrtf(var + 1e-5f);
  __syncthreads();
  for (int i = t; i < 1024; i += 256) {
    float v = (h1[i] - mean) * rstd * lng[i] + lnb[i];
    h1[i] = 0.5f * v * (1.0f + erff(v * 0.70710678118654752f));
  }
  __syncthreads();
  for (int o = t; o < 512; o += 256) {
    float acc = b2[o];
    const float* wr = w2 + (size_t)o * 1024;
    for (int k = 0; k < 1024; ++k) acc += h1[k] * wr[k];
    h2[o] = 0.5f * acc * (1.0f + erff(acc * 0.70710678118654752f));
  }
  __syncthreads();
  float lgv[3];
  for (int c = 0; c < 3; ++c) {
    float p = 0.f;
    for (int i = t; i < 512; i += 256) p += h2[i] * w3[c * 512 + i];
    __syncthreads();
    red[t] = p; __syncthreads();
    for (int s = 128; s > 0; s >>= 1) { if (t < s) red[t] += red[t + s]; __syncthreads(); }
    lgv[c] = red[0] + b3[c] + pb[c];
  }
  if (t == 0) {
    float mx = fmaxf(lgv[0], fmaxf(lgv[1], lgv[2]));
    float e0 = __expf(lgv[0] - mx), e1 = __expf(lgv[1] - mx), e2 = __expf(lgv[2] - mx);
    float inv = 1.0f / (e0 + e1 + e2);
    float p0 = e0 * inv, p1 = e1 * inv, p2 = e2 * inv;
    float c00 = p1;
    float c10 = p0 + p1;
    float c01 = p1 + p2;
    float c11 = (p0 + p1) + p2;
    int t00 = c00 > 0.1f, t10 = c10 > 0.1f, t01 = c01 > 0.1f, t11 = c11 > 0.1f;
    meta[b * 8 + 0] = t00;
    meta[b * 8 + 1] = t10;
    meta[b * 8 + 2] = t01;
    meta[b * 8 + 3] = t11;
    meta[b * 8 + 4] = (t00 != t01) || (t10 != t11);
  }
}

__global__ __launch_bounds__(256) void attn_kernel_f32(const float* __restrict__ qw,
                                                       const float* __restrict__ kw,
                                                       const float* __restrict__ vw,
                                                       const int* __restrict__ meta,
                                                       float* __restrict__ ao) {
  __shared__ float S[32][1028];
  __shared__ float qs[32][68];
  __shared__ float kc[64][68];
  __shared__ float rowsum_s[32];

  int tid = threadIdx.x;
  int lane = tid & 63;
  int wv = tid >> 6;
  int id = blockIdx.x;
  int rt = id & 31;
  int h = (id >> 5) & 15;
  int b = id >> 9;
  int bh = b * 16 + h;
  int row0 = rt * 32;

  const int* mb = meta + b * 8;
  int t00 = mb[0], t10 = mb[1], t01 = mb[2], t11 = mb[3], needs = mb[4];

  {
    const float4* qp = (const float4*)(qw + ((size_t)bh * 1024 + row0 + wv * 8) * 64);
    #pragma unroll
    for (int i = 0; i < 2; ++i) {
      int f = lane + 64 * i;
      float4 v = qp[f];
      int r = wv * 8 + (f >> 4);
      int d = (f & 15) << 2;
      qs[r][d] = v.x; qs[r][d + 1] = v.y; qs[r][d + 2] = v.z; qs[r][d + 3] = v.w;
    }
  }

  int lr = lane >> 4, lc = lane & 15;
  int r_a = wv * 8 + lr * 2;
  int r_b = r_a + 1;

  for (int cb = 0; cb < 16; ++cb) {
    __syncthreads();
    const float4* kp = (const float4*)(kw + ((size_t)bh * 1024 + cb * 64) * 64);
    #pragma unroll
    for (int i = 0; i < 4; ++i) {
      int f = tid + 256 * i;
      float4 v = kp[f];
      int c = f >> 4, d = (f & 15) << 2;
      kc[c][d] = v.x; kc[c][d + 1] = v.y; kc[c][d + 2] = v.z; kc[c][d + 3] = v.w;
    }
    __syncthreads();

    float acc0[4] = {0.f, 0.f, 0.f, 0.f};
    float acc1[4] = {0.f, 0.f, 0.f, 0.f};
    for (int dq = 0; dq < 64; dq += 4) {
      float4 qa = *(const float4*)&qs[r_a][dq];
      float4 qb = *(const float4*)&qs[r_b][dq];
      #pragma unroll
      for (int cj = 0; cj < 4; ++cj) {
        float4 kv = *(const float4*)&kc[lc + 16 * cj][dq];
        acc0[cj] += qa.x * kv.x + qa.y * kv.y + qa.z * kv.z + qa.w * kv.w;
        acc1[cj] += qb.x * kv.x + qb.y * kv.y + qb.z * kv.z + qb.w * kv.w;
      }
    }
    #pragma unroll
    for (int cj = 0; cj < 4; ++cj) {
      S[r_a][cb * 64 + lc + 16 * cj] = acc0[cj] * SCALE_;
      S[r_b][cb * 64 + lc + 16 * cj] = acc1[cj] * SCALE_;
    }
  }

  for (int rr = 0; rr < 8; ++rr) {
    int r = wv * 8 + rr;
    int grow = row0 + r;
    float sv[16];
    unsigned kv[16];
    #pragma unroll
    for (int i2 = 0; i2 < 16; ++i2) {
      float s = S[r][lane + 64 * i2];
      sv[i2] = s;
      unsigned u = __float_as_uint(s);
      kv[i2] = (u & 0x80000000u) ? ~u : (u | 0x80000000u);
    }
    unsigned T = 0u;
    if (needs) {
      for (int bit = 31; bit >= 0; --bit) {
        unsigned cand = T | (1u << bit);
        int cnt = 0;
        #pragma unroll
        for (int i2 = 0; i2 < 16; ++i2) cnt += (kv[i2] >= cand) ? 1 : 0;
        for (int off = 32; off; off >>= 1) cnt += __shfl_xor(cnt, off, 64);
        if (cnt >= KTOP_) T = cand;
      }
    }
    float mx = -INFINITY;
    int kept = 0;
    unsigned kmask = 0;
    #pragma unroll
    for (int i2 = 0; i2 < 16; ++i2) {
      int j = lane + 64 * i2;
      int sp = (kv[i2] >= T) ? 1 : 0;
      int dj = grow - j;
      int lo = (dj <= 16 && dj >= -16) ? 1 : 0;
      int keep = sp ? (lo ? t11 : t01) : (lo ? t10 : t00);
      kept += keep;
      if (keep) { kmask |= (1u << i2); mx = fmaxf(mx, sv[i2]); }
    }
    for (int off = 32; off; off >>= 1) {
      mx = fmaxf(mx, __shfl_xor(mx, off, 64));
      kept += __shfl_xor(kept, off, 64);
    }
    if (kept == 0) {
      #pragma unroll
      for (int i2 = 0; i2 < 16; ++i2) {
        int j = lane + 64 * i2;
        S[r][j] = (j == grow) ? 1.0f : 0.0f;
      }
      if (lane == 0) rowsum_s[r] = 1.0f;
    } else {
      float sum = 0.f;
      #pragma unroll
      for (int i2 = 0; i2 < 16; ++i2) {
        float p = ((kmask >> i2) & 1u) ? __expf(sv[i2] - mx) : 0.0f;
        sum += p;
        S[r][lane + 64 * i2] = p;
      }
      for (int off = 32; off; off >>= 1) sum += __shfl_xor(sum, off, 64);
      if (lane == 0) rowsum_s[r] = sum;
    }
  }

  int ld = lane & 15;
  int d0 = ld * 4;
  float4 oa0 = make_float4(0.f, 0.f, 0.f, 0.f);
  float4 oa1 = make_float4(0.f, 0.f, 0.f, 0.f);
  for (int vb = 0; vb < 16; ++vb) {
    __syncthreads();
    const float4* vp = (const float4*)(vw + ((size_t)bh * 1024 + vb * 64) * 64);
    #pragma unroll
    for (int i = 0; i < 4; ++i) {
      int f = tid + 256 * i;
      float4 v = vp[f];
      int c = f >> 4, d = (f & 15) << 2;
      kc[c][d] = v.x; kc[c][d + 1] = v.y; kc[c][d + 2] = v.z; kc[c][d + 3] = v.w;
    }
    __syncthreads();
    for (int cq = 0; cq < 64; cq += 4) {
      float4 pa = *(const float4*)&S[r_a][vb * 64 + cq];
      float4 pb = *(const float4*)&S[r_b][vb * 64 + cq];
      float par[4] = {pa.x, pa.y, pa.z, pa.w};
      float pbr[4] = {pb.x, pb.y, pb.z, pb.w};
      #pragma unroll
      for (int tt = 0; tt < 4; ++tt) {
        float4 vv = *(const float4*)&kc[cq + tt][d0];
        oa0.x += par[tt] * vv.x; oa0.y += par[tt] * vv.y;
        oa0.z += par[tt] * vv.z; oa0.w += par[tt] * vv.w;
        oa1.x += pbr[tt] * vv.x; oa1.y += pbr[tt] * vv.y;
        oa1.z += pbr[tt] * vv.z; oa1.w += pbr[tt] * vv.w;
      }
    }
  }
  float inv0 = 1.0f / rowsum_s[r_a];
  float inv1 = 1.0f / rowsum_s[r_b];
  float* p0 = ao + ((size_t)b * 1024 + row0 + r_a) * 1024 + h * 64 + d0;
  float* p1 = ao + ((size_t)b * 1024 + row0 + r_b) * 1024 + h * 64 + d0;
  *(float4*)p0 = make_float4(oa0.x * inv0, oa0.y * inv0, oa0.z * inv0, oa0.w * inv0);
  *(float4*)p1 = make_float4(oa1.x * inv1, oa1.y * inv1, oa1.z * inv1, oa1.w * inv1);
}

// ---------------------------------------------------------------------------
extern "C" void kernel_launch(void* const* d_in, const int* in_sizes, int n_in,
                              void* d_out, int out_size, void* d_ws, size_t ws_size,
                              hipStream_t stream) {
  const float* x      = (const float*)d_in[0];
  const float* w_qkv  = (const float*)d_in[1];
  const float* w_proj = (const float*)d_in[2];
  const float* b_proj = (const float*)d_in[3];
  const float* ps_w1  = (const float*)d_in[4];
  const float* ps_b1  = (const float*)d_in[5];
  const float* ln_g   = (const float*)d_in[6];
  const float* ln_b   = (const float*)d_in[7];
  const float* ps_w2  = (const float*)d_in[8];
  const float* ps_b2  = (const float*)d_in[9];
  const float* ps_w3  = (const float*)d_in[10];
  const float* ps_b3  = (const float*)d_in[11];
  const float* pbias  = (const float*)d_in[12];
  // d_in[13]=sparse_w, d_in[14]=sparse_b: monotone per-row affine -> top-k invariant.

  float* ws = (float*)d_ws;
  float* pooled = ws;                              // 4096
  int*   meta   = (int*)(ws + 4096);               // 32
  float* h1buf  = ws + 8192;                       // 4096
  float* h2buf  = ws + 12288;                      // 2048
  float* ppsum  = ws + 16384;                      // 262144
  float* ppmax  = ws + 278528;                     // 262144
  float* qw = ws + 1048576;                        // 4M each (force path)
  float* kw = qw + 4194304;
  float* vw = kw + 4194304;
  float* ao = vw + 4194304;
  unsigned short* u16b = (unsigned short*)(ao + 4194304);
  unsigned short* xs   = u16b;                     // [4096][2048]  8.39M u16
  unsigned short* wqs  = xs + 8388608;             // [3072][2048]  6.29M
  unsigned short* wps  = wqs + 6291456;            // [1024][2048]  2.10M
  unsigned short* aos  = wps + 2097152;            // [4096][2048]  8.39M
  unsigned short* qx   = aos + 8388608;            // [64][1024][128] 8.39M
  unsigned short* kx   = qx + 8388608;             // 8.39M
  unsigned short* vx   = kx + 8388608;             // [64][64][2048]  8.39M
  float* out = (float*)d_out;

  const size_t NEED_FULL = (size_t)(1048576 + 4 * 4194304) * 4 +
                           (size_t)(8388608 + 6291456 + 2097152 + 8388608 +
                                    3 * 8388608) * 2;

  if (ws_size >= NEED_FULL) {
    pool1<<<256, 256, 0, stream>>>(x, ppsum, ppmax, (unsigned*)xs);
    pool2<<<16, 256, 0, stream>>>(ppsum, ppmax, pooled);
    ps_gemv1<<<64, 256, 0, stream>>>(pooled, ps_w1, ps_b1, h1buf);
    ps_ln<<<4, 256, 0, stream>>>(h1buf, ln_g, ln_b);
    ps_gemv2<<<32, 256, 0, stream>>>(h1buf, ps_w2, ps_b2, h2buf);
    ps_logits<<<4, 256, 0, stream>>>(h2buf, ps_w3, ps_b3, pbias, meta);

    prep_split<<<3072, 256, 0, stream>>>(w_qkv, wqs, 786432);
    prep_split<<<1024, 256, 0, stream>>>(w_proj, wps, 262144);
    gemm_sp<0><<<768, 256, 0, stream>>>(xs, wqs, nullptr,
                                        (unsigned*)qx, (unsigned*)kx, vx,
                                        nullptr, 24);

    attn_flash<<<1024, 256, 0, stream>>>(qx, kx, vx, meta, (unsigned int*)aos);
    attn_sparse<<<2048, 256, 0, stream>>>(qx, kx, vx, meta, (unsigned int*)aos);

    gemm_sp<1><<<256, 256, 0, stream>>>(aos, wps, b_proj,
                                        nullptr, nullptr, nullptr, out, 8);
  } else {
    // fallback: f32 path (needs only the f32 region)
    pool_kernel<<<16, 256, 0, stream>>>(x, pooled);
    pattern_kernel<<<4, 256, 0, stream>>>(pooled, ps_w1, ps_b1, ln_g, ln_b,
                                          ps_w2, ps_b2, ps_w3, ps_b3, pbias, meta);
    qkv_gemm<<<dim3(24, 32), 256, 0, stream>>>(x, w_qkv, qw, kw, vw);
    attn_kernel_f32<<<2048, 256, 0, stream>>>(qw, kw, vw, meta, ao);
    proj_gemm<<<dim3(8, 32), 256, 0, stream>>>(ao, w_proj, b_proj, out);
  }
}